// Round 2
// baseline (243.498 us; speedup 1.0000x reference)
//
#include <hip/hip_runtime.h>

typedef _Float16 f16;
typedef _Float16 f16x8 __attribute__((ext_vector_type(8)));
typedef _Float16 f16x4 __attribute__((ext_vector_type(4)));
typedef float f32x4 __attribute__((ext_vector_type(4)));

#define MFMA32(a, b, c) __builtin_amdgcn_mfma_f32_16x16x32_f16((a), (b), (c), 0, 0, 0)

constexpr int Bs = 2, Ls = 2048, DIM = 1024, NH = 16, HD = 64;
constexpr int BL = Bs * Ls;  // 4096
constexpr float EPSV = 1e-6f;
constexpr float SCL2 = 0.125f * 1.44269504f;  // (1/sqrt(64)) * log2(e); folded into q

// async global->LDS, 16B per lane. LDS dest = wave-uniform base + lane*16.
__device__ __forceinline__ void async16(void* lds, const void* g) {
  __builtin_amdgcn_global_load_lds((const __attribute__((address_space(1))) void*)g,
                                   (__attribute__((address_space(3))) void*)lds, 16, 0, 0);
}

// BK=32 pair-XOR swizzle: rows are 64B (4 chunks); swizzle unit = row PAIR (8 chunks).
// LDS linear chunk lc <-> (pair p = lc>>3, phys ph = lc&7); global chunk g = ph ^ (p&7),
// global (row, colElems) = (2p + (g>>2), (g&3)*8). Frag read of (row r, kchunk q):
// addr elems = (r>>1)*64 + (((r&1)*4 + q) ^ ((r>>1)&7))*8.  Banks: 2-way (free).
__device__ __forceinline__ int sw32(int r, int q) {
  int p = r >> 1;
  return p * 64 + ((((r & 1) * 4 + q) ^ (p & 7)) * 8);
}

// ---------------- fp32 -> fp16 convert: weights only (x is fused into qkv) ----------------
__global__ void cvt_w_kernel(const float* __restrict__ wq, const float* __restrict__ wp,
                             f16* __restrict__ wqf, f16* __restrict__ wpf) {
  constexpr int NW4 = 3 * DIM * DIM / 4;
  int i = blockIdx.x * blockDim.x + threadIdx.x;
  const float4* src;
  f16x4* dst;
  int j;
  if (i < NW4) {
    src = (const float4*)wq; dst = (f16x4*)wqf; j = i;
  } else {
    src = (const float4*)wp; dst = (f16x4*)wpf; j = i - NW4;
  }
  float4 a = src[j];
  f16x4 o = {(f16)a.x, (f16)a.y, (f16)a.z, (f16)a.w};
  dst[j] = o;
}

// ============ QKV GEMM: 128x128 tile, BK=32, double-buffered, early-issue staging ============
// A = x (fp32) reg-staged + converted in-kernel; B = weights via glLDS. One barrier/iter:
// issue loads for t+1 into buf^1 BEFORE the MFMA phase of t, so load latency hides under
// compute instead of being drained cold at the barrier. XCD-bijective block remap gives each
// XCD 4 contiguous A-row panels (2MB fp32, L2-resident). v-epilogue transposes through the
// (dead) staging LDS -> 16 coalesced b64 stores/wave instead of 64 scattered 2B stores.
__global__ __launch_bounds__(256) void qkv_gemm_kernel(
    const float* __restrict__ X, const f16* __restrict__ W,
    const float* __restrict__ v0,
    const float* __restrict__ rcos, const float* __restrict__ rsin,
    const float* __restrict__ lamp,
    f16* __restrict__ qb, f16* __restrict__ kb, f16* __restrict__ vbT,
    float* __restrict__ vout) {
  constexpr int K = DIM;
  __shared__ alignas(16) f16 sm[4][128 * 32];  // [0..1]=A dbuf, [2..3]=B dbuf; 32KB
  const int tid = threadIdx.x;
  const int w = tid >> 6, lane = tid & 63, ln = lane & 15, quad = lane >> 4;
  const int wm = w >> 1, wn = w & 1;

  // XCD-bijective remap: 768 blocks, blocks with same (bid&7) share an XCD-contiguous
  // chunk of 96 = 4 A-row panels (512 rows x 1024 f32 = 2MB, fits 4MB XCD L2).
  const int wg = ((blockIdx.x & 7) * 96) + (blockIdx.x >> 3);
  const int m0 = (wg / 24) * 128, n0 = (wg % 24) * 128;

  // A: per-thread 2 chunks (8 f32 each), pre-swizzled source so LDS layout matches sw32.
  const float* gAx[2];
  const f16* gB[2];
#pragma unroll
  for (int s = 0; s < 2; ++s) {
    int lc = tid + s * 256;
    int p = lc >> 3, g = (lc & 7) ^ (p & 7);
    int r = 2 * p + (g >> 2), ce = (g & 3) * 8;
    gAx[s] = X + (size_t)(m0 + r) * K + ce;
    gB[s] = W + (size_t)(n0 + r) * K + ce;
  }

  float4 ar[2][2];
  auto loadA = [&](int k0) {
#pragma unroll
    for (int s = 0; s < 2; ++s) {
      const float* pa = gAx[s] + k0;
      ar[s][0] = *(const float4*)pa;
      ar[s][1] = *(const float4*)(pa + 4);
    }
  };
  auto writeA = [&](int buf) {
#pragma unroll
    for (int s = 0; s < 2; ++s) {
      f16x8 h8 = {(f16)ar[s][0].x, (f16)ar[s][0].y, (f16)ar[s][0].z, (f16)ar[s][0].w,
                  (f16)ar[s][1].x, (f16)ar[s][1].y, (f16)ar[s][1].z, (f16)ar[s][1].w};
      *(f16x8*)&sm[buf][(tid + s * 256) * 8] = h8;
    }
  };
  auto issueB = [&](int k0, int buf) {
#pragma unroll
    for (int s = 0; s < 2; ++s) async16(&sm[2 + buf][(tid + s * 256) * 8], gB[s] + k0);
  };

  f32x4 acc[4][4] = {};

  // prologue: fill buffer 0
  loadA(0);
  issueB(0, 0);
  writeA(0);
  __syncthreads();

  for (int it = 0; it < 32; ++it) {
    const int cur = it & 1, nxt = cur ^ 1;
    if (it < 31) {            // issue next tile's loads BEFORE compute
      loadA((it + 1) * 32);   // fp32 A -> regs (vmem in flight)
      issueB((it + 1) * 32, nxt);  // glLDS B -> buf[nxt]
    }
    f16x8 a[4];
#pragma unroll
    for (int mi = 0; mi < 4; ++mi)
      a[mi] = *(const f16x8*)&sm[cur][sw32(wm * 64 + mi * 16 + ln, quad)];
#pragma unroll
    for (int ni = 0; ni < 4; ++ni) {
      f16x8 b = *(const f16x8*)&sm[2 + cur][sw32(wn * 64 + ni * 16 + ln, quad)];
#pragma unroll
      for (int mi = 0; mi < 4; ++mi) acc[mi][ni] = MFMA32(a[mi], b, acc[mi][ni]);
    }
    if (it < 31) writeA(nxt);  // convert + LDS write (waits its own vmem late)
    __syncthreads();           // drains (glLDS mostly done by now) + swap
  }

  // Epilogue. Wave covers one head (64 cols). C/D: col=ln (ni tile), row=quad*4+rg (mi tile).
  const int nb = n0 + wn * 64;
  const int nsec = nb >> 10;        // 0=q, 1=k, 2=v  (uniform per block)
  const int h = (nb & 1023) >> 6;   // head

  if (nsec == 2) {
    const float lam = lamp[0];
    const int l064 = m0 + wm * 64;           // 64-aligned key-group base (global row)
    const int b = l064 >> 11, l0 = l064 & 2047;
    const size_t vb = (size_t)(b * NH + h) * Ls * HD;
    f16* wT = &sm[0][0] + w * 4096;          // per-wave 8KB transpose tile [d][sidx]
    __syncthreads();                         // all waves done reading staging bufs
#pragma unroll
    for (int mi = 0; mi < 4; ++mi) {
#pragma unroll
      for (int ni = 0; ni < 4; ++ni) {
        const int d = ni * 16 + ln;
        f16 pk[4];
#pragma unroll
        for (int rg = 0; rg < 4; ++rg) {
          const int kk = mi * 16 + quad * 4 + rg;
          const size_t base = vb + (size_t)(l0 + kk) * HD + d;
          float vnew = lam * acc[mi][ni][rg] + (1.0f - lam) * v0[base];
          vout[base] = vnew;  // fp32 output #1 (b,h,l,d), coalesced
          pk[rg] = (f16)vnew;
        }
        // sidx for kk: quad*16 + mi*4 + rg -> rg-contiguous; bank-XOR by d
        f16x4 q4 = {pk[0], pk[1], pk[2], pk[3]};
        const int sidx0 = quad * 16 + mi * 4;
        *(f16x4*)&wT[d * 64 + (sidx0 ^ ((d & 7) << 3))] = q4;
      }
    }
    __syncthreads();
    // coalesced read-out: per d-row, 16 lanes x 8B = 128B contiguous in vbT
    const size_t tB = (size_t)(b * NH + h) * HD * Ls + l0;
#pragma unroll
    for (int dd = 0; dd < 16; ++dd) {
      const int d = dd * 4 + quad;
      f16x4 vv = *(const f16x4*)&wT[d * 64 + ((ln * 4) ^ ((d & 7) << 3))];
      *(f16x4*)&vbT[tB + (size_t)d * Ls + ln * 4] = vv;
    }
  } else {
    f16* dst = nsec ? kb : qb;
    const float ratio = sqrtf(logf(2048.0f) / logf(1040.0f));
    const float post = nsec ? 1.0f : SCL2;  // fold softmax scale*log2e into q
#pragma unroll
    for (int mi = 0; mi < 4; ++mi) {
#pragma unroll
      for (int rg = 0; rg < 4; ++rg) {
        int row = m0 + wm * 64 + mi * 16 + quad * 4 + rg;
        int b = row >> 11, l = row & 2047;
        float vals[4];
#pragma unroll
        for (int ni = 0; ni < 4; ++ni) vals[ni] = acc[mi][ni][rg];
#pragma unroll
        for (int t = 0; t < 2; ++t) {
          int j = t * 16 + ln;
          float c = rcos[l * 32 + j], s = rsin[l * 32 + j];
          float x1 = vals[t], x2 = vals[t + 2];
          vals[t] = x1 * c + x2 * s;
          vals[t + 2] = -x1 * s + x2 * c;
        }
        if (nsec) {
#pragma unroll
          for (int ni = 0; ni < 4; ++ni) vals[ni] *= ratio;
        }
        float ms = vals[0] * vals[0] + vals[1] * vals[1] + vals[2] * vals[2] + vals[3] * vals[3];
        ms += __shfl_xor(ms, 1);
        ms += __shfl_xor(ms, 2);
        ms += __shfl_xor(ms, 4);
        ms += __shfl_xor(ms, 8);
        float rn = rsqrtf(ms * (1.0f / 64.0f) + EPSV) * post;
        size_t base = ((size_t)(b * NH + h) * Ls + l) * HD;
#pragma unroll
        for (int ni = 0; ni < 4; ++ni) dst[base + ni * 16 + ln] = (f16)(vals[ni] * rn);
      }
    }
  }
}

// ============ Flash attention: kt-split wave groups + all-MFMA32 + rsum-via-ones ============
__global__ __launch_bounds__(512, 4) void flash_kernel(
    const f16* __restrict__ qg, const f16* __restrict__ kg, const f16* __restrict__ vtg,
    f16* __restrict__ ao) {
  __shared__ alignas(16) f16 sK[2][2][64 * 64];   // [group][buf]
  __shared__ alignas(16) f16 sVT[2][2][64 * 64];  // [group][buf] [d][key-permuted]
  const int tid = threadIdx.x;
  const int w = tid >> 6, lane = tid & 63, ln = lane & 15, quad = lane >> 4;
  const int grp = w >> 2, wl = w & 3;  // kt-group, wave-in-group
  const int gt = tid & 255;            // thread id within group (staging)
  const int bx = blockIdx.x;
  const int bh = bx & 31, qt = bx >> 5;  // XCD-major: (b,h) fixed per bx%8 class
  const int h = bh & 15, b = bh >> 4;
  const f16* Qh = qg + (size_t)(b * NH + h) * Ls * HD;
  const f16* Kh = kg + (size_t)(b * NH + h) * Ls * HD;
  const f16* VTh = vtg + (size_t)(b * NH + h) * HD * Ls;
  const int q0 = qt * 128;

  // Q as B-frags straight from global: lane n=ln (q-col), k = kk*32 + quad*8 + j
  f16x8 aq[2][2];
#pragma unroll
  for (int st = 0; st < 2; ++st)
#pragma unroll
    for (int kk = 0; kk < 2; ++kk)
      aq[st][kk] = *(const f16x8*)&Qh[(size_t)(q0 + wl * 32 + st * 16 + ln) * HD + kk * 32 + quad * 8];

  f16x8 kr[2], vr[2];
  auto loadKV = [&](int k0) {
#pragma unroll
    for (int s = 0; s < 2; ++s) {
      int ch = gt + s * 256, r = ch >> 3, cg = (ch & 7) * 8;
      kr[s] = *(const f16x8*)&Kh[(size_t)(k0 + r) * HD + cg];
      vr[s] = *(const f16x8*)&VTh[(size_t)r * Ls + k0 + cg];
    }
  };
  auto stageKV = [&](int buf) {
#pragma unroll
    for (int s = 0; s < 2; ++s) {
      int ch = gt + s * 256, r = ch >> 3;
      int po = r * 64 + (((ch & 7) ^ (r & 7)) * 8);
      *(f16x8*)&sK[grp][buf][po] = kr[s];
      *(f16x8*)&sVT[grp][buf][po] = vr[s];
    }
  };

  f32x4 O[2][4] = {};
  f32x4 racc[2] = {};
  const f16x8 onesv = {(f16)1.f, (f16)1.f, (f16)1.f, (f16)1.f,
                       (f16)1.f, (f16)1.f, (f16)1.f, (f16)1.f};
  const f32x4 zc = {};

  const int kbase = grp << 10;  // group key offset
  loadKV(kbase);
  stageKV(0);
  __syncthreads();

  for (int t = 0; t < 16; ++t) {
    const int cur = t & 1;
    if (t < 15) loadKV(kbase + (t + 1) * 64);  // global->reg prefetch across compute

    // S^T + exp in registers -> merged PV A-frags (f16x8 = two 16-key tiles)
    f16x8 pA[2][2];
#pragma unroll
    for (int nt = 0; nt < 4; ++nt) {
      const int r = nt * 16 + ln;  // key row
      const f16x8 kf0 = *(const f16x8*)&sK[grp][cur][r * 64 + ((quad ^ (r & 7)) * 8)];
      const f16x8 kf1 = *(const f16x8*)&sK[grp][cur][r * 64 + (((4 + quad) ^ (r & 7)) * 8)];
#pragma unroll
      for (int st = 0; st < 2; ++st) {
        f32x4 z = MFMA32(kf1, aq[st][1], MFMA32(kf0, aq[st][0], zc));
#pragma unroll
        for (int j = 0; j < 4; ++j)
          pA[st][nt >> 1][(nt & 1) * 4 + j] = (f16)exp2f(z[j]);
      }
    }

    __builtin_amdgcn_s_setprio(1);
#pragma unroll
    for (int st = 0; st < 2; ++st) {
      racc[st] = MFMA32(pA[st][0], onesv, racc[st]);
      racc[st] = MFMA32(pA[st][1], onesv, racc[st]);
    }
#pragma unroll
    for (int dt = 0; dt < 4; ++dt) {
      const int row = dt * 16 + ln;  // d row
#pragma unroll
      for (int nt2 = 0; nt2 < 2; ++nt2) {
        const f16x8 vf = *(const f16x8*)&sVT[grp][cur][row * 64 + (((quad * 2 + nt2) ^ (row & 7)) * 8)];
#pragma unroll
        for (int st = 0; st < 2; ++st)
          O[st][dt] = MFMA32(pA[st][nt2], vf, O[st][dt]);
      }
    }
    __builtin_amdgcn_s_setprio(0);

    if (t < 15) stageKV(cur ^ 1);  // vmcnt wait lands here, after compute
    __syncthreads();
  }

  // ---- combine the two kt-halves through the (now dead) staging LDS ----
  float* cO = (float*)&sK[0][0][0];   // 128 q x 64 d f32 = 32 KB (all of sK)
  float* cR = (float*)&sVT[0][0][0];  // 128 f32
  if (grp == 1) {
#pragma unroll
    for (int st = 0; st < 2; ++st) {
#pragma unroll
      for (int rg = 0; rg < 4; ++rg) {
        const int ql = wl * 32 + st * 16 + quad * 4 + rg;
#pragma unroll
        for (int dt = 0; dt < 4; ++dt) cO[ql * 64 + dt * 16 + ln] = O[st][dt][rg];
        if (ln == 0) cR[ql] = racc[st][rg];
      }
    }
  }
  __syncthreads();
  if (grp == 0) {
#pragma unroll
    for (int st = 0; st < 2; ++st) {
#pragma unroll
      for (int rg = 0; rg < 4; ++rg) {
        const int ql = wl * 32 + st * 16 + quad * 4 + rg;
        const float inv = 1.0f / (racc[st][rg] + cR[ql]);
        const int q = q0 + ql;
        const size_t orow = ((size_t)b * Ls + q) * DIM + h * HD;
#pragma unroll
        for (int dt = 0; dt < 4; ++dt)
          ao[orow + dt * 16 + ln] = (f16)((O[st][dt][rg] + cO[ql * 64 + dt * 16 + ln]) * inv);
      }
    }
  }
}

// ============ proj GEMM: 64x128 tile, BK=32 m97-style single-buffer glLDS ============
__global__ __launch_bounds__(256) void proj_gemm_kernel(
    const f16* __restrict__ A, const f16* __restrict__ W, float* __restrict__ out) {
  constexpr int K = DIM;
  __shared__ alignas(16) f16 sA[64 * 32];
  __shared__ alignas(16) f16 sB[128 * 32];
  const int tid = threadIdx.x;
  const int w = tid >> 6, lane = tid & 63, ln = lane & 15, quad = lane >> 4;
  const int wm = w >> 1, wn = w & 1;  // wave: 32 rows x 64 cols
  const int m0 = blockIdx.y * 64, n0 = blockIdx.x * 128;

  const f16* gA;  // 256 chunks: 1 per thread
  {
    int p = tid >> 3, g = (tid & 7) ^ (p & 7);
    gA = A + (size_t)(m0 + 2 * p + (g >> 2)) * K + (g & 3) * 8;
  }
  const f16* gB[2];
#pragma unroll
  for (int s = 0; s < 2; ++s) {
    int lc = tid + s * 256;
    int p = lc >> 3, g = (lc & 7) ^ (p & 7);
    gB[s] = W + (size_t)(n0 + 2 * p + (g >> 2)) * K + (g & 3) * 8;
  }

  f32x4 acc[2][4] = {};

  for (int it = 0; it < 32; ++it) {
    const int k0 = it * 32;
    async16(&sA[tid * 8], gA + k0);
#pragma unroll
    for (int s = 0; s < 2; ++s) async16(&sB[(tid + s * 256) * 8], gB[s] + k0);
    __syncthreads();
    f16x8 a[2];
#pragma unroll
    for (int mi = 0; mi < 2; ++mi)
      a[mi] = *(const f16x8*)&sA[sw32(wm * 32 + mi * 16 + ln, quad)];
#pragma unroll
    for (int ni = 0; ni < 4; ++ni) {
      f16x8 b = *(const f16x8*)&sB[sw32(wn * 64 + ni * 16 + ln, quad)];
#pragma unroll
      for (int mi = 0; mi < 2; ++mi) acc[mi][ni] = MFMA32(a[mi], b, acc[mi][ni]);
    }
    __syncthreads();
  }

#pragma unroll
  for (int mi = 0; mi < 2; ++mi) {
#pragma unroll
    for (int rg = 0; rg < 4; ++rg) {
      int row = m0 + wm * 32 + mi * 16 + quad * 4 + rg;
      size_t o = (size_t)row * DIM + n0 + wn * 64;
#pragma unroll
      for (int ni = 0; ni < 4; ++ni) out[o + ni * 16 + ln] = acc[mi][ni][rg];
    }
  }
}

extern "C" void kernel_launch(void* const* d_in, const int* in_sizes, int n_in,
                              void* d_out, int out_size, void* d_ws, size_t ws_size,
                              hipStream_t stream) {
  (void)in_sizes; (void)n_in; (void)out_size; (void)ws_size;
  const float* x = (const float*)d_in[0];
  const float* v0 = (const float*)d_in[1];
  const float* rcos = (const float*)d_in[2];
  const float* rsin = (const float*)d_in[3];
  const float* wqkv = (const float*)d_in[4];
  const float* wproj = (const float*)d_in[5];
  const float* lamp = (const float*)d_in[6];
  float* out = (float*)d_out;
  float* vout = out + (size_t)BL * DIM;  // output #1: blended v, (B,H,L,HD)

  char* p = (char*)d_ws;
  auto take = [&](size_t n) { char* q = p; p += ((n + 255) / 256) * 256; return q; };
  f16* ao = (f16*)take((size_t)BL * DIM * 2);
  f16* wqf = (f16*)take((size_t)3 * DIM * DIM * 2);
  f16* wpf = (f16*)take((size_t)DIM * DIM * 2);
  f16* qb = (f16*)take((size_t)BL * DIM * 2);
  f16* kb = (f16*)take((size_t)BL * DIM * 2);
  f16* vbT = (f16*)take((size_t)BL * DIM * 2);  // (b,h,d, key-permuted l)

  constexpr int NCVT4 = (3 * DIM * DIM + DIM * DIM) / 4;
  cvt_w_kernel<<<dim3(NCVT4 / 256), dim3(256), 0, stream>>>(wqkv, wproj, wqf, wpf);

  qkv_gemm_kernel<<<dim3(3 * DIM / 128 * (BL / 128)), dim3(256), 0, stream>>>(
      x, wqf, v0, rcos, rsin, lamp, qb, kb, vbT, vout);

  flash_kernel<<<dim3(Bs * NH * (Ls / 128)), dim3(512), 0, stream>>>(qb, kb, vbT, ao);

  proj_gemm_kernel<<<dim3(DIM / 128, BL / 64), dim3(256), 0, stream>>>(ao, wpf, out);
}

// Round 3
// 231.645 us; speedup vs baseline: 1.0512x; 1.0512x over previous
//
#include <hip/hip_runtime.h>

typedef _Float16 f16;
typedef _Float16 f16x8 __attribute__((ext_vector_type(8)));
typedef _Float16 f16x4 __attribute__((ext_vector_type(4)));
typedef float f32x4 __attribute__((ext_vector_type(4)));

#define MFMA32(a, b, c) __builtin_amdgcn_mfma_f32_16x16x32_f16((a), (b), (c), 0, 0, 0)

constexpr int Bs = 2, Ls = 2048, DIM = 1024, NH = 16, HD = 64;
constexpr int BL = Bs * Ls;  // 4096
constexpr float EPSV = 1e-6f;
constexpr float SCL2 = 0.125f * 1.44269504f;  // (1/sqrt(64)) * log2(e); folded into q

// async global->LDS, 16B per lane. LDS dest = wave-uniform base + lane*16.
__device__ __forceinline__ void async16(void* lds, const void* g) {
  __builtin_amdgcn_global_load_lds((const __attribute__((address_space(1))) void*)g,
                                   (__attribute__((address_space(3))) void*)lds, 16, 0, 0);
}

// BK=32 pair-XOR swizzle: rows are 64B (4 chunks); swizzle unit = row PAIR (8 chunks).
// LDS linear chunk lc <-> (pair p = lc>>3, phys ph = lc&7); global chunk g = ph ^ (p&7),
// global (row, colElems) = (2p + (g>>2), (g&3)*8). Frag read of (row r, kchunk q):
// addr elems = (r>>1)*64 + (((r&1)*4 + q) ^ ((r>>1)&7))*8.  Banks: 2-way (free).
__device__ __forceinline__ int sw32(int r, int q) {
  int p = r >> 1;
  return p * 64 + ((((r & 1) * 4 + q) ^ (p & 7)) * 8);
}

// ---------------- fp32 -> fp16 convert, all three tensors in one launch ----------------
__global__ void cvt_all_kernel(const float* __restrict__ x, const float* __restrict__ wq,
                               const float* __restrict__ wp, f16* __restrict__ xf,
                               f16* __restrict__ wqf, f16* __restrict__ wpf) {
  constexpr int NX4 = BL * DIM / 4;
  constexpr int NW4 = 3 * DIM * DIM / 4;
  int i = blockIdx.x * blockDim.x + threadIdx.x;
  const float4* src;
  f16x4* dst;
  int j;
  if (i < NX4) {
    src = (const float4*)x; dst = (f16x4*)xf; j = i;
  } else if (i < NX4 + NW4) {
    src = (const float4*)wq; dst = (f16x4*)wqf; j = i - NX4;
  } else {
    src = (const float4*)wp; dst = (f16x4*)wpf; j = i - NX4 - NW4;
  }
  float4 a = src[j];
  f16x4 o = {(f16)a.x, (f16)a.y, (f16)a.z, (f16)a.w};
  dst[j] = o;
}

// ============ QKV GEMM: 128x128 tile, BK=32, glLDS DOUBLE-buffer, 1 barrier/iter ============
// Both operands f16 via global_load_lds (no VALU in staging path). Per iter: issue next
// tile's 4 glLDS into buf^1 BEFORE reading/computing buf -> the barrier's vmcnt drain lands
// after the MFMA phase instead of cold. XCD-bijective remap: 768 blocks, 96/XCD = 4 A-row
// panels (1MB f16, L2-resident) x all 24 n-panels; all 96 XCD-blocks co-resident so W
// panels (256KB) get concurrent L2 reuse. v-epilogue: transpose through dead LDS ->
// coalesced 8B vbT stores.
__global__ __launch_bounds__(256) void qkv_gemm_kernel(
    const f16* __restrict__ A, const f16* __restrict__ W,
    const float* __restrict__ v0,
    const float* __restrict__ rcos, const float* __restrict__ rsin,
    const float* __restrict__ lamp,
    f16* __restrict__ qb, f16* __restrict__ kb, f16* __restrict__ vbT,
    float* __restrict__ vout) {
  constexpr int K = DIM;
  __shared__ alignas(16) f16 sm[4][128 * 32];  // [0,1]=A dbuf, [2,3]=B dbuf; 32KB
  const int tid = threadIdx.x;
  const int w = tid >> 6, lane = tid & 63, ln = lane & 15, quad = lane >> 4;
  const int wm = w >> 1, wn = w & 1;

  // XCD-bijective remap: chunk of 96 per XCD class = 4 m-panels x 24 n-panels.
  const int wg = ((blockIdx.x & 7) * 96) + (blockIdx.x >> 3);
  const int m0 = (wg / 24) * 128, n0 = (wg % 24) * 128;

  const f16* gA[2];
  const f16* gB[2];
#pragma unroll
  for (int s = 0; s < 2; ++s) {
    int lc = tid + s * 256;
    int p = lc >> 3, g = (lc & 7) ^ (p & 7);
    int r = 2 * p + (g >> 2), ce = (g & 3) * 8;
    gA[s] = A + (size_t)(m0 + r) * K + ce;
    gB[s] = W + (size_t)(n0 + r) * K + ce;
  }

  auto issue = [&](int k0, int buf) {
#pragma unroll
    for (int s = 0; s < 2; ++s) {
      async16(&sm[buf][(tid + s * 256) * 8], gA[s] + k0);
      async16(&sm[2 + buf][(tid + s * 256) * 8], gB[s] + k0);
    }
  };

  f32x4 acc[4][4] = {};

  issue(0, 0);
  __syncthreads();  // drain prologue loads

  for (int it = 0; it < 32; ++it) {
    const int cur = it & 1;
    if (it < 31) issue((it + 1) * 32, cur ^ 1);  // in flight across compute
    f16x8 a[4];
#pragma unroll
    for (int mi = 0; mi < 4; ++mi)
      a[mi] = *(const f16x8*)&sm[cur][sw32(wm * 64 + mi * 16 + ln, quad)];
#pragma unroll
    for (int ni = 0; ni < 4; ++ni) {
      f16x8 b = *(const f16x8*)&sm[2 + cur][sw32(wn * 64 + ni * 16 + ln, quad)];
#pragma unroll
      for (int mi = 0; mi < 4; ++mi) acc[mi][ni] = MFMA32(a[mi], b, acc[mi][ni]);
    }
    __syncthreads();  // drains next-buf loads + protects cur for overwrite at it+1
  }

  // Epilogue. Wave covers one head (64 cols). C/D: col=ln (ni tile), row=quad*4+rg (mi tile).
  const int nb = n0 + wn * 64;
  const int nsec = nb >> 10;        // 0=q, 1=k, 2=v  (uniform per block)
  const int h = (nb & 1023) >> 6;   // head

  if (nsec == 2) {
    const float lam = lamp[0];
    const int l064 = m0 + wm * 64;           // 64-aligned key-group base (global row)
    const int b = l064 >> 11, l0 = l064 & 2047;
    const size_t vb = (size_t)(b * NH + h) * Ls * HD;
    f16* wT = &sm[0][0] + w * 4096;          // per-wave 8KB transpose tile [d][sidx]
#pragma unroll
    for (int mi = 0; mi < 4; ++mi) {
#pragma unroll
      for (int ni = 0; ni < 4; ++ni) {
        const int d = ni * 16 + ln;
        f16 pk[4];
#pragma unroll
        for (int rg = 0; rg < 4; ++rg) {
          const int kk = mi * 16 + quad * 4 + rg;
          const size_t base = vb + (size_t)(l0 + kk) * HD + d;
          float vnew = lam * acc[mi][ni][rg] + (1.0f - lam) * v0[base];
          vout[base] = vnew;  // fp32 output #1 (b,h,l,d), coalesced
          pk[rg] = (f16)vnew;
        }
        // sidx for kk = mi*16+quad*4+rg: quad*16 + mi*4 + rg (flash's key permutation)
        f16x4 q4 = {pk[0], pk[1], pk[2], pk[3]};
        const int sidx0 = quad * 16 + mi * 4;
        *(f16x4*)&wT[d * 64 + (sidx0 ^ ((d & 7) << 3))] = q4;
      }
    }
    // coalesced read-out (per-wave-private tile, no barrier needed)
    const size_t tB = (size_t)(b * NH + h) * HD * Ls + l0;
#pragma unroll
    for (int dd = 0; dd < 16; ++dd) {
      const int d = dd * 4 + quad;
      f16x4 vv = *(const f16x4*)&wT[d * 64 + ((ln * 4) ^ ((d & 7) << 3))];
      *(f16x4*)&vbT[tB + (size_t)d * Ls + ln * 4] = vv;
    }
  } else {
    f16* dst = nsec ? kb : qb;
    const float ratio = sqrtf(logf(2048.0f) / logf(1040.0f));
    const float post = nsec ? 1.0f : SCL2;  // fold softmax scale*log2e into q
#pragma unroll
    for (int mi = 0; mi < 4; ++mi) {
#pragma unroll
      for (int rg = 0; rg < 4; ++rg) {
        int row = m0 + wm * 64 + mi * 16 + quad * 4 + rg;
        int b = row >> 11, l = row & 2047;
        float vals[4];
#pragma unroll
        for (int ni = 0; ni < 4; ++ni) vals[ni] = acc[mi][ni][rg];
#pragma unroll
        for (int t = 0; t < 2; ++t) {
          int j = t * 16 + ln;
          float c = rcos[l * 32 + j], s = rsin[l * 32 + j];
          float x1 = vals[t], x2 = vals[t + 2];
          vals[t] = x1 * c + x2 * s;
          vals[t + 2] = -x1 * s + x2 * c;
        }
        if (nsec) {
#pragma unroll
          for (int ni = 0; ni < 4; ++ni) vals[ni] *= ratio;
        }
        float ms = vals[0] * vals[0] + vals[1] * vals[1] + vals[2] * vals[2] + vals[3] * vals[3];
        ms += __shfl_xor(ms, 1);
        ms += __shfl_xor(ms, 2);
        ms += __shfl_xor(ms, 4);
        ms += __shfl_xor(ms, 8);
        float rn = rsqrtf(ms * (1.0f / 64.0f) + EPSV) * post;
        size_t base = ((size_t)(b * NH + h) * Ls + l) * HD;
#pragma unroll
        for (int ni = 0; ni < 4; ++ni) dst[base + ni * 16 + ln] = (f16)(vals[ni] * rn);
      }
    }
  }
}

// ============ Flash attention: kt-split wave groups + all-MFMA32 + rsum-via-ones ============
__global__ __launch_bounds__(512, 4) void flash_kernel(
    const f16* __restrict__ qg, const f16* __restrict__ kg, const f16* __restrict__ vtg,
    f16* __restrict__ ao) {
  __shared__ alignas(16) f16 sK[2][2][64 * 64];   // [group][buf]
  __shared__ alignas(16) f16 sVT[2][2][64 * 64];  // [group][buf] [d][key-permuted]
  const int tid = threadIdx.x;
  const int w = tid >> 6, lane = tid & 63, ln = lane & 15, quad = lane >> 4;
  const int grp = w >> 2, wl = w & 3;  // kt-group, wave-in-group
  const int gt = tid & 255;            // thread id within group (staging)
  const int bx = blockIdx.x;
  const int bh = bx & 31, qt = bx >> 5;  // XCD-major: (b,h) fixed per bx%8 class
  const int h = bh & 15, b = bh >> 4;
  const f16* Qh = qg + (size_t)(b * NH + h) * Ls * HD;
  const f16* Kh = kg + (size_t)(b * NH + h) * Ls * HD;
  const f16* VTh = vtg + (size_t)(b * NH + h) * HD * Ls;
  const int q0 = qt * 128;

  // Q as B-frags straight from global: lane n=ln (q-col), k = kk*32 + quad*8 + j
  f16x8 aq[2][2];
#pragma unroll
  for (int st = 0; st < 2; ++st)
#pragma unroll
    for (int kk = 0; kk < 2; ++kk)
      aq[st][kk] = *(const f16x8*)&Qh[(size_t)(q0 + wl * 32 + st * 16 + ln) * HD + kk * 32 + quad * 8];

  f16x8 kr[2], vr[2];
  auto loadKV = [&](int k0) {
#pragma unroll
    for (int s = 0; s < 2; ++s) {
      int ch = gt + s * 256, r = ch >> 3, cg = (ch & 7) * 8;
      kr[s] = *(const f16x8*)&Kh[(size_t)(k0 + r) * HD + cg];
      vr[s] = *(const f16x8*)&VTh[(size_t)r * Ls + k0 + cg];
    }
  };
  auto stageKV = [&](int buf) {
#pragma unroll
    for (int s = 0; s < 2; ++s) {
      int ch = gt + s * 256, r = ch >> 3;
      int po = r * 64 + (((ch & 7) ^ (r & 7)) * 8);
      *(f16x8*)&sK[grp][buf][po] = kr[s];
      *(f16x8*)&sVT[grp][buf][po] = vr[s];
    }
  };

  f32x4 O[2][4] = {};
  f32x4 racc[2] = {};
  const f16x8 onesv = {(f16)1.f, (f16)1.f, (f16)1.f, (f16)1.f,
                       (f16)1.f, (f16)1.f, (f16)1.f, (f16)1.f};
  const f32x4 zc = {};

  const int kbase = grp << 10;  // group key offset
  loadKV(kbase);
  stageKV(0);
  __syncthreads();

  for (int t = 0; t < 16; ++t) {
    const int cur = t & 1;
    if (t < 15) loadKV(kbase + (t + 1) * 64);  // global->reg prefetch across compute

    // S^T + exp in registers -> merged PV A-frags (f16x8 = two 16-key tiles)
    f16x8 pA[2][2];
#pragma unroll
    for (int nt = 0; nt < 4; ++nt) {
      const int r = nt * 16 + ln;  // key row
      const f16x8 kf0 = *(const f16x8*)&sK[grp][cur][r * 64 + ((quad ^ (r & 7)) * 8)];
      const f16x8 kf1 = *(const f16x8*)&sK[grp][cur][r * 64 + (((4 + quad) ^ (r & 7)) * 8)];
#pragma unroll
      for (int st = 0; st < 2; ++st) {
        f32x4 z = MFMA32(kf1, aq[st][1], MFMA32(kf0, aq[st][0], zc));
#pragma unroll
        for (int j = 0; j < 4; ++j)
          pA[st][nt >> 1][(nt & 1) * 4 + j] = (f16)exp2f(z[j]);
      }
    }

    __builtin_amdgcn_s_setprio(1);
#pragma unroll
    for (int st = 0; st < 2; ++st) {
      racc[st] = MFMA32(pA[st][0], onesv, racc[st]);
      racc[st] = MFMA32(pA[st][1], onesv, racc[st]);
    }
#pragma unroll
    for (int dt = 0; dt < 4; ++dt) {
      const int row = dt * 16 + ln;  // d row
#pragma unroll
      for (int nt2 = 0; nt2 < 2; ++nt2) {
        const f16x8 vf = *(const f16x8*)&sVT[grp][cur][row * 64 + (((quad * 2 + nt2) ^ (row & 7)) * 8)];
#pragma unroll
        for (int st = 0; st < 2; ++st)
          O[st][dt] = MFMA32(pA[st][nt2], vf, O[st][dt]);
      }
    }
    __builtin_amdgcn_s_setprio(0);

    if (t < 15) stageKV(cur ^ 1);  // vmcnt wait lands here, after compute
    __syncthreads();
  }

  // ---- combine the two kt-halves through the (now dead) staging LDS ----
  float* cO = (float*)&sK[0][0][0];   // 128 q x 64 d f32 = 32 KB (all of sK)
  float* cR = (float*)&sVT[0][0][0];  // 128 f32
  if (grp == 1) {
#pragma unroll
    for (int st = 0; st < 2; ++st) {
#pragma unroll
      for (int rg = 0; rg < 4; ++rg) {
        const int ql = wl * 32 + st * 16 + quad * 4 + rg;
#pragma unroll
        for (int dt = 0; dt < 4; ++dt) cO[ql * 64 + dt * 16 + ln] = O[st][dt][rg];
        if (ln == 0) cR[ql] = racc[st][rg];
      }
    }
  }
  __syncthreads();
  if (grp == 0) {
#pragma unroll
    for (int st = 0; st < 2; ++st) {
#pragma unroll
      for (int rg = 0; rg < 4; ++rg) {
        const int ql = wl * 32 + st * 16 + quad * 4 + rg;
        const float inv = 1.0f / (racc[st][rg] + cR[ql]);
        const int q = q0 + ql;
        const size_t orow = ((size_t)b * Ls + q) * DIM + h * HD;
#pragma unroll
        for (int dt = 0; dt < 4; ++dt)
          ao[orow + dt * 16 + ln] = (f16)((O[st][dt][rg] + cO[ql * 64 + dt * 16 + ln]) * inv);
      }
    }
  }
}

// ============ proj GEMM: 64x128 tile, BK=32, glLDS double-buffer, 1 barrier/iter ============
__global__ __launch_bounds__(256) void proj_gemm_kernel(
    const f16* __restrict__ A, const f16* __restrict__ W, float* __restrict__ out) {
  constexpr int K = DIM;
  __shared__ alignas(16) f16 sA[2][64 * 32];
  __shared__ alignas(16) f16 sB[2][128 * 32];
  const int tid = threadIdx.x;
  const int w = tid >> 6, lane = tid & 63, ln = lane & 15, quad = lane >> 4;
  const int wm = w >> 1, wn = w & 1;  // wave: 32 rows x 64 cols
  const int m0 = blockIdx.y * 64, n0 = blockIdx.x * 128;

  const f16* gA;  // 256 chunks: 1 per thread
  {
    int p = tid >> 3, g = (tid & 7) ^ (p & 7);
    gA = A + (size_t)(m0 + 2 * p + (g >> 2)) * K + (g & 3) * 8;
  }
  const f16* gB[2];
#pragma unroll
  for (int s = 0; s < 2; ++s) {
    int lc = tid + s * 256;
    int p = lc >> 3, g = (lc & 7) ^ (p & 7);
    gB[s] = W + (size_t)(n0 + 2 * p + (g >> 2)) * K + (g & 3) * 8;
  }

  auto issue = [&](int k0, int buf) {
    async16(&sA[buf][tid * 8], gA + k0);
#pragma unroll
    for (int s = 0; s < 2; ++s) async16(&sB[buf][(tid + s * 256) * 8], gB[s] + k0);
  };

  f32x4 acc[2][4] = {};

  issue(0, 0);
  __syncthreads();

  for (int it = 0; it < 32; ++it) {
    const int cur = it & 1;
    if (it < 31) issue((it + 1) * 32, cur ^ 1);
    f16x8 a[2];
#pragma unroll
    for (int mi = 0; mi < 2; ++mi)
      a[mi] = *(const f16x8*)&sA[cur][sw32(wm * 32 + mi * 16 + ln, quad)];
#pragma unroll
    for (int ni = 0; ni < 4; ++ni) {
      f16x8 b = *(const f16x8*)&sB[cur][sw32(wn * 64 + ni * 16 + ln, quad)];
#pragma unroll
      for (int mi = 0; mi < 2; ++mi) acc[mi][ni] = MFMA32(a[mi], b, acc[mi][ni]);
    }
    __syncthreads();
  }

#pragma unroll
  for (int mi = 0; mi < 2; ++mi) {
#pragma unroll
    for (int rg = 0; rg < 4; ++rg) {
      int row = m0 + wm * 32 + mi * 16 + quad * 4 + rg;
      size_t o = (size_t)row * DIM + n0 + wn * 64;
#pragma unroll
      for (int ni = 0; ni < 4; ++ni) out[o + ni * 16 + ln] = acc[mi][ni][rg];
    }
  }
}

extern "C" void kernel_launch(void* const* d_in, const int* in_sizes, int n_in,
                              void* d_out, int out_size, void* d_ws, size_t ws_size,
                              hipStream_t stream) {
  (void)in_sizes; (void)n_in; (void)out_size; (void)ws_size;
  const float* x = (const float*)d_in[0];
  const float* v0 = (const float*)d_in[1];
  const float* rcos = (const float*)d_in[2];
  const float* rsin = (const float*)d_in[3];
  const float* wqkv = (const float*)d_in[4];
  const float* wproj = (const float*)d_in[5];
  const float* lamp = (const float*)d_in[6];
  float* out = (float*)d_out;
  float* vout = out + (size_t)BL * DIM;  // output #1: blended v, (B,H,L,HD)

  char* p = (char*)d_ws;
  auto take = [&](size_t n) { char* q = p; p += ((n + 255) / 256) * 256; return q; };
  f16* xf = (f16*)take((size_t)BL * DIM * 2);
  f16* wqf = (f16*)take((size_t)3 * DIM * DIM * 2);
  f16* wpf = (f16*)take((size_t)DIM * DIM * 2);
  f16* qb = (f16*)take((size_t)BL * DIM * 2);
  f16* kb = (f16*)take((size_t)BL * DIM * 2);
  f16* vbT = (f16*)take((size_t)BL * DIM * 2);  // (b,h,d, key-permuted l)
  f16* ao = xf;  // x dead after qkv_gemm; reuse (stream-ordered)

  constexpr int NCVT4 = (BL * DIM + 3 * DIM * DIM + DIM * DIM) / 4;
  cvt_all_kernel<<<dim3(NCVT4 / 256), dim3(256), 0, stream>>>(x, wqkv, wproj, xf, wqf, wpf);

  qkv_gemm_kernel<<<dim3(3 * DIM / 128 * (BL / 128)), dim3(256), 0, stream>>>(
      xf, wqf, v0, rcos, rsin, lamp, qb, kb, vbT, vout);

  flash_kernel<<<dim3(Bs * NH * (Ls / 128)), dim3(512), 0, stream>>>(qb, kb, vbT, ao);

  proj_gemm_kernel<<<dim3(DIM / 128, BL / 64), dim3(256), 0, stream>>>(ao, wpf, out);
}

// Round 6
// 224.269 us; speedup vs baseline: 1.0857x; 1.0329x over previous
//
#include <hip/hip_runtime.h>

typedef _Float16 f16;
typedef _Float16 f16x8 __attribute__((ext_vector_type(8)));
typedef _Float16 f16x4 __attribute__((ext_vector_type(4)));
typedef float f32x4 __attribute__((ext_vector_type(4)));

#define MFMA32(a, b, c) __builtin_amdgcn_mfma_f32_16x16x32_f16((a), (b), (c), 0, 0, 0)

constexpr int Bs = 2, Ls = 2048, DIM = 1024, NH = 16, HD = 64;
constexpr int BL = Bs * Ls;  // 4096
constexpr float EPSV = 1e-6f;
constexpr float SCL2 = 0.125f * 1.44269504f;  // (1/sqrt(64)) * log2(e); folded into q

// async global->LDS, 16B per lane. LDS dest = wave-uniform base + lane*16.
__device__ __forceinline__ void async16(void* lds, const void* g) {
  __builtin_amdgcn_global_load_lds((const __attribute__((address_space(1))) void*)g,
                                   (__attribute__((address_space(3))) void*)lds, 16, 0, 0);
}

// BK=32 pair-XOR swizzle: rows are 64B (4 chunks); swizzle unit = row PAIR (8 chunks).
// LDS linear chunk lc <-> (pair p = lc>>3, phys ph = lc&7); global chunk g = ph ^ (p&7),
// global (row, colElems) = (2p + (g>>2), (g&3)*8). Frag read of (row r, kchunk q):
// addr elems = (r>>1)*64 + (((r&1)*4 + q) ^ ((r>>1)&7))*8.  Banks: 2-way (free).
__device__ __forceinline__ int sw32(int r, int q) {
  int p = r >> 1;
  return p * 64 + ((((r & 1) * 4 + q) ^ (p & 7)) * 8);
}

// ---------------- fp32 -> fp16 convert, all three tensors in one launch ----------------
__global__ void cvt_all_kernel(const float* __restrict__ x, const float* __restrict__ wq,
                               const float* __restrict__ wp, f16* __restrict__ xf,
                               f16* __restrict__ wqf, f16* __restrict__ wpf) {
  constexpr int NX4 = BL * DIM / 4;
  constexpr int NW4 = 3 * DIM * DIM / 4;
  int i = blockIdx.x * blockDim.x + threadIdx.x;
  const float4* src;
  f16x4* dst;
  int j;
  if (i < NX4) {
    src = (const float4*)x; dst = (f16x4*)xf; j = i;
  } else if (i < NX4 + NW4) {
    src = (const float4*)wq; dst = (f16x4*)wqf; j = i - NX4;
  } else {
    src = (const float4*)wp; dst = (f16x4*)wpf; j = i - NX4 - NW4;
  }
  float4 a = src[j];
  f16x4 o = {(f16)a.x, (f16)a.y, (f16)a.z, (f16)a.w};
  dst[j] = o;
}

// ============ QKV GEMM: 128x128 tile, BK=32, glLDS DOUBLE-buffer, 1 barrier/iter ============
// Both operands f16 via global_load_lds (no VALU in staging path). Per iter: issue next
// tile's 4 glLDS into buf^1 BEFORE reading/computing buf -> the barrier's vmcnt drain lands
// after the MFMA phase instead of cold. Linear 2D grid (n-fastest) — measured lower HBM
// fetch than XCD-chunked remap (51.6 vs 63.2 MB, r1 vs r3). Counted-vmcnt multi-buffer
// variant (r4) raced (output-1 fail) — reverted to this verified structure.
// v-epilogue: transpose through dead LDS -> coalesced 8B vbT stores.
__global__ __launch_bounds__(256) void qkv_gemm_kernel(
    const f16* __restrict__ A, const f16* __restrict__ W,
    const float* __restrict__ v0,
    const float* __restrict__ rcos, const float* __restrict__ rsin,
    const float* __restrict__ lamp,
    f16* __restrict__ qb, f16* __restrict__ kb, f16* __restrict__ vbT,
    float* __restrict__ vout) {
  constexpr int K = DIM;
  __shared__ alignas(16) f16 sm[4][128 * 32];  // [0,1]=A dbuf, [2,3]=B dbuf; 32KB
  const int tid = threadIdx.x;
  const int w = tid >> 6, lane = tid & 63, ln = lane & 15, quad = lane >> 4;
  const int wm = w >> 1, wn = w & 1;
  const int m0 = blockIdx.y * 128, n0 = blockIdx.x * 128;

  const f16* gA[2];
  const f16* gB[2];
#pragma unroll
  for (int s = 0; s < 2; ++s) {
    int lc = tid + s * 256;
    int p = lc >> 3, g = (lc & 7) ^ (p & 7);
    int r = 2 * p + (g >> 2), ce = (g & 3) * 8;
    gA[s] = A + (size_t)(m0 + r) * K + ce;
    gB[s] = W + (size_t)(n0 + r) * K + ce;
  }

  auto issue = [&](int k0, int buf) {
#pragma unroll
    for (int s = 0; s < 2; ++s) {
      async16(&sm[buf][(tid + s * 256) * 8], gA[s] + k0);
      async16(&sm[2 + buf][(tid + s * 256) * 8], gB[s] + k0);
    }
  };

  f32x4 acc[4][4] = {};

  issue(0, 0);
  __syncthreads();  // drain prologue loads

  for (int it = 0; it < 32; ++it) {
    const int cur = it & 1;
    if (it < 31) issue((it + 1) * 32, cur ^ 1);  // in flight across compute
    f16x8 a[4];
#pragma unroll
    for (int mi = 0; mi < 4; ++mi)
      a[mi] = *(const f16x8*)&sm[cur][sw32(wm * 64 + mi * 16 + ln, quad)];
#pragma unroll
    for (int ni = 0; ni < 4; ++ni) {
      f16x8 b = *(const f16x8*)&sm[2 + cur][sw32(wn * 64 + ni * 16 + ln, quad)];
#pragma unroll
      for (int mi = 0; mi < 4; ++mi) acc[mi][ni] = MFMA32(a[mi], b, acc[mi][ni]);
    }
    __syncthreads();  // drains next-buf loads + protects cur for overwrite at it+1
  }

  // Epilogue. Wave covers one head (64 cols). C/D: col=ln (ni tile), row=quad*4+rg (mi tile).
  const int nb = n0 + wn * 64;
  const int nsec = nb >> 10;        // 0=q, 1=k, 2=v  (per-wave)
  const int h = (nb & 1023) >> 6;   // head

  if (nsec == 2) {
    const float lam = lamp[0];
    const int l064 = m0 + wm * 64;           // 64-aligned key-group base (global row)
    const int b = l064 >> 11, l0 = l064 & 2047;
    const size_t vb = (size_t)(b * NH + h) * Ls * HD;
    f16* wT = &sm[0][0] + w * 4096;          // per-wave 8KB transpose tile [d][sidx]
#pragma unroll
    for (int mi = 0; mi < 4; ++mi) {
#pragma unroll
      for (int ni = 0; ni < 4; ++ni) {
        const int d = ni * 16 + ln;
        f16 pk[4];
#pragma unroll
        for (int rg = 0; rg < 4; ++rg) {
          const int kk = mi * 16 + quad * 4 + rg;
          const size_t base = vb + (size_t)(l0 + kk) * HD + d;
          float vnew = lam * acc[mi][ni][rg] + (1.0f - lam) * v0[base];
          vout[base] = vnew;  // fp32 output #1 (b,h,l,d), coalesced
          pk[rg] = (f16)vnew;
        }
        // sidx for kk = mi*16+quad*4+rg: quad*16 + mi*4 + rg (flash's key permutation)
        f16x4 q4 = {pk[0], pk[1], pk[2], pk[3]};
        const int sidx0 = quad * 16 + mi * 4;
        *(f16x4*)&wT[d * 64 + (sidx0 ^ ((d & 7) << 3))] = q4;
      }
    }
    // coalesced read-out (per-wave-private tile, no barrier needed)
    const size_t tB = (size_t)(b * NH + h) * HD * Ls + l0;
#pragma unroll
    for (int dd = 0; dd < 16; ++dd) {
      const int d = dd * 4 + quad;
      f16x4 vv = *(const f16x4*)&wT[d * 64 + ((ln * 4) ^ ((d & 7) << 3))];
      *(f16x4*)&vbT[tB + (size_t)d * Ls + ln * 4] = vv;
    }
  } else {
    f16* dst = nsec ? kb : qb;
    const float ratio = sqrtf(logf(2048.0f) / logf(1040.0f));
    const float post = nsec ? 1.0f : SCL2;  // fold softmax scale*log2e into q
#pragma unroll
    for (int mi = 0; mi < 4; ++mi) {
#pragma unroll
      for (int rg = 0; rg < 4; ++rg) {
        int row = m0 + wm * 64 + mi * 16 + quad * 4 + rg;
        int b = row >> 11, l = row & 2047;
        float vals[4];
#pragma unroll
        for (int ni = 0; ni < 4; ++ni) vals[ni] = acc[mi][ni][rg];
#pragma unroll
        for (int t = 0; t < 2; ++t) {
          int j = t * 16 + ln;
          float c = rcos[l * 32 + j], s = rsin[l * 32 + j];
          float x1 = vals[t], x2 = vals[t + 2];
          vals[t] = x1 * c + x2 * s;
          vals[t + 2] = -x1 * s + x2 * c;
        }
        if (nsec) {
#pragma unroll
          for (int ni = 0; ni < 4; ++ni) vals[ni] *= ratio;
        }
        float ms = vals[0] * vals[0] + vals[1] * vals[1] + vals[2] * vals[2] + vals[3] * vals[3];
        ms += __shfl_xor(ms, 1);
        ms += __shfl_xor(ms, 2);
        ms += __shfl_xor(ms, 4);
        ms += __shfl_xor(ms, 8);
        float rn = rsqrtf(ms * (1.0f / 64.0f) + EPSV) * post;
        size_t base = ((size_t)(b * NH + h) * Ls + l) * HD;
#pragma unroll
        for (int ni = 0; ni < 4; ++ni) dst[base + ni * 16 + ln] = (f16)(vals[ni] * rn);
      }
    }
  }
}

// ============ Flash attention: kt-split wave groups + all-MFMA32 + rsum-via-ones ============
__global__ __launch_bounds__(512, 4) void flash_kernel(
    const f16* __restrict__ qg, const f16* __restrict__ kg, const f16* __restrict__ vtg,
    f16* __restrict__ ao) {
  __shared__ alignas(16) f16 sK[2][2][64 * 64];   // [group][buf]
  __shared__ alignas(16) f16 sVT[2][2][64 * 64];  // [group][buf] [d][key-permuted]
  const int tid = threadIdx.x;
  const int w = tid >> 6, lane = tid & 63, ln = lane & 15, quad = lane >> 4;
  const int grp = w >> 2, wl = w & 3;  // kt-group, wave-in-group
  const int gt = tid & 255;            // thread id within group (staging)
  const int bx = blockIdx.x;
  const int bh = bx & 31, qt = bx >> 5;  // XCD-major: (b,h) fixed per bx%8 class
  const int h = bh & 15, b = bh >> 4;
  const f16* Qh = qg + (size_t)(b * NH + h) * Ls * HD;
  const f16* Kh = kg + (size_t)(b * NH + h) * Ls * HD;
  const f16* VTh = vtg + (size_t)(b * NH + h) * HD * Ls;
  const int q0 = qt * 128;

  // Q as B-frags straight from global: lane n=ln (q-col), k = kk*32 + quad*8 + j
  f16x8 aq[2][2];
#pragma unroll
  for (int st = 0; st < 2; ++st)
#pragma unroll
    for (int kk = 0; kk < 2; ++kk)
      aq[st][kk] = *(const f16x8*)&Qh[(size_t)(q0 + wl * 32 + st * 16 + ln) * HD + kk * 32 + quad * 8];

  f16x8 kr[2], vr[2];
  auto loadKV = [&](int k0) {
#pragma unroll
    for (int s = 0; s < 2; ++s) {
      int ch = gt + s * 256, r = ch >> 3, cg = (ch & 7) * 8;
      kr[s] = *(const f16x8*)&Kh[(size_t)(k0 + r) * HD + cg];
      vr[s] = *(const f16x8*)&VTh[(size_t)r * Ls + k0 + cg];
    }
  };
  auto stageKV = [&](int buf) {
#pragma unroll
    for (int s = 0; s < 2; ++s) {
      int ch = gt + s * 256, r = ch >> 3;
      int po = r * 64 + (((ch & 7) ^ (r & 7)) * 8);
      *(f16x8*)&sK[grp][buf][po] = kr[s];
      *(f16x8*)&sVT[grp][buf][po] = vr[s];
    }
  };

  f32x4 O[2][4] = {};
  f32x4 racc[2] = {};
  const f16x8 onesv = {(f16)1.f, (f16)1.f, (f16)1.f, (f16)1.f,
                       (f16)1.f, (f16)1.f, (f16)1.f, (f16)1.f};
  const f32x4 zc = {};

  const int kbase = grp << 10;  // group key offset
  loadKV(kbase);
  stageKV(0);
  __syncthreads();

  for (int t = 0; t < 16; ++t) {
    const int cur = t & 1;
    if (t < 15) loadKV(kbase + (t + 1) * 64);  // global->reg prefetch across compute

    // S^T + exp in registers -> merged PV A-frags (f16x8 = two 16-key tiles)
    f16x8 pA[2][2];
#pragma unroll
    for (int nt = 0; nt < 4; ++nt) {
      const int r = nt * 16 + ln;  // key row
      const f16x8 kf0 = *(const f16x8*)&sK[grp][cur][r * 64 + ((quad ^ (r & 7)) * 8)];
      const f16x8 kf1 = *(const f16x8*)&sK[grp][cur][r * 64 + (((4 + quad) ^ (r & 7)) * 8)];
#pragma unroll
      for (int st = 0; st < 2; ++st) {
        f32x4 z = MFMA32(kf1, aq[st][1], MFMA32(kf0, aq[st][0], zc));
#pragma unroll
        for (int j = 0; j < 4; ++j)
          pA[st][nt >> 1][(nt & 1) * 4 + j] = (f16)exp2f(z[j]);
      }
    }

    __builtin_amdgcn_s_setprio(1);
#pragma unroll
    for (int st = 0; st < 2; ++st) {
      racc[st] = MFMA32(pA[st][0], onesv, racc[st]);
      racc[st] = MFMA32(pA[st][1], onesv, racc[st]);
    }
#pragma unroll
    for (int dt = 0; dt < 4; ++dt) {
      const int row = dt * 16 + ln;  // d row
#pragma unroll
      for (int nt2 = 0; nt2 < 2; ++nt2) {
        const f16x8 vf = *(const f16x8*)&sVT[grp][cur][row * 64 + (((quad * 2 + nt2) ^ (row & 7)) * 8)];
#pragma unroll
        for (int st = 0; st < 2; ++st)
          O[st][dt] = MFMA32(pA[st][nt2], vf, O[st][dt]);
      }
    }
    __builtin_amdgcn_s_setprio(0);

    if (t < 15) stageKV(cur ^ 1);  // vmcnt wait lands here, after compute
    __syncthreads();
  }

  // ---- combine the two kt-halves through the (now dead) staging LDS ----
  float* cO = (float*)&sK[0][0][0];   // 128 q x 64 d f32 = 32 KB (all of sK)
  float* cR = (float*)&sVT[0][0][0];  // 128 f32
  if (grp == 1) {
#pragma unroll
    for (int st = 0; st < 2; ++st) {
#pragma unroll
      for (int rg = 0; rg < 4; ++rg) {
        const int ql = wl * 32 + st * 16 + quad * 4 + rg;
#pragma unroll
        for (int dt = 0; dt < 4; ++dt) cO[ql * 64 + dt * 16 + ln] = O[st][dt][rg];
        if (ln == 0) cR[ql] = racc[st][rg];
      }
    }
  }
  __syncthreads();
  if (grp == 0) {
#pragma unroll
    for (int st = 0; st < 2; ++st) {
#pragma unroll
      for (int rg = 0; rg < 4; ++rg) {
        const int ql = wl * 32 + st * 16 + quad * 4 + rg;
        const float inv = 1.0f / (racc[st][rg] + cR[ql]);
        const int q = q0 + ql;
        const size_t orow = ((size_t)b * Ls + q) * DIM + h * HD;
#pragma unroll
        for (int dt = 0; dt < 4; ++dt)
          ao[orow + dt * 16 + ln] = (f16)((O[st][dt][rg] + cO[ql * 64 + dt * 16 + ln]) * inv);
      }
    }
  }
}

// ============ proj GEMM: 64x128 tile, BK=32, glLDS double-buffer, 1 barrier/iter ============
__global__ __launch_bounds__(256) void proj_gemm_kernel(
    const f16* __restrict__ A, const f16* __restrict__ W, float* __restrict__ out) {
  constexpr int K = DIM;
  __shared__ alignas(16) f16 sA[2][64 * 32];
  __shared__ alignas(16) f16 sB[2][128 * 32];
  const int tid = threadIdx.x;
  const int w = tid >> 6, lane = tid & 63, ln = lane & 15, quad = lane >> 4;
  const int wm = w >> 1, wn = w & 1;  // wave: 32 rows x 64 cols
  const int m0 = blockIdx.y * 64, n0 = blockIdx.x * 128;

  const f16* gA;  // 256 chunks: 1 per thread
  {
    int p = tid >> 3, g = (tid & 7) ^ (p & 7);
    gA = A + (size_t)(m0 + 2 * p + (g >> 2)) * K + (g & 3) * 8;
  }
  const f16* gB[2];
#pragma unroll
  for (int s = 0; s < 2; ++s) {
    int lc = tid + s * 256;
    int p = lc >> 3, g = (lc & 7) ^ (p & 7);
    gB[s] = W + (size_t)(n0 + 2 * p + (g >> 2)) * K + (g & 3) * 8;
  }

  auto issue = [&](int k0, int buf) {
    async16(&sA[buf][tid * 8], gA + k0);
#pragma unroll
    for (int s = 0; s < 2; ++s) async16(&sB[buf][(tid + s * 256) * 8], gB[s] + k0);
  };

  f32x4 acc[2][4] = {};

  issue(0, 0);
  __syncthreads();

  for (int it = 0; it < 32; ++it) {
    const int cur = it & 1;
    if (it < 31) issue((it + 1) * 32, cur ^ 1);
    f16x8 a[2];
#pragma unroll
    for (int mi = 0; mi < 2; ++mi)
      a[mi] = *(const f16x8*)&sA[cur][sw32(wm * 32 + mi * 16 + ln, quad)];
#pragma unroll
    for (int ni = 0; ni < 4; ++ni) {
      f16x8 b = *(const f16x8*)&sB[cur][sw32(wn * 64 + ni * 16 + ln, quad)];
#pragma unroll
      for (int mi = 0; mi < 2; ++mi) acc[mi][ni] = MFMA32(a[mi], b, acc[mi][ni]);
    }
    __syncthreads();
  }

#pragma unroll
  for (int mi = 0; mi < 2; ++mi) {
#pragma unroll
    for (int rg = 0; rg < 4; ++rg) {
      int row = m0 + wm * 32 + mi * 16 + quad * 4 + rg;
      size_t o = (size_t)row * DIM + n0 + wn * 64;
#pragma unroll
      for (int ni = 0; ni < 4; ++ni) out[o + ni * 16 + ln] = acc[mi][ni][rg];
    }
  }
}

extern "C" void kernel_launch(void* const* d_in, const int* in_sizes, int n_in,
                              void* d_out, int out_size, void* d_ws, size_t ws_size,
                              hipStream_t stream) {
  (void)in_sizes; (void)n_in; (void)out_size; (void)ws_size;
  const float* x = (const float*)d_in[0];
  const float* v0 = (const float*)d_in[1];
  const float* rcos = (const float*)d_in[2];
  const float* rsin = (const float*)d_in[3];
  const float* wqkv = (const float*)d_in[4];
  const float* wproj = (const float*)d_in[5];
  const float* lamp = (const float*)d_in[6];
  float* out = (float*)d_out;
  float* vout = out + (size_t)BL * DIM;  // output #1: blended v, (B,H,L,HD)

  char* p = (char*)d_ws;
  auto take = [&](size_t n) { char* q = p; p += ((n + 255) / 256) * 256; return q; };
  f16* xf = (f16*)take((size_t)BL * DIM * 2);
  f16* wqf = (f16*)take((size_t)3 * DIM * DIM * 2);
  f16* wpf = (f16*)take((size_t)DIM * DIM * 2);
  f16* qb = (f16*)take((size_t)BL * DIM * 2);
  f16* kb = (f16*)take((size_t)BL * DIM * 2);
  f16* vbT = (f16*)take((size_t)BL * DIM * 2);  // (b,h,d, key-permuted l)
  f16* ao = xf;  // x dead after qkv_gemm; reuse (stream-ordered)

  constexpr int NCVT4 = (BL * DIM + 3 * DIM * DIM + DIM * DIM) / 4;
  cvt_all_kernel<<<dim3(NCVT4 / 256), dim3(256), 0, stream>>>(x, wqkv, wproj, xf, wqf, wpf);

  qkv_gemm_kernel<<<dim3(3 * DIM / 128, BL / 128), dim3(256), 0, stream>>>(
      xf, wqf, v0, rcos, rsin, lamp, qb, kb, vbT, vout);

  flash_kernel<<<dim3(Bs * NH * (Ls / 128)), dim3(512), 0, stream>>>(qb, kb, vbT, ao);

  proj_gemm_kernel<<<dim3(DIM / 128, BL / 64), dim3(256), 0, stream>>>(ao, wpf, out);
}

// Round 8
// 222.613 us; speedup vs baseline: 1.0938x; 1.0074x over previous
//
#include <hip/hip_runtime.h>

typedef _Float16 f16;
typedef _Float16 f16x8 __attribute__((ext_vector_type(8)));
typedef _Float16 f16x4 __attribute__((ext_vector_type(4)));
typedef float f32x4 __attribute__((ext_vector_type(4)));

#define MFMA32(a, b, c) __builtin_amdgcn_mfma_f32_16x16x32_f16((a), (b), (c), 0, 0, 0)

constexpr int Bs = 2, Ls = 2048, DIM = 1024, NH = 16, HD = 64;
constexpr int BL = Bs * Ls;  // 4096
constexpr float EPSV = 1e-6f;
constexpr float SCL2 = 0.125f * 1.44269504f;  // (1/sqrt(64)) * log2(e); folded into q

// async global->LDS, 16B per lane. LDS dest = wave-uniform base + lane*16.
__device__ __forceinline__ void async16(void* lds, const void* g) {
  __builtin_amdgcn_global_load_lds((const __attribute__((address_space(1))) void*)g,
                                   (__attribute__((address_space(3))) void*)lds, 16, 0, 0);
}

// BK=32 pair-XOR swizzle: rows are 64B (4 chunks); swizzle unit = row PAIR (8 chunks).
// LDS linear chunk lc <-> (pair p = lc>>3, phys ph = lc&7); global chunk g = ph ^ (p&7),
// global (row, colElems) = (2p + (g>>2), (g&3)*8). Frag read of (row r, kchunk q):
// addr elems = (r>>1)*64 + (((r&1)*4 + q) ^ ((r>>1)&7))*8.  Banks: 2-way (free).
__device__ __forceinline__ int sw32(int r, int q) {
  int p = r >> 1;
  return p * 64 + ((((r & 1) * 4 + q) ^ (p & 7)) * 8);
}

// ---------------- fp32 -> fp16 convert, all three tensors in one launch ----------------
// fp32 sources are never read again -> nontemporal loads keep them out of L2 (protects
// W/A/KV residency for the downstream kernels). Converted outputs stay cached (re-read soon).
// NOTE: nontemporal builtins need clang ext-vector types (f32x4), not HIP_vector_type float4.
__global__ void cvt_all_kernel(const float* __restrict__ x, const float* __restrict__ wq,
                               const float* __restrict__ wp, f16* __restrict__ xf,
                               f16* __restrict__ wqf, f16* __restrict__ wpf) {
  constexpr int NX4 = BL * DIM / 4;
  constexpr int NW4 = 3 * DIM * DIM / 4;
  int i = blockIdx.x * blockDim.x + threadIdx.x;
  const f32x4* src;
  f16x4* dst;
  int j;
  if (i < NX4) {
    src = (const f32x4*)x; dst = (f16x4*)xf; j = i;
  } else if (i < NX4 + NW4) {
    src = (const f32x4*)wq; dst = (f16x4*)wqf; j = i - NX4;
  } else {
    src = (const f32x4*)wp; dst = (f16x4*)wpf; j = i - NX4 - NW4;
  }
  f32x4 a = __builtin_nontemporal_load(&src[j]);
  f16x4 o = {(f16)a[0], (f16)a[1], (f16)a[2], (f16)a[3]};
  dst[j] = o;
}

// ============ QKV GEMM: 128x128 tile, BK=32, glLDS DOUBLE-buffer, 1 barrier/iter ============
// Both operands f16 via global_load_lds. Per iter: issue next tile's 4 glLDS into buf^1
// BEFORE reading/computing buf -> the barrier's vmcnt drain lands after the MFMA phase.
// K-loop fully unrolled: global addrs become base+const (backend folds into offset: imm),
// buffer selects constant-fold -> per-iter address VALU ~0 (r6: VALUBusy 31%).
// Linear 2D grid (n-fastest): measured lower HBM fetch than XCD-chunked remap (51.6 vs
// 63.2 MB). Counted-vmcnt (r4) raced — parked. v0 read-once -> nontemporal load; vout is a
// final output -> nontemporal store (kills ~16MB read-for-ownership seen in FETCH_SIZE).
// v-epilogue: transpose through dead LDS -> coalesced 8B vbT stores.
__global__ __launch_bounds__(256) void qkv_gemm_kernel(
    const f16* __restrict__ A, const f16* __restrict__ W,
    const float* __restrict__ v0,
    const float* __restrict__ rcos, const float* __restrict__ rsin,
    const float* __restrict__ lamp,
    f16* __restrict__ qb, f16* __restrict__ kb, f16* __restrict__ vbT,
    float* __restrict__ vout) {
  constexpr int K = DIM;
  __shared__ alignas(16) f16 sm[4][128 * 32];  // [0,1]=A dbuf, [2,3]=B dbuf; 32KB
  const int tid = threadIdx.x;
  const int w = tid >> 6, lane = tid & 63, ln = lane & 15, quad = lane >> 4;
  const int wm = w >> 1, wn = w & 1;
  const int m0 = blockIdx.y * 128, n0 = blockIdx.x * 128;

  const f16* gA[2];
  const f16* gB[2];
#pragma unroll
  for (int s = 0; s < 2; ++s) {
    int lc = tid + s * 256;
    int p = lc >> 3, g = (lc & 7) ^ (p & 7);
    int r = 2 * p + (g >> 2), ce = (g & 3) * 8;
    gA[s] = A + (size_t)(m0 + r) * K + ce;
    gB[s] = W + (size_t)(n0 + r) * K + ce;
  }

  auto issue = [&](int k0, int buf) {
#pragma unroll
    for (int s = 0; s < 2; ++s) {
      async16(&sm[buf][(tid + s * 256) * 8], gA[s] + k0);
      async16(&sm[2 + buf][(tid + s * 256) * 8], gB[s] + k0);
    }
  };

  f32x4 acc[4][4] = {};

  issue(0, 0);
  __syncthreads();  // drain prologue loads

#pragma unroll
  for (int it = 0; it < 32; ++it) {
    const int cur = it & 1;
    if (it < 31) issue((it + 1) * 32, cur ^ 1);  // in flight across compute
    f16x8 a[4];
#pragma unroll
    for (int mi = 0; mi < 4; ++mi)
      a[mi] = *(const f16x8*)&sm[cur][sw32(wm * 64 + mi * 16 + ln, quad)];
#pragma unroll
    for (int ni = 0; ni < 4; ++ni) {
      f16x8 b = *(const f16x8*)&sm[2 + cur][sw32(wn * 64 + ni * 16 + ln, quad)];
#pragma unroll
      for (int mi = 0; mi < 4; ++mi) acc[mi][ni] = MFMA32(a[mi], b, acc[mi][ni]);
    }
    __syncthreads();  // drains next-buf loads + protects cur for overwrite at it+1
  }

  // Epilogue. Wave covers one head (64 cols). C/D: col=ln (ni tile), row=quad*4+rg (mi tile).
  const int nb = n0 + wn * 64;
  const int nsec = nb >> 10;        // 0=q, 1=k, 2=v  (per-wave)
  const int h = (nb & 1023) >> 6;   // head

  if (nsec == 2) {
    const float lam = lamp[0];
    const int l064 = m0 + wm * 64;           // 64-aligned key-group base (global row)
    const int b = l064 >> 11, l0 = l064 & 2047;
    const size_t vb = (size_t)(b * NH + h) * Ls * HD;
    f16* wT = &sm[0][0] + w * 4096;          // per-wave 8KB transpose tile [d][sidx]
#pragma unroll
    for (int mi = 0; mi < 4; ++mi) {
#pragma unroll
      for (int ni = 0; ni < 4; ++ni) {
        const int d = ni * 16 + ln;
        f16 pk[4];
#pragma unroll
        for (int rg = 0; rg < 4; ++rg) {
          const int kk = mi * 16 + quad * 4 + rg;
          const size_t base = vb + (size_t)(l0 + kk) * HD + d;
          float vnew = lam * acc[mi][ni][rg] + (1.0f - lam) * __builtin_nontemporal_load(&v0[base]);
          __builtin_nontemporal_store(vnew, &vout[base]);  // final output, no RFO
          pk[rg] = (f16)vnew;
        }
        // sidx for kk = mi*16+quad*4+rg: quad*16 + mi*4 + rg (flash's key permutation)
        f16x4 q4 = {pk[0], pk[1], pk[2], pk[3]};
        const int sidx0 = quad * 16 + mi * 4;
        *(f16x4*)&wT[d * 64 + (sidx0 ^ ((d & 7) << 3))] = q4;
      }
    }
    // coalesced read-out (per-wave-private tile, no barrier needed)
    const size_t tB = (size_t)(b * NH + h) * HD * Ls + l0;
#pragma unroll
    for (int dd = 0; dd < 16; ++dd) {
      const int d = dd * 4 + quad;
      f16x4 vv = *(const f16x4*)&wT[d * 64 + ((ln * 4) ^ ((d & 7) << 3))];
      *(f16x4*)&vbT[tB + (size_t)d * Ls + ln * 4] = vv;
    }
  } else {
    f16* dst = nsec ? kb : qb;
    const float ratio = sqrtf(logf(2048.0f) / logf(1040.0f));
    const float post = nsec ? 1.0f : SCL2;  // fold softmax scale*log2e into q
#pragma unroll
    for (int mi = 0; mi < 4; ++mi) {
#pragma unroll
      for (int rg = 0; rg < 4; ++rg) {
        int row = m0 + wm * 64 + mi * 16 + quad * 4 + rg;
        int b = row >> 11, l = row & 2047;
        float vals[4];
#pragma unroll
        for (int ni = 0; ni < 4; ++ni) vals[ni] = acc[mi][ni][rg];
#pragma unroll
        for (int t = 0; t < 2; ++t) {
          int j = t * 16 + ln;
          float c = rcos[l * 32 + j], s = rsin[l * 32 + j];
          float x1 = vals[t], x2 = vals[t + 2];
          vals[t] = x1 * c + x2 * s;
          vals[t + 2] = -x1 * s + x2 * c;
        }
        if (nsec) {
#pragma unroll
          for (int ni = 0; ni < 4; ++ni) vals[ni] *= ratio;
        }
        float ms = vals[0] * vals[0] + vals[1] * vals[1] + vals[2] * vals[2] + vals[3] * vals[3];
        ms += __shfl_xor(ms, 1);
        ms += __shfl_xor(ms, 2);
        ms += __shfl_xor(ms, 4);
        ms += __shfl_xor(ms, 8);
        float rn = rsqrtf(ms * (1.0f / 64.0f) + EPSV) * post;
        size_t base = ((size_t)(b * NH + h) * Ls + l) * HD;
#pragma unroll
        for (int ni = 0; ni < 4; ++ni) dst[base + ni * 16 + ln] = (f16)(vals[ni] * rn);
      }
    }
  }
}

// ============ Flash attention: kt-split wave groups + all-MFMA32 + rsum-via-ones ============
__global__ __launch_bounds__(512, 4) void flash_kernel(
    const f16* __restrict__ qg, const f16* __restrict__ kg, const f16* __restrict__ vtg,
    f16* __restrict__ ao) {
  __shared__ alignas(16) f16 sK[2][2][64 * 64];   // [group][buf]
  __shared__ alignas(16) f16 sVT[2][2][64 * 64];  // [group][buf] [d][key-permuted]
  const int tid = threadIdx.x;
  const int w = tid >> 6, lane = tid & 63, ln = lane & 15, quad = lane >> 4;
  const int grp = w >> 2, wl = w & 3;  // kt-group, wave-in-group
  const int gt = tid & 255;            // thread id within group (staging)
  const int bx = blockIdx.x;
  const int bh = bx & 31, qt = bx >> 5;  // XCD-major: (b,h) fixed per bx%8 class
  const int h = bh & 15, b = bh >> 4;
  const f16* Qh = qg + (size_t)(b * NH + h) * Ls * HD;
  const f16* Kh = kg + (size_t)(b * NH + h) * Ls * HD;
  const f16* VTh = vtg + (size_t)(b * NH + h) * HD * Ls;
  const int q0 = qt * 128;

  // Q as B-frags straight from global: lane n=ln (q-col), k = kk*32 + quad*8 + j
  f16x8 aq[2][2];
#pragma unroll
  for (int st = 0; st < 2; ++st)
#pragma unroll
    for (int kk = 0; kk < 2; ++kk)
      aq[st][kk] = *(const f16x8*)&Qh[(size_t)(q0 + wl * 32 + st * 16 + ln) * HD + kk * 32 + quad * 8];

  f16x8 kr[2], vr[2];
  auto loadKV = [&](int k0) {
#pragma unroll
    for (int s = 0; s < 2; ++s) {
      int ch = gt + s * 256, r = ch >> 3, cg = (ch & 7) * 8;
      kr[s] = *(const f16x8*)&Kh[(size_t)(k0 + r) * HD + cg];
      vr[s] = *(const f16x8*)&VTh[(size_t)r * Ls + k0 + cg];
    }
  };
  auto stageKV = [&](int buf) {
#pragma unroll
    for (int s = 0; s < 2; ++s) {
      int ch = gt + s * 256, r = ch >> 3;
      int po = r * 64 + (((ch & 7) ^ (r & 7)) * 8);
      *(f16x8*)&sK[grp][buf][po] = kr[s];
      *(f16x8*)&sVT[grp][buf][po] = vr[s];
    }
  };

  f32x4 O[2][4] = {};
  f32x4 racc[2] = {};
  const f16x8 onesv = {(f16)1.f, (f16)1.f, (f16)1.f, (f16)1.f,
                       (f16)1.f, (f16)1.f, (f16)1.f, (f16)1.f};
  const f32x4 zc = {};

  const int kbase = grp << 10;  // group key offset
  loadKV(kbase);
  stageKV(0);
  __syncthreads();

  for (int t = 0; t < 16; ++t) {
    const int cur = t & 1;
    if (t < 15) loadKV(kbase + (t + 1) * 64);  // global->reg prefetch across compute

    // S^T + exp in registers -> merged PV A-frags (f16x8 = two 16-key tiles)
    f16x8 pA[2][2];
#pragma unroll
    for (int nt = 0; nt < 4; ++nt) {
      const int r = nt * 16 + ln;  // key row
      const f16x8 kf0 = *(const f16x8*)&sK[grp][cur][r * 64 + ((quad ^ (r & 7)) * 8)];
      const f16x8 kf1 = *(const f16x8*)&sK[grp][cur][r * 64 + (((4 + quad) ^ (r & 7)) * 8)];
#pragma unroll
      for (int st = 0; st < 2; ++st) {
        f32x4 z = MFMA32(kf1, aq[st][1], MFMA32(kf0, aq[st][0], zc));
#pragma unroll
        for (int j = 0; j < 4; ++j)
          pA[st][nt >> 1][(nt & 1) * 4 + j] = (f16)exp2f(z[j]);
      }
    }

    __builtin_amdgcn_s_setprio(1);
#pragma unroll
    for (int st = 0; st < 2; ++st) {
      racc[st] = MFMA32(pA[st][0], onesv, racc[st]);
      racc[st] = MFMA32(pA[st][1], onesv, racc[st]);
    }
#pragma unroll
    for (int dt = 0; dt < 4; ++dt) {
      const int row = dt * 16 + ln;  // d row
#pragma unroll
      for (int nt2 = 0; nt2 < 2; ++nt2) {
        const f16x8 vf = *(const f16x8*)&sVT[grp][cur][row * 64 + (((quad * 2 + nt2) ^ (row & 7)) * 8)];
#pragma unroll
        for (int st = 0; st < 2; ++st)
          O[st][dt] = MFMA32(pA[st][nt2], vf, O[st][dt]);
      }
    }
    __builtin_amdgcn_s_setprio(0);

    if (t < 15) stageKV(cur ^ 1);  // vmcnt wait lands here, after compute
    __syncthreads();
  }

  // ---- combine the two kt-halves through the (now dead) staging LDS ----
  float* cO = (float*)&sK[0][0][0];   // 128 q x 64 d f32 = 32 KB (all of sK)
  float* cR = (float*)&sVT[0][0][0];  // 128 f32
  if (grp == 1) {
#pragma unroll
    for (int st = 0; st < 2; ++st) {
#pragma unroll
      for (int rg = 0; rg < 4; ++rg) {
        const int ql = wl * 32 + st * 16 + quad * 4 + rg;
#pragma unroll
        for (int dt = 0; dt < 4; ++dt) cO[ql * 64 + dt * 16 + ln] = O[st][dt][rg];
        if (ln == 0) cR[ql] = racc[st][rg];
      }
    }
  }
  __syncthreads();
  if (grp == 0) {
#pragma unroll
    for (int st = 0; st < 2; ++st) {
#pragma unroll
      for (int rg = 0; rg < 4; ++rg) {
        const int ql = wl * 32 + st * 16 + quad * 4 + rg;
        const float inv = 1.0f / (racc[st][rg] + cR[ql]);
        const int q = q0 + ql;
        const size_t orow = ((size_t)b * Ls + q) * DIM + h * HD;
#pragma unroll
        for (int dt = 0; dt < 4; ++dt)
          ao[orow + dt * 16 + ln] = (f16)((O[st][dt][rg] + cO[ql * 64 + dt * 16 + ln]) * inv);
      }
    }
  }
}

// ============ proj GEMM: 64x128 tile, BK=32, glLDS double-buffer, 1 barrier/iter ============
// Same unroll + nt-store treatment as qkv (out is a final fp32 output -> no RFO).
__global__ __launch_bounds__(256) void proj_gemm_kernel(
    const f16* __restrict__ A, const f16* __restrict__ W, float* __restrict__ out) {
  constexpr int K = DIM;
  __shared__ alignas(16) f16 sA[2][64 * 32];
  __shared__ alignas(16) f16 sB[2][128 * 32];
  const int tid = threadIdx.x;
  const int w = tid >> 6, lane = tid & 63, ln = lane & 15, quad = lane >> 4;
  const int wm = w >> 1, wn = w & 1;  // wave: 32 rows x 64 cols
  const int m0 = blockIdx.y * 64, n0 = blockIdx.x * 128;

  const f16* gA;  // 256 chunks: 1 per thread
  {
    int p = tid >> 3, g = (tid & 7) ^ (p & 7);
    gA = A + (size_t)(m0 + 2 * p + (g >> 2)) * K + (g & 3) * 8;
  }
  const f16* gB[2];
#pragma unroll
  for (int s = 0; s < 2; ++s) {
    int lc = tid + s * 256;
    int p = lc >> 3, g = (lc & 7) ^ (p & 7);
    gB[s] = W + (size_t)(n0 + 2 * p + (g >> 2)) * K + (g & 3) * 8;
  }

  auto issue = [&](int k0, int buf) {
    async16(&sA[buf][tid * 8], gA + k0);
#pragma unroll
    for (int s = 0; s < 2; ++s) async16(&sB[buf][(tid + s * 256) * 8], gB[s] + k0);
  };

  f32x4 acc[2][4] = {};

  issue(0, 0);
  __syncthreads();

#pragma unroll
  for (int it = 0; it < 32; ++it) {
    const int cur = it & 1;
    if (it < 31) issue((it + 1) * 32, cur ^ 1);
    f16x8 a[2];
#pragma unroll
    for (int mi = 0; mi < 2; ++mi)
      a[mi] = *(const f16x8*)&sA[cur][sw32(wm * 32 + mi * 16 + ln, quad)];
#pragma unroll
    for (int ni = 0; ni < 4; ++ni) {
      f16x8 b = *(const f16x8*)&sB[cur][sw32(wn * 64 + ni * 16 + ln, quad)];
#pragma unroll
      for (int mi = 0; mi < 2; ++mi) acc[mi][ni] = MFMA32(a[mi], b, acc[mi][ni]);
    }
    __syncthreads();
  }

#pragma unroll
  for (int mi = 0; mi < 2; ++mi) {
#pragma unroll
    for (int rg = 0; rg < 4; ++rg) {
      int row = m0 + wm * 32 + mi * 16 + quad * 4 + rg;
      size_t o = (size_t)row * DIM + n0 + wn * 64;
#pragma unroll
      for (int ni = 0; ni < 4; ++ni)
        __builtin_nontemporal_store(acc[mi][ni][rg], &out[o + ni * 16 + ln]);
    }
  }
}

extern "C" void kernel_launch(void* const* d_in, const int* in_sizes, int n_in,
                              void* d_out, int out_size, void* d_ws, size_t ws_size,
                              hipStream_t stream) {
  (void)in_sizes; (void)n_in; (void)out_size; (void)ws_size;
  const float* x = (const float*)d_in[0];
  const float* v0 = (const float*)d_in[1];
  const float* rcos = (const float*)d_in[2];
  const float* rsin = (const float*)d_in[3];
  const float* wqkv = (const float*)d_in[4];
  const float* wproj = (const float*)d_in[5];
  const float* lamp = (const float*)d_in[6];
  float* out = (float*)d_out;
  float* vout = out + (size_t)BL * DIM;  // output #1: blended v, (B,H,L,HD)

  char* p = (char*)d_ws;
  auto take = [&](size_t n) { char* q = p; p += ((n + 255) / 256) * 256; return q; };
  f16* xf = (f16*)take((size_t)BL * DIM * 2);
  f16* wqf = (f16*)take((size_t)3 * DIM * DIM * 2);
  f16* wpf = (f16*)take((size_t)DIM * DIM * 2);
  f16* qb = (f16*)take((size_t)BL * DIM * 2);
  f16* kb = (f16*)take((size_t)BL * DIM * 2);
  f16* vbT = (f16*)take((size_t)BL * DIM * 2);  // (b,h,d, key-permuted l)
  f16* ao = xf;  // x dead after qkv_gemm; reuse (stream-ordered)

  constexpr int NCVT4 = (BL * DIM + 3 * DIM * DIM + DIM * DIM) / 4;
  cvt_all_kernel<<<dim3(NCVT4 / 256), dim3(256), 0, stream>>>(x, wqkv, wproj, xf, wqf, wpf);

  qkv_gemm_kernel<<<dim3(3 * DIM / 128, BL / 128), dim3(256), 0, stream>>>(
      xf, wqf, v0, rcos, rsin, lamp, qb, kb, vbT, vout);

  flash_kernel<<<dim3(Bs * NH * (Ls / 128)), dim3(512), 0, stream>>>(qb, kb, vbT, ao);

  proj_gemm_kernel<<<dim3(DIM / 128, BL / 64), dim3(256), 0, stream>>>(ao, wpf, out);
}

// Round 9
// 214.842 us; speedup vs baseline: 1.1334x; 1.0362x over previous
//
#include <hip/hip_runtime.h>

typedef _Float16 f16;
typedef _Float16 f16x8 __attribute__((ext_vector_type(8)));
typedef _Float16 f16x4 __attribute__((ext_vector_type(4)));
typedef float f32x4 __attribute__((ext_vector_type(4)));

#define MFMA32(a, b, c) __builtin_amdgcn_mfma_f32_16x16x32_f16((a), (b), (c), 0, 0, 0)

constexpr int Bs = 2, Ls = 2048, DIM = 1024, NH = 16, HD = 64;
constexpr int BL = Bs * Ls;  // 4096
constexpr float EPSV = 1e-6f;
constexpr float SCL2 = 0.125f * 1.44269504f;  // (1/sqrt(64)) * log2(e); folded into q

// Raw v_exp_f32 (2^x). Scores are RMS-normed, |x| small -> ocml's denorm/clamp fixup
// path (~3-4 insts each at plain -O3) is pure VALU waste; the bare instruction suffices.
__device__ __forceinline__ float fexp2(float x) {
#if __has_builtin(__builtin_amdgcn_exp2f)
  return __builtin_amdgcn_exp2f(x);
#else
  return exp2f(x);
#endif
}

// async global->LDS, 16B per lane. LDS dest = wave-uniform base + lane*16.
__device__ __forceinline__ void async16(void* lds, const void* g) {
  __builtin_amdgcn_global_load_lds((const __attribute__((address_space(1))) void*)g,
                                   (__attribute__((address_space(3))) void*)lds, 16, 0, 0);
}

// BK=32 pair-XOR swizzle: rows are 64B (4 chunks); swizzle unit = row PAIR (8 chunks).
// LDS linear chunk lc <-> (pair p = lc>>3, phys ph = lc&7); global chunk g = ph ^ (p&7),
// global (row, colElems) = (2p + (g>>2), (g&3)*8). Frag read of (row r, kchunk q):
// addr elems = (r>>1)*64 + (((r&1)*4 + q) ^ ((r>>1)&7))*8.  Banks: 2-way (free).
__device__ __forceinline__ int sw32(int r, int q) {
  int p = r >> 1;
  return p * 64 + ((((r & 1) * 4 + q) ^ (p & 7)) * 8);
}

// ---------------- fp32 -> fp16 convert, all three tensors in one launch ----------------
// fp32 sources are never read again -> nontemporal loads keep them out of L2 (protects
// W/A/KV residency for the downstream kernels). Converted outputs stay cached (re-read soon).
// NOTE: nontemporal builtins need clang ext-vector types (f32x4), not HIP_vector_type float4.
__global__ void cvt_all_kernel(const float* __restrict__ x, const float* __restrict__ wq,
                               const float* __restrict__ wp, f16* __restrict__ xf,
                               f16* __restrict__ wqf, f16* __restrict__ wpf) {
  constexpr int NX4 = BL * DIM / 4;
  constexpr int NW4 = 3 * DIM * DIM / 4;
  int i = blockIdx.x * blockDim.x + threadIdx.x;
  const f32x4* src;
  f16x4* dst;
  int j;
  if (i < NX4) {
    src = (const f32x4*)x; dst = (f16x4*)xf; j = i;
  } else if (i < NX4 + NW4) {
    src = (const f32x4*)wq; dst = (f16x4*)wqf; j = i - NX4;
  } else {
    src = (const f32x4*)wp; dst = (f16x4*)wpf; j = i - NX4 - NW4;
  }
  f32x4 a = __builtin_nontemporal_load(&src[j]);
  f16x4 o = {(f16)a[0], (f16)a[1], (f16)a[2], (f16)a[3]};
  dst[j] = o;
}

// ============ QKV GEMM: 128x128 tile, BK=32, glLDS DOUBLE-buffer, 1 barrier/iter ============
// Both operands f16 via global_load_lds. Per iter: issue next tile's 4 glLDS into buf^1
// BEFORE reading/computing buf -> the barrier's vmcnt drain lands after the MFMA phase.
// K-loop fully unrolled: global addrs become base+const, buffer selects constant-fold.
// Linear 2D grid (n-fastest): measured lower HBM fetch than XCD-chunked remap (51.6 vs
// 63.2 MB). Counted-vmcnt (r4) raced — parked. v0 read-once -> nontemporal load; vout is a
// final output -> nontemporal store (kills read-for-ownership traffic).
// v-epilogue: transpose through dead LDS -> coalesced 8B vbT stores.
__global__ __launch_bounds__(256) void qkv_gemm_kernel(
    const f16* __restrict__ A, const f16* __restrict__ W,
    const float* __restrict__ v0,
    const float* __restrict__ rcos, const float* __restrict__ rsin,
    const float* __restrict__ lamp,
    f16* __restrict__ qb, f16* __restrict__ kb, f16* __restrict__ vbT,
    float* __restrict__ vout) {
  constexpr int K = DIM;
  __shared__ alignas(16) f16 sm[4][128 * 32];  // [0,1]=A dbuf, [2,3]=B dbuf; 32KB
  const int tid = threadIdx.x;
  const int w = tid >> 6, lane = tid & 63, ln = lane & 15, quad = lane >> 4;
  const int wm = w >> 1, wn = w & 1;
  const int m0 = blockIdx.y * 128, n0 = blockIdx.x * 128;

  const f16* gA[2];
  const f16* gB[2];
#pragma unroll
  for (int s = 0; s < 2; ++s) {
    int lc = tid + s * 256;
    int p = lc >> 3, g = (lc & 7) ^ (p & 7);
    int r = 2 * p + (g >> 2), ce = (g & 3) * 8;
    gA[s] = A + (size_t)(m0 + r) * K + ce;
    gB[s] = W + (size_t)(n0 + r) * K + ce;
  }

  auto issue = [&](int k0, int buf) {
#pragma unroll
    for (int s = 0; s < 2; ++s) {
      async16(&sm[buf][(tid + s * 256) * 8], gA[s] + k0);
      async16(&sm[2 + buf][(tid + s * 256) * 8], gB[s] + k0);
    }
  };

  f32x4 acc[4][4] = {};

  issue(0, 0);
  __syncthreads();  // drain prologue loads

#pragma unroll
  for (int it = 0; it < 32; ++it) {
    const int cur = it & 1;
    if (it < 31) issue((it + 1) * 32, cur ^ 1);  // in flight across compute
    f16x8 a[4];
#pragma unroll
    for (int mi = 0; mi < 4; ++mi)
      a[mi] = *(const f16x8*)&sm[cur][sw32(wm * 64 + mi * 16 + ln, quad)];
#pragma unroll
    for (int ni = 0; ni < 4; ++ni) {
      f16x8 b = *(const f16x8*)&sm[2 + cur][sw32(wn * 64 + ni * 16 + ln, quad)];
#pragma unroll
      for (int mi = 0; mi < 4; ++mi) acc[mi][ni] = MFMA32(a[mi], b, acc[mi][ni]);
    }
    __syncthreads();  // drains next-buf loads + protects cur for overwrite at it+1
  }

  // Epilogue. Wave covers one head (64 cols). C/D: col=ln (ni tile), row=quad*4+rg (mi tile).
  const int nb = n0 + wn * 64;
  const int nsec = nb >> 10;        // 0=q, 1=k, 2=v  (per-wave)
  const int h = (nb & 1023) >> 6;   // head

  if (nsec == 2) {
    const float lam = lamp[0];
    const int l064 = m0 + wm * 64;           // 64-aligned key-group base (global row)
    const int b = l064 >> 11, l0 = l064 & 2047;
    const size_t vb = (size_t)(b * NH + h) * Ls * HD;
    f16* wT = &sm[0][0] + w * 4096;          // per-wave 8KB transpose tile [d][sidx]
#pragma unroll
    for (int mi = 0; mi < 4; ++mi) {
#pragma unroll
      for (int ni = 0; ni < 4; ++ni) {
        const int d = ni * 16 + ln;
        f16 pk[4];
#pragma unroll
        for (int rg = 0; rg < 4; ++rg) {
          const int kk = mi * 16 + quad * 4 + rg;
          const size_t base = vb + (size_t)(l0 + kk) * HD + d;
          float vnew = lam * acc[mi][ni][rg] + (1.0f - lam) * __builtin_nontemporal_load(&v0[base]);
          __builtin_nontemporal_store(vnew, &vout[base]);  // final output, no RFO
          pk[rg] = (f16)vnew;
        }
        // sidx for kk = mi*16+quad*4+rg: quad*16 + mi*4 + rg (flash's key permutation)
        f16x4 q4 = {pk[0], pk[1], pk[2], pk[3]};
        const int sidx0 = quad * 16 + mi * 4;
        *(f16x4*)&wT[d * 64 + (sidx0 ^ ((d & 7) << 3))] = q4;
      }
    }
    // coalesced read-out (per-wave-private tile, no barrier needed)
    const size_t tB = (size_t)(b * NH + h) * HD * Ls + l0;
#pragma unroll
    for (int dd = 0; dd < 16; ++dd) {
      const int d = dd * 4 + quad;
      f16x4 vv = *(const f16x4*)&wT[d * 64 + ((ln * 4) ^ ((d & 7) << 3))];
      *(f16x4*)&vbT[tB + (size_t)d * Ls + ln * 4] = vv;
    }
  } else {
    f16* dst = nsec ? kb : qb;
    const float ratio = sqrtf(logf(2048.0f) / logf(1040.0f));
    const float post = nsec ? 1.0f : SCL2;  // fold softmax scale*log2e into q
#pragma unroll
    for (int mi = 0; mi < 4; ++mi) {
#pragma unroll
      for (int rg = 0; rg < 4; ++rg) {
        int row = m0 + wm * 64 + mi * 16 + quad * 4 + rg;
        int b = row >> 11, l = row & 2047;
        float vals[4];
#pragma unroll
        for (int ni = 0; ni < 4; ++ni) vals[ni] = acc[mi][ni][rg];
#pragma unroll
        for (int t = 0; t < 2; ++t) {
          int j = t * 16 + ln;
          float c = rcos[l * 32 + j], s = rsin[l * 32 + j];
          float x1 = vals[t], x2 = vals[t + 2];
          vals[t] = x1 * c + x2 * s;
          vals[t + 2] = -x1 * s + x2 * c;
        }
        if (nsec) {
#pragma unroll
          for (int ni = 0; ni < 4; ++ni) vals[ni] *= ratio;
        }
        float ms = vals[0] * vals[0] + vals[1] * vals[1] + vals[2] * vals[2] + vals[3] * vals[3];
        ms += __shfl_xor(ms, 1);
        ms += __shfl_xor(ms, 2);
        ms += __shfl_xor(ms, 4);
        ms += __shfl_xor(ms, 8);
        float rn = rsqrtf(ms * (1.0f / 64.0f) + EPSV) * post;
        size_t base = ((size_t)(b * NH + h) * Ls + l) * HD;
#pragma unroll
        for (int ni = 0; ni < 4; ++ni) dst[base + ni * 16 + ln] = (f16)(vals[ni] * rn);
      }
    }
  }
}

// ============ Flash attention: kt-split wave groups + all-MFMA32 + rsum-via-ones ============
// r8 counters: VALUBusy 56%, MfmaUtil 26% -> VALU-throughput-bound. This round: (1) raw
// v_exp_f32 via fexp2 (drop ocml fixup path, ~2-3x fewer exp insts); (2) unroll-2 on the
// t-loop so `cur` is compile-time -> all swizzled LDS addresses become loop-invariant and
// hoist to registers (kills per-iter address VALU). LDS-capped at 2 blocks/CU, so the
// VGPR growth from hoisting is free.
__global__ __launch_bounds__(512, 4) void flash_kernel(
    const f16* __restrict__ qg, const f16* __restrict__ kg, const f16* __restrict__ vtg,
    f16* __restrict__ ao) {
  __shared__ alignas(16) f16 sK[2][2][64 * 64];   // [group][buf]
  __shared__ alignas(16) f16 sVT[2][2][64 * 64];  // [group][buf] [d][key-permuted]
  const int tid = threadIdx.x;
  const int w = tid >> 6, lane = tid & 63, ln = lane & 15, quad = lane >> 4;
  const int grp = w >> 2, wl = w & 3;  // kt-group, wave-in-group
  const int gt = tid & 255;            // thread id within group (staging)
  const int bx = blockIdx.x;
  const int bh = bx & 31, qt = bx >> 5;  // XCD-major: (b,h) fixed per bx%8 class
  const int h = bh & 15, b = bh >> 4;
  const f16* Qh = qg + (size_t)(b * NH + h) * Ls * HD;
  const f16* Kh = kg + (size_t)(b * NH + h) * Ls * HD;
  const f16* VTh = vtg + (size_t)(b * NH + h) * HD * Ls;
  const int q0 = qt * 128;

  // Q as B-frags straight from global: lane n=ln (q-col), k = kk*32 + quad*8 + j
  f16x8 aq[2][2];
#pragma unroll
  for (int st = 0; st < 2; ++st)
#pragma unroll
    for (int kk = 0; kk < 2; ++kk)
      aq[st][kk] = *(const f16x8*)&Qh[(size_t)(q0 + wl * 32 + st * 16 + ln) * HD + kk * 32 + quad * 8];

  f16x8 kr[2], vr[2];
  auto loadKV = [&](int k0) {
#pragma unroll
    for (int s = 0; s < 2; ++s) {
      int ch = gt + s * 256, r = ch >> 3, cg = (ch & 7) * 8;
      kr[s] = *(const f16x8*)&Kh[(size_t)(k0 + r) * HD + cg];
      vr[s] = *(const f16x8*)&VTh[(size_t)r * Ls + k0 + cg];
    }
  };
  auto stageKV = [&](int buf) {
#pragma unroll
    for (int s = 0; s < 2; ++s) {
      int ch = gt + s * 256, r = ch >> 3;
      int po = r * 64 + (((ch & 7) ^ (r & 7)) * 8);
      *(f16x8*)&sK[grp][buf][po] = kr[s];
      *(f16x8*)&sVT[grp][buf][po] = vr[s];
    }
  };

  f32x4 O[2][4] = {};
  f32x4 racc[2] = {};
  const f16x8 onesv = {(f16)1.f, (f16)1.f, (f16)1.f, (f16)1.f,
                       (f16)1.f, (f16)1.f, (f16)1.f, (f16)1.f};
  const f32x4 zc = {};

  const int kbase = grp << 10;  // group key offset
  loadKV(kbase);
  stageKV(0);
  __syncthreads();

#pragma unroll 2
  for (int t = 0; t < 16; ++t) {
    const int cur = t & 1;  // compile-time under unroll-2
    if (t < 15) loadKV(kbase + (t + 1) * 64);  // global->reg prefetch across compute

    // S^T + exp in registers -> merged PV A-frags (f16x8 = two 16-key tiles)
    f16x8 pA[2][2];
#pragma unroll
    for (int nt = 0; nt < 4; ++nt) {
      const int r = nt * 16 + ln;  // key row
      const f16x8 kf0 = *(const f16x8*)&sK[grp][cur][r * 64 + ((quad ^ (r & 7)) * 8)];
      const f16x8 kf1 = *(const f16x8*)&sK[grp][cur][r * 64 + (((4 + quad) ^ (r & 7)) * 8)];
#pragma unroll
      for (int st = 0; st < 2; ++st) {
        f32x4 z = MFMA32(kf1, aq[st][1], MFMA32(kf0, aq[st][0], zc));
#pragma unroll
        for (int j = 0; j < 4; ++j)
          pA[st][nt >> 1][(nt & 1) * 4 + j] = (f16)fexp2(z[j]);
      }
    }

    __builtin_amdgcn_s_setprio(1);
#pragma unroll
    for (int st = 0; st < 2; ++st) {
      racc[st] = MFMA32(pA[st][0], onesv, racc[st]);
      racc[st] = MFMA32(pA[st][1], onesv, racc[st]);
    }
#pragma unroll
    for (int dt = 0; dt < 4; ++dt) {
      const int row = dt * 16 + ln;  // d row
#pragma unroll
      for (int nt2 = 0; nt2 < 2; ++nt2) {
        const f16x8 vf = *(const f16x8*)&sVT[grp][cur][row * 64 + (((quad * 2 + nt2) ^ (row & 7)) * 8)];
#pragma unroll
        for (int st = 0; st < 2; ++st)
          O[st][dt] = MFMA32(pA[st][nt2], vf, O[st][dt]);
      }
    }
    __builtin_amdgcn_s_setprio(0);

    if (t < 15) stageKV(cur ^ 1);  // vmcnt wait lands here, after compute
    __syncthreads();
  }

  // ---- combine the two kt-halves through the (now dead) staging LDS ----
  float* cO = (float*)&sK[0][0][0];   // 128 q x 64 d f32 = 32 KB (all of sK)
  float* cR = (float*)&sVT[0][0][0];  // 128 f32
  if (grp == 1) {
#pragma unroll
    for (int st = 0; st < 2; ++st) {
#pragma unroll
      for (int rg = 0; rg < 4; ++rg) {
        const int ql = wl * 32 + st * 16 + quad * 4 + rg;
#pragma unroll
        for (int dt = 0; dt < 4; ++dt) cO[ql * 64 + dt * 16 + ln] = O[st][dt][rg];
        if (ln == 0) cR[ql] = racc[st][rg];
      }
    }
  }
  __syncthreads();
  if (grp == 0) {
#pragma unroll
    for (int st = 0; st < 2; ++st) {
#pragma unroll
      for (int rg = 0; rg < 4; ++rg) {
        const int ql = wl * 32 + st * 16 + quad * 4 + rg;
        const float inv = 1.0f / (racc[st][rg] + cR[ql]);
        const int q = q0 + ql;
        const size_t orow = ((size_t)b * Ls + q) * DIM + h * HD;
#pragma unroll
        for (int dt = 0; dt < 4; ++dt)
          ao[orow + dt * 16 + ln] = (f16)((O[st][dt][rg] + cO[ql * 64 + dt * 16 + ln]) * inv);
      }
    }
  }
}

// ============ proj GEMM: 64x128 tile, BK=32, glLDS double-buffer, 1 barrier/iter ============
// Same unroll + nt-store treatment as qkv (out is a final fp32 output -> no RFO).
__global__ __launch_bounds__(256) void proj_gemm_kernel(
    const f16* __restrict__ A, const f16* __restrict__ W, float* __restrict__ out) {
  constexpr int K = DIM;
  __shared__ alignas(16) f16 sA[2][64 * 32];
  __shared__ alignas(16) f16 sB[2][128 * 32];
  const int tid = threadIdx.x;
  const int w = tid >> 6, lane = tid & 63, ln = lane & 15, quad = lane >> 4;
  const int wm = w >> 1, wn = w & 1;  // wave: 32 rows x 64 cols
  const int m0 = blockIdx.y * 64, n0 = blockIdx.x * 128;

  const f16* gA;  // 256 chunks: 1 per thread
  {
    int p = tid >> 3, g = (tid & 7) ^ (p & 7);
    gA = A + (size_t)(m0 + 2 * p + (g >> 2)) * K + (g & 3) * 8;
  }
  const f16* gB[2];
#pragma unroll
  for (int s = 0; s < 2; ++s) {
    int lc = tid + s * 256;
    int p = lc >> 3, g = (lc & 7) ^ (p & 7);
    gB[s] = W + (size_t)(n0 + 2 * p + (g >> 2)) * K + (g & 3) * 8;
  }

  auto issue = [&](int k0, int buf) {
    async16(&sA[buf][tid * 8], gA + k0);
#pragma unroll
    for (int s = 0; s < 2; ++s) async16(&sB[buf][(tid + s * 256) * 8], gB[s] + k0);
  };

  f32x4 acc[2][4] = {};

  issue(0, 0);
  __syncthreads();

#pragma unroll
  for (int it = 0; it < 32; ++it) {
    const int cur = it & 1;
    if (it < 31) issue((it + 1) * 32, cur ^ 1);
    f16x8 a[2];
#pragma unroll
    for (int mi = 0; mi < 2; ++mi)
      a[mi] = *(const f16x8*)&sA[cur][sw32(wm * 32 + mi * 16 + ln, quad)];
#pragma unroll
    for (int ni = 0; ni < 4; ++ni) {
      f16x8 b = *(const f16x8*)&sB[cur][sw32(wn * 64 + ni * 16 + ln, quad)];
#pragma unroll
      for (int mi = 0; mi < 2; ++mi) acc[mi][ni] = MFMA32(a[mi], b, acc[mi][ni]);
    }
    __syncthreads();
  }

#pragma unroll
  for (int mi = 0; mi < 2; ++mi) {
#pragma unroll
    for (int rg = 0; rg < 4; ++rg) {
      int row = m0 + wm * 32 + mi * 16 + quad * 4 + rg;
      size_t o = (size_t)row * DIM + n0 + wn * 64;
#pragma unroll
      for (int ni = 0; ni < 4; ++ni)
        __builtin_nontemporal_store(acc[mi][ni][rg], &out[o + ni * 16 + ln]);
    }
  }
}

extern "C" void kernel_launch(void* const* d_in, const int* in_sizes, int n_in,
                              void* d_out, int out_size, void* d_ws, size_t ws_size,
                              hipStream_t stream) {
  (void)in_sizes; (void)n_in; (void)out_size; (void)ws_size;
  const float* x = (const float*)d_in[0];
  const float* v0 = (const float*)d_in[1];
  const float* rcos = (const float*)d_in[2];
  const float* rsin = (const float*)d_in[3];
  const float* wqkv = (const float*)d_in[4];
  const float* wproj = (const float*)d_in[5];
  const float* lamp = (const float*)d_in[6];
  float* out = (float*)d_out;
  float* vout = out + (size_t)BL * DIM;  // output #1: blended v, (B,H,L,HD)

  char* p = (char*)d_ws;
  auto take = [&](size_t n) { char* q = p; p += ((n + 255) / 256) * 256; return q; };
  f16* xf = (f16*)take((size_t)BL * DIM * 2);
  f16* wqf = (f16*)take((size_t)3 * DIM * DIM * 2);
  f16* wpf = (f16*)take((size_t)DIM * DIM * 2);
  f16* qb = (f16*)take((size_t)BL * DIM * 2);
  f16* kb = (f16*)take((size_t)BL * DIM * 2);
  f16* vbT = (f16*)take((size_t)BL * DIM * 2);  // (b,h,d, key-permuted l)
  f16* ao = xf;  // x dead after qkv_gemm; reuse (stream-ordered)

  constexpr int NCVT4 = (BL * DIM + 3 * DIM * DIM + DIM * DIM) / 4;
  cvt_all_kernel<<<dim3(NCVT4 / 256), dim3(256), 0, stream>>>(x, wqkv, wproj, xf, wqf, wpf);

  qkv_gemm_kernel<<<dim3(3 * DIM / 128, BL / 128), dim3(256), 0, stream>>>(
      xf, wqf, v0, rcos, rsin, lamp, qb, kb, vbT, vout);

  flash_kernel<<<dim3(Bs * NH * (Ls / 128)), dim3(512), 0, stream>>>(qb, kb, vbT, ao);

  proj_gemm_kernel<<<dim3(DIM / 128, BL / 64), dim3(256), 0, stream>>>(ao, wpf, out);
}

// Round 10
// 206.418 us; speedup vs baseline: 1.1796x; 1.0408x over previous
//
#include <hip/hip_runtime.h>

typedef _Float16 f16;
typedef _Float16 f16x8 __attribute__((ext_vector_type(8)));
typedef _Float16 f16x4 __attribute__((ext_vector_type(4)));
typedef float f32x4 __attribute__((ext_vector_type(4)));

#define MFMA32(a, b, c) __builtin_amdgcn_mfma_f32_16x16x32_f16((a), (b), (c), 0, 0, 0)

constexpr int Bs = 2, Ls = 2048, DIM = 1024, NH = 16, HD = 64;
constexpr int BL = Bs * Ls;  // 4096
constexpr float EPSV = 1e-6f;
constexpr float SCL2 = 0.125f * 1.44269504f;  // (1/sqrt(64)) * log2(e); folded into q

// Raw v_exp_f32 (2^x). Scores are RMS-normed, |x| small -> ocml's denorm/clamp fixup
// path is pure VALU waste; the bare instruction suffices.
__device__ __forceinline__ float fexp2(float x) {
#if __has_builtin(__builtin_amdgcn_exp2f)
  return __builtin_amdgcn_exp2f(x);
#else
  return exp2f(x);
#endif
}

// async global->LDS, 16B per lane. LDS dest = wave-uniform base + lane*16.
__device__ __forceinline__ void async16(void* lds, const void* g) {
  __builtin_amdgcn_global_load_lds((const __attribute__((address_space(1))) void*)g,
                                   (__attribute__((address_space(3))) void*)lds, 16, 0, 0);
}

// BK=32 pair-XOR swizzle: rows are 64B (4 chunks); swizzle unit = row PAIR (8 chunks).
// LDS linear chunk lc <-> (pair p = lc>>3, phys ph = lc&7); global chunk g = ph ^ (p&7),
// global (row, colElems) = (2p + (g>>2), (g&3)*8). Frag read of (row r, kchunk q):
// addr elems = (r>>1)*64 + (((r&1)*4 + q) ^ ((r>>1)&7))*8.  Banks: 2-way (free).
__device__ __forceinline__ int sw32(int r, int q) {
  int p = r >> 1;
  return p * 64 + ((((r & 1) * 4 + q) ^ (p & 7)) * 8);
}

// ---------------- fp32 -> fp16 convert, all three tensors in one launch ----------------
// fp32 sources are never read again -> nontemporal loads keep them out of L2.
__global__ void cvt_all_kernel(const float* __restrict__ x, const float* __restrict__ wq,
                               const float* __restrict__ wp, f16* __restrict__ xf,
                               f16* __restrict__ wqf, f16* __restrict__ wpf) {
  constexpr int NX4 = BL * DIM / 4;
  constexpr int NW4 = 3 * DIM * DIM / 4;
  int i = blockIdx.x * blockDim.x + threadIdx.x;
  const f32x4* src;
  f16x4* dst;
  int j;
  if (i < NX4) {
    src = (const f32x4*)x; dst = (f16x4*)xf; j = i;
  } else if (i < NX4 + NW4) {
    src = (const f32x4*)wq; dst = (f16x4*)wqf; j = i - NX4;
  } else {
    src = (const f32x4*)wp; dst = (f16x4*)wpf; j = i - NX4 - NW4;
  }
  f32x4 a = __builtin_nontemporal_load(&src[j]);
  f16x4 o = {(f16)a[0], (f16)a[1], (f16)a[2], (f16)a[3]};
  dst[j] = o;
}

// ====== QKV GEMM: 128x128 tile, BK=32, T14 reg-staged double-buffer (depth-2) ======
// r9 counters: MfmaUtil 13.5 + VALUBusy 9.6 -> ~77% stall at the per-iter vmcnt(0) drain
// (__syncthreads drains glLDS). Fix: stage via REGISTERS — plain global loads survive
// barriers (T14, m214 r277); the vmcnt wait moves to the ds_write of tile it+1 at the END
// of iter it, giving loads issued at iter it-1 a ~1.5-iteration window instead of ~0.3.
// Schedule/iter: loadT(it+2)->regs ; ds_read+MFMA(tile it) ; writeT(tile it+1)->LDS ; bar.
// Parity reg sets (tile j in set j&1), all indices static under full unroll (rule #20).
// nt-store/nt-load reverted (r9 counters: FETCH unchanged, WRITE +4.8MB -> nt hurt).
// Pre-commit: if qkv >= 65us, drain theory falsified -> revert + attack occupancy.
__global__ __launch_bounds__(256) void qkv_gemm_kernel(
    const f16* __restrict__ A, const f16* __restrict__ W,
    const float* __restrict__ v0,
    const float* __restrict__ rcos, const float* __restrict__ rsin,
    const float* __restrict__ lamp,
    f16* __restrict__ qb, f16* __restrict__ kb, f16* __restrict__ vbT,
    float* __restrict__ vout) {
  constexpr int K = DIM;
  __shared__ alignas(16) f16 sm[4][128 * 32];  // [0,1]=A dbuf, [2,3]=B dbuf; 32KB
  const int tid = threadIdx.x;
  const int w = tid >> 6, lane = tid & 63, ln = lane & 15, quad = lane >> 4;
  const int wm = w >> 1, wn = w & 1;
  const int m0 = blockIdx.y * 128, n0 = blockIdx.x * 128;

  const f16* gA[2];
  const f16* gB[2];
#pragma unroll
  for (int s = 0; s < 2; ++s) {
    int lc = tid + s * 256;
    int p = lc >> 3, g = (lc & 7) ^ (p & 7);
    int r = 2 * p + (g >> 2), ce = (g & 3) * 8;
    gA[s] = A + (size_t)(m0 + r) * K + ce;
    gB[s] = W + (size_t)(n0 + r) * K + ce;
  }

  f16x8 rA[2][2], rB[2][2];  // [parity][s]; tile j lives in parity j&1
  auto loadT = [&](int k0, int pr) {
#pragma unroll
    for (int s = 0; s < 2; ++s) {
      rA[pr][s] = *(const f16x8*)(gA[s] + k0);
      rB[pr][s] = *(const f16x8*)(gB[s] + k0);
    }
  };
  auto writeT = [&](int buf, int pr) {
#pragma unroll
    for (int s = 0; s < 2; ++s) {
      *(f16x8*)&sm[buf][(tid + s * 256) * 8] = rA[pr][s];
      *(f16x8*)&sm[2 + buf][(tid + s * 256) * 8] = rB[pr][s];
    }
  };

  f32x4 acc[4][4] = {};

  loadT(0, 0);
  loadT(32, 1);
  writeT(0, 0);     // waits tile0's loads only (data dep)
  __syncthreads();  // buf0 visible; tile1's reg loads stay in flight across the barrier

#pragma unroll
  for (int it = 0; it < 32; ++it) {
    const int cur = it & 1, nxt = cur ^ 1;
    // issue tile it+2 (parity cur): its reg set was freed by writeT at iter it-1.
    if (it < 30) loadT((it + 2) * 32, cur);
    f16x8 a[4];
#pragma unroll
    for (int mi = 0; mi < 4; ++mi)
      a[mi] = *(const f16x8*)&sm[cur][sw32(wm * 64 + mi * 16 + ln, quad)];
#pragma unroll
    for (int ni = 0; ni < 4; ++ni) {
      f16x8 b = *(const f16x8*)&sm[2 + cur][sw32(wn * 64 + ni * 16 + ln, quad)];
#pragma unroll
      for (int mi = 0; mi < 4; ++mi) acc[mi][ni] = MFMA32(a[mi], b, acc[mi][ni]);
    }
    // stage tile it+1 into buf nxt (read-free since the barrier at end of iter it-1);
    // the vmcnt wait for its loads (issued at iter it-1) lands HERE, after compute.
    if (it < 31) writeT(nxt, nxt);
    __syncthreads();
  }

  // Epilogue. Wave covers one head (64 cols). C/D: col=ln (ni tile), row=quad*4+rg (mi tile).
  const int nb = n0 + wn * 64;
  const int nsec = nb >> 10;        // 0=q, 1=k, 2=v  (per-wave)
  const int h = (nb & 1023) >> 6;   // head

  if (nsec == 2) {
    const float lam = lamp[0];
    const int l064 = m0 + wm * 64;           // 64-aligned key-group base (global row)
    const int b = l064 >> 11, l0 = l064 & 2047;
    const size_t vb = (size_t)(b * NH + h) * Ls * HD;
    f16* wT = &sm[0][0] + w * 4096;          // per-wave 8KB transpose tile [d][sidx]
#pragma unroll
    for (int mi = 0; mi < 4; ++mi) {
#pragma unroll
      for (int ni = 0; ni < 4; ++ni) {
        const int d = ni * 16 + ln;
        f16 pk[4];
#pragma unroll
        for (int rg = 0; rg < 4; ++rg) {
          const int kk = mi * 16 + quad * 4 + rg;
          const size_t base = vb + (size_t)(l0 + kk) * HD + d;
          float vnew = lam * acc[mi][ni][rg] + (1.0f - lam) * v0[base];
          vout[base] = vnew;  // fp32 output #1 (b,h,l,d), coalesced
          pk[rg] = (f16)vnew;
        }
        // sidx for kk = mi*16+quad*4+rg: quad*16 + mi*4 + rg (flash's key permutation)
        f16x4 q4 = {pk[0], pk[1], pk[2], pk[3]};
        const int sidx0 = quad * 16 + mi * 4;
        *(f16x4*)&wT[d * 64 + (sidx0 ^ ((d & 7) << 3))] = q4;
      }
    }
    // coalesced read-out (per-wave-private tile, no barrier needed)
    const size_t tB = (size_t)(b * NH + h) * HD * Ls + l0;
#pragma unroll
    for (int dd = 0; dd < 16; ++dd) {
      const int d = dd * 4 + quad;
      f16x4 vv = *(const f16x4*)&wT[d * 64 + ((ln * 4) ^ ((d & 7) << 3))];
      *(f16x4*)&vbT[tB + (size_t)d * Ls + ln * 4] = vv;
    }
  } else {
    f16* dst = nsec ? kb : qb;
    const float ratio = sqrtf(logf(2048.0f) / logf(1040.0f));
    const float post = nsec ? 1.0f : SCL2;  // fold softmax scale*log2e into q
#pragma unroll
    for (int mi = 0; mi < 4; ++mi) {
#pragma unroll
      for (int rg = 0; rg < 4; ++rg) {
        int row = m0 + wm * 64 + mi * 16 + quad * 4 + rg;
        int b = row >> 11, l = row & 2047;
        float vals[4];
#pragma unroll
        for (int ni = 0; ni < 4; ++ni) vals[ni] = acc[mi][ni][rg];
#pragma unroll
        for (int t = 0; t < 2; ++t) {
          int j = t * 16 + ln;
          float c = rcos[l * 32 + j], s = rsin[l * 32 + j];
          float x1 = vals[t], x2 = vals[t + 2];
          vals[t] = x1 * c + x2 * s;
          vals[t + 2] = -x1 * s + x2 * c;
        }
        if (nsec) {
#pragma unroll
          for (int ni = 0; ni < 4; ++ni) vals[ni] *= ratio;
        }
        float ms = vals[0] * vals[0] + vals[1] * vals[1] + vals[2] * vals[2] + vals[3] * vals[3];
        ms += __shfl_xor(ms, 1);
        ms += __shfl_xor(ms, 2);
        ms += __shfl_xor(ms, 4);
        ms += __shfl_xor(ms, 8);
        float rn = rsqrtf(ms * (1.0f / 64.0f) + EPSV) * post;
        size_t base = ((size_t)(b * NH + h) * Ls + l) * HD;
#pragma unroll
        for (int ni = 0; ni < 4; ++ni) dst[base + ni * 16 + ln] = (f16)(vals[ni] * rn);
      }
    }
  }
}

// ============ Flash attention: kt-split wave groups + all-MFMA32 + rsum-via-ones ============
// r8->r9: fexp2 + unroll-2 verified (flash left the top-5). Unchanged this round.
__global__ __launch_bounds__(512, 4) void flash_kernel(
    const f16* __restrict__ qg, const f16* __restrict__ kg, const f16* __restrict__ vtg,
    f16* __restrict__ ao) {
  __shared__ alignas(16) f16 sK[2][2][64 * 64];   // [group][buf]
  __shared__ alignas(16) f16 sVT[2][2][64 * 64];  // [group][buf] [d][key-permuted]
  const int tid = threadIdx.x;
  const int w = tid >> 6, lane = tid & 63, ln = lane & 15, quad = lane >> 4;
  const int grp = w >> 2, wl = w & 3;  // kt-group, wave-in-group
  const int gt = tid & 255;            // thread id within group (staging)
  const int bx = blockIdx.x;
  const int bh = bx & 31, qt = bx >> 5;  // XCD-major: (b,h) fixed per bx%8 class
  const int h = bh & 15, b = bh >> 4;
  const f16* Qh = qg + (size_t)(b * NH + h) * Ls * HD;
  const f16* Kh = kg + (size_t)(b * NH + h) * Ls * HD;
  const f16* VTh = vtg + (size_t)(b * NH + h) * HD * Ls;
  const int q0 = qt * 128;

  // Q as B-frags straight from global: lane n=ln (q-col), k = kk*32 + quad*8 + j
  f16x8 aq[2][2];
#pragma unroll
  for (int st = 0; st < 2; ++st)
#pragma unroll
    for (int kk = 0; kk < 2; ++kk)
      aq[st][kk] = *(const f16x8*)&Qh[(size_t)(q0 + wl * 32 + st * 16 + ln) * HD + kk * 32 + quad * 8];

  f16x8 kr[2], vr[2];
  auto loadKV = [&](int k0) {
#pragma unroll
    for (int s = 0; s < 2; ++s) {
      int ch = gt + s * 256, r = ch >> 3, cg = (ch & 7) * 8;
      kr[s] = *(const f16x8*)&Kh[(size_t)(k0 + r) * HD + cg];
      vr[s] = *(const f16x8*)&VTh[(size_t)r * Ls + k0 + cg];
    }
  };
  auto stageKV = [&](int buf) {
#pragma unroll
    for (int s = 0; s < 2; ++s) {
      int ch = gt + s * 256, r = ch >> 3;
      int po = r * 64 + (((ch & 7) ^ (r & 7)) * 8);
      *(f16x8*)&sK[grp][buf][po] = kr[s];
      *(f16x8*)&sVT[grp][buf][po] = vr[s];
    }
  };

  f32x4 O[2][4] = {};
  f32x4 racc[2] = {};
  const f16x8 onesv = {(f16)1.f, (f16)1.f, (f16)1.f, (f16)1.f,
                       (f16)1.f, (f16)1.f, (f16)1.f, (f16)1.f};
  const f32x4 zc = {};

  const int kbase = grp << 10;  // group key offset
  loadKV(kbase);
  stageKV(0);
  __syncthreads();

#pragma unroll 2
  for (int t = 0; t < 16; ++t) {
    const int cur = t & 1;  // compile-time under unroll-2
    if (t < 15) loadKV(kbase + (t + 1) * 64);  // global->reg prefetch across compute

    // S^T + exp in registers -> merged PV A-frags (f16x8 = two 16-key tiles)
    f16x8 pA[2][2];
#pragma unroll
    for (int nt = 0; nt < 4; ++nt) {
      const int r = nt * 16 + ln;  // key row
      const f16x8 kf0 = *(const f16x8*)&sK[grp][cur][r * 64 + ((quad ^ (r & 7)) * 8)];
      const f16x8 kf1 = *(const f16x8*)&sK[grp][cur][r * 64 + (((4 + quad) ^ (r & 7)) * 8)];
#pragma unroll
      for (int st = 0; st < 2; ++st) {
        f32x4 z = MFMA32(kf1, aq[st][1], MFMA32(kf0, aq[st][0], zc));
#pragma unroll
        for (int j = 0; j < 4; ++j)
          pA[st][nt >> 1][(nt & 1) * 4 + j] = (f16)fexp2(z[j]);
      }
    }

    __builtin_amdgcn_s_setprio(1);
#pragma unroll
    for (int st = 0; st < 2; ++st) {
      racc[st] = MFMA32(pA[st][0], onesv, racc[st]);
      racc[st] = MFMA32(pA[st][1], onesv, racc[st]);
    }
#pragma unroll
    for (int dt = 0; dt < 4; ++dt) {
      const int row = dt * 16 + ln;  // d row
#pragma unroll
      for (int nt2 = 0; nt2 < 2; ++nt2) {
        const f16x8 vf = *(const f16x8*)&sVT[grp][cur][row * 64 + (((quad * 2 + nt2) ^ (row & 7)) * 8)];
#pragma unroll
        for (int st = 0; st < 2; ++st)
          O[st][dt] = MFMA32(pA[st][nt2], vf, O[st][dt]);
      }
    }
    __builtin_amdgcn_s_setprio(0);

    if (t < 15) stageKV(cur ^ 1);  // vmcnt wait lands here, after compute
    __syncthreads();
  }

  // ---- combine the two kt-halves through the (now dead) staging LDS ----
  float* cO = (float*)&sK[0][0][0];   // 128 q x 64 d f32 = 32 KB (all of sK)
  float* cR = (float*)&sVT[0][0][0];  // 128 f32
  if (grp == 1) {
#pragma unroll
    for (int st = 0; st < 2; ++st) {
#pragma unroll
      for (int rg = 0; rg < 4; ++rg) {
        const int ql = wl * 32 + st * 16 + quad * 4 + rg;
#pragma unroll
        for (int dt = 0; dt < 4; ++dt) cO[ql * 64 + dt * 16 + ln] = O[st][dt][rg];
        if (ln == 0) cR[ql] = racc[st][rg];
      }
    }
  }
  __syncthreads();
  if (grp == 0) {
#pragma unroll
    for (int st = 0; st < 2; ++st) {
#pragma unroll
      for (int rg = 0; rg < 4; ++rg) {
        const int ql = wl * 32 + st * 16 + quad * 4 + rg;
        const float inv = 1.0f / (racc[st][rg] + cR[ql]);
        const int q = q0 + ql;
        const size_t orow = ((size_t)b * Ls + q) * DIM + h * HD;
#pragma unroll
        for (int dt = 0; dt < 4; ++dt)
          ao[orow + dt * 16 + ln] = (f16)((O[st][dt][rg] + cO[ql * 64 + dt * 16 + ln]) * inv);
      }
    }
  }
}

// ============ proj GEMM: 64x128 tile, BK=32, glLDS double-buffer, 1 barrier/iter ============
// nt-store reverted (r9: nt stores added write traffic, no fetch benefit).
__global__ __launch_bounds__(256) void proj_gemm_kernel(
    const f16* __restrict__ A, const f16* __restrict__ W, float* __restrict__ out) {
  constexpr int K = DIM;
  __shared__ alignas(16) f16 sA[2][64 * 32];
  __shared__ alignas(16) f16 sB[2][128 * 32];
  const int tid = threadIdx.x;
  const int w = tid >> 6, lane = tid & 63, ln = lane & 15, quad = lane >> 4;
  const int wm = w >> 1, wn = w & 1;  // wave: 32 rows x 64 cols
  const int m0 = blockIdx.y * 64, n0 = blockIdx.x * 128;

  const f16* gA;  // 256 chunks: 1 per thread
  {
    int p = tid >> 3, g = (tid & 7) ^ (p & 7);
    gA = A + (size_t)(m0 + 2 * p + (g >> 2)) * K + (g & 3) * 8;
  }
  const f16* gB[2];
#pragma unroll
  for (int s = 0; s < 2; ++s) {
    int lc = tid + s * 256;
    int p = lc >> 3, g = (lc & 7) ^ (p & 7);
    gB[s] = W + (size_t)(n0 + 2 * p + (g >> 2)) * K + (g & 3) * 8;
  }

  auto issue = [&](int k0, int buf) {
    async16(&sA[buf][tid * 8], gA + k0);
#pragma unroll
    for (int s = 0; s < 2; ++s) async16(&sB[buf][(tid + s * 256) * 8], gB[s] + k0);
  };

  f32x4 acc[2][4] = {};

  issue(0, 0);
  __syncthreads();

#pragma unroll
  for (int it = 0; it < 32; ++it) {
    const int cur = it & 1;
    if (it < 31) issue((it + 1) * 32, cur ^ 1);
    f16x8 a[2];
#pragma unroll
    for (int mi = 0; mi < 2; ++mi)
      a[mi] = *(const f16x8*)&sA[cur][sw32(wm * 32 + mi * 16 + ln, quad)];
#pragma unroll
    for (int ni = 0; ni < 4; ++ni) {
      f16x8 b = *(const f16x8*)&sB[cur][sw32(wn * 64 + ni * 16 + ln, quad)];
#pragma unroll
      for (int mi = 0; mi < 2; ++mi) acc[mi][ni] = MFMA32(a[mi], b, acc[mi][ni]);
    }
    __syncthreads();
  }

#pragma unroll
  for (int mi = 0; mi < 2; ++mi) {
#pragma unroll
    for (int rg = 0; rg < 4; ++rg) {
      int row = m0 + wm * 32 + mi * 16 + quad * 4 + rg;
      size_t o = (size_t)row * DIM + n0 + wn * 64;
#pragma unroll
      for (int ni = 0; ni < 4; ++ni) out[o + ni * 16 + ln] = acc[mi][ni][rg];
    }
  }
}

extern "C" void kernel_launch(void* const* d_in, const int* in_sizes, int n_in,
                              void* d_out, int out_size, void* d_ws, size_t ws_size,
                              hipStream_t stream) {
  (void)in_sizes; (void)n_in; (void)out_size; (void)ws_size;
  const float* x = (const float*)d_in[0];
  const float* v0 = (const float*)d_in[1];
  const float* rcos = (const float*)d_in[2];
  const float* rsin = (const float*)d_in[3];
  const float* wqkv = (const float*)d_in[4];
  const float* wproj = (const float*)d_in[5];
  const float* lamp = (const float*)d_in[6];
  float* out = (float*)d_out;
  float* vout = out + (size_t)BL * DIM;  // output #1: blended v, (B,H,L,HD)

  char* p = (char*)d_ws;
  auto take = [&](size_t n) { char* q = p; p += ((n + 255) / 256) * 256; return q; };
  f16* xf = (f16*)take((size_t)BL * DIM * 2);
  f16* wqf = (f16*)take((size_t)3 * DIM * DIM * 2);
  f16* wpf = (f16*)take((size_t)DIM * DIM * 2);
  f16* qb = (f16*)take((size_t)BL * DIM * 2);
  f16* kb = (f16*)take((size_t)BL * DIM * 2);
  f16* vbT = (f16*)take((size_t)BL * DIM * 2);  // (b,h,d, key-permuted l)
  f16* ao = xf;  // x dead after qkv_gemm; reuse (stream-ordered)

  constexpr int NCVT4 = (BL * DIM + 3 * DIM * DIM + DIM * DIM) / 4;
  cvt_all_kernel<<<dim3(NCVT4 / 256), dim3(256), 0, stream>>>(x, wqkv, wproj, xf, wqf, wpf);

  qkv_gemm_kernel<<<dim3(3 * DIM / 128, BL / 128), dim3(256), 0, stream>>>(
      xf, wqf, v0, rcos, rsin, lamp, qb, kb, vbT, vout);

  flash_kernel<<<dim3(Bs * NH * (Ls / 128)), dim3(512), 0, stream>>>(qb, kb, vbT, ao);

  proj_gemm_kernel<<<dim3(DIM / 128, BL / 64), dim3(256), 0, stream>>>(ao, wpf, out);
}

// Round 11
// 201.413 us; speedup vs baseline: 1.2090x; 1.0248x over previous
//
#include <hip/hip_runtime.h>

typedef _Float16 f16;
typedef _Float16 f16x8 __attribute__((ext_vector_type(8)));
typedef _Float16 f16x4 __attribute__((ext_vector_type(4)));
typedef float f32x4 __attribute__((ext_vector_type(4)));

#define MFMA32(a, b, c) __builtin_amdgcn_mfma_f32_16x16x32_f16((a), (b), (c), 0, 0, 0)

constexpr int Bs = 2, Ls = 2048, DIM = 1024, NH = 16, HD = 64;
constexpr int BL = Bs * Ls;  // 4096
constexpr float EPSV = 1e-6f;
constexpr float SCL2 = 0.125f * 1.44269504f;  // (1/sqrt(64)) * log2(e); folded into q

// Raw v_exp_f32 (2^x). Scores are RMS-normed, |x| small -> ocml's denorm/clamp fixup
// path is pure VALU waste; the bare instruction suffices.
__device__ __forceinline__ float fexp2(float x) {
#if __has_builtin(__builtin_amdgcn_exp2f)
  return __builtin_amdgcn_exp2f(x);
#else
  return exp2f(x);
#endif
}

// BK=32 pair-XOR swizzle: rows are 64B (4 chunks); swizzle unit = row PAIR (8 chunks).
// LDS linear chunk lc <-> (pair p = lc>>3, phys ph = lc&7); global chunk g = ph ^ (p&7),
// global (row, colElems) = (2p + (g>>2), (g&3)*8). Frag read of (row r, kchunk q):
// addr elems = (r>>1)*64 + (((r&1)*4 + q) ^ ((r>>1)&7))*8.  Banks: 2-way (free).
__device__ __forceinline__ int sw32(int r, int q) {
  int p = r >> 1;
  return p * 64 + ((((r & 1) * 4 + q) ^ (p & 7)) * 8);
}

// ---------------- fp32 -> fp16 convert, all three tensors in one launch ----------------
// fp32 sources are never read again -> nontemporal loads keep them out of L2.
__global__ void cvt_all_kernel(const float* __restrict__ x, const float* __restrict__ wq,
                               const float* __restrict__ wp, f16* __restrict__ xf,
                               f16* __restrict__ wqf, f16* __restrict__ wpf) {
  constexpr int NX4 = BL * DIM / 4;
  constexpr int NW4 = 3 * DIM * DIM / 4;
  int i = blockIdx.x * blockDim.x + threadIdx.x;
  const f32x4* src;
  f16x4* dst;
  int j;
  if (i < NX4) {
    src = (const f32x4*)x; dst = (f16x4*)xf; j = i;
  } else if (i < NX4 + NW4) {
    src = (const f32x4*)wq; dst = (f16x4*)wqf; j = i - NX4;
  } else {
    src = (const f32x4*)wp; dst = (f16x4*)wpf; j = i - NX4 - NW4;
  }
  f32x4 a = __builtin_nontemporal_load(&src[j]);
  f16x4 o = {(f16)a[0], (f16)a[1], (f16)a[2], (f16)a[3]};
  dst[j] = o;
}

// ====== QKV GEMM: 128x128 tile, BK=32, T14 reg-staged, DEPTH-3 prefetch ======
// r10 verified T14 depth-2 (71->54us, MfmaUtil 13.5->18.5) but ~70% stall remains: tile
// it+1's loads (issued iter it-1) get only ~600 busy-cy before writeT's vmcnt wait — short
// of ~900cy HBM latency. Depth-3: tile j issued at iter j-3, consumed end of j-1 -> window
// ~2 full iters (~2700cy). 3 parity reg sets, mod-3 static under full unroll (rule #20).
// LDS stays 2-buffer; sync structure unchanged from the r10-verified version.
__global__ __launch_bounds__(256) void qkv_gemm_kernel(
    const f16* __restrict__ A, const f16* __restrict__ W,
    const float* __restrict__ v0,
    const float* __restrict__ rcos, const float* __restrict__ rsin,
    const float* __restrict__ lamp,
    f16* __restrict__ qb, f16* __restrict__ kb, f16* __restrict__ vbT,
    float* __restrict__ vout) {
  constexpr int K = DIM;
  __shared__ alignas(16) f16 sm[4][128 * 32];  // [0,1]=A dbuf, [2,3]=B dbuf; 32KB
  const int tid = threadIdx.x;
  const int w = tid >> 6, lane = tid & 63, ln = lane & 15, quad = lane >> 4;
  const int wm = w >> 1, wn = w & 1;
  const int m0 = blockIdx.y * 128, n0 = blockIdx.x * 128;

  const f16* gA[2];
  const f16* gB[2];
#pragma unroll
  for (int s = 0; s < 2; ++s) {
    int lc = tid + s * 256;
    int p = lc >> 3, g = (lc & 7) ^ (p & 7);
    int r = 2 * p + (g >> 2), ce = (g & 3) * 8;
    gA[s] = A + (size_t)(m0 + r) * K + ce;
    gB[s] = W + (size_t)(n0 + r) * K + ce;
  }

  f16x8 rA[3][2], rB[3][2];  // [parity][s]; tile j lives in set j%3
  auto loadT = [&](int k0, int pr) {
#pragma unroll
    for (int s = 0; s < 2; ++s) {
      rA[pr][s] = *(const f16x8*)(gA[s] + k0);
      rB[pr][s] = *(const f16x8*)(gB[s] + k0);
    }
  };
  auto writeT = [&](int buf, int pr) {
#pragma unroll
    for (int s = 0; s < 2; ++s) {
      *(f16x8*)&sm[buf][(tid + s * 256) * 8] = rA[pr][s];
      *(f16x8*)&sm[2 + buf][(tid + s * 256) * 8] = rB[pr][s];
    }
  };

  f32x4 acc[4][4] = {};

  loadT(0, 0);
  loadT(32, 1);
  loadT(64, 2);
  writeT(0, 0);     // waits set0's loads only (data dep); sets 1,2 stay in flight
  __syncthreads();

#pragma unroll
  for (int it = 0; it < 32; ++it) {
    const int cur = it & 1, nxt = cur ^ 1;
    // issue tile it+3 into set (it+3)%3 == it%3 (freed by writeT at end of iter it-1)
    if (it < 29) loadT((it + 3) * 32, (it + 3) % 3);
    f16x8 a[4];
#pragma unroll
    for (int mi = 0; mi < 4; ++mi)
      a[mi] = *(const f16x8*)&sm[cur][sw32(wm * 64 + mi * 16 + ln, quad)];
#pragma unroll
    for (int ni = 0; ni < 4; ++ni) {
      f16x8 b = *(const f16x8*)&sm[2 + cur][sw32(wn * 64 + ni * 16 + ln, quad)];
#pragma unroll
      for (int mi = 0; mi < 4; ++mi) acc[mi][ni] = MFMA32(a[mi], b, acc[mi][ni]);
    }
    // stage tile it+1 (set (it+1)%3, issued at iter it-2 -> ~2-iter window) into buf nxt
    if (it < 31) writeT(nxt, (it + 1) % 3);
    __syncthreads();
  }

  // Epilogue. Wave covers one head (64 cols). C/D: col=ln (ni tile), row=quad*4+rg (mi tile).
  const int nb = n0 + wn * 64;
  const int nsec = nb >> 10;        // 0=q, 1=k, 2=v  (per-wave)
  const int h = (nb & 1023) >> 6;   // head

  if (nsec == 2) {
    const float lam = lamp[0];
    const int l064 = m0 + wm * 64;           // 64-aligned key-group base (global row)
    const int b = l064 >> 11, l0 = l064 & 2047;
    const size_t vb = (size_t)(b * NH + h) * Ls * HD;
    f16* wT = &sm[0][0] + w * 4096;          // per-wave 8KB transpose tile [d][sidx]
#pragma unroll
    for (int mi = 0; mi < 4; ++mi) {
#pragma unroll
      for (int ni = 0; ni < 4; ++ni) {
        const int d = ni * 16 + ln;
        f16 pk[4];
#pragma unroll
        for (int rg = 0; rg < 4; ++rg) {
          const int kk = mi * 16 + quad * 4 + rg;
          const size_t base = vb + (size_t)(l0 + kk) * HD + d;
          float vnew = lam * acc[mi][ni][rg] + (1.0f - lam) * v0[base];
          vout[base] = vnew;  // fp32 output #1 (b,h,l,d), coalesced
          pk[rg] = (f16)vnew;
        }
        // sidx for kk = mi*16+quad*4+rg: quad*16 + mi*4 + rg (flash's key permutation)
        f16x4 q4 = {pk[0], pk[1], pk[2], pk[3]};
        const int sidx0 = quad * 16 + mi * 4;
        *(f16x4*)&wT[d * 64 + (sidx0 ^ ((d & 7) << 3))] = q4;
      }
    }
    // coalesced read-out (per-wave-private tile, no barrier needed)
    const size_t tB = (size_t)(b * NH + h) * HD * Ls + l0;
#pragma unroll
    for (int dd = 0; dd < 16; ++dd) {
      const int d = dd * 4 + quad;
      f16x4 vv = *(const f16x4*)&wT[d * 64 + ((ln * 4) ^ ((d & 7) << 3))];
      *(f16x4*)&vbT[tB + (size_t)d * Ls + ln * 4] = vv;
    }
  } else {
    f16* dst = nsec ? kb : qb;
    const float ratio = sqrtf(logf(2048.0f) / logf(1040.0f));
    const float post = nsec ? 1.0f : SCL2;  // fold softmax scale*log2e into q
#pragma unroll
    for (int mi = 0; mi < 4; ++mi) {
#pragma unroll
      for (int rg = 0; rg < 4; ++rg) {
        int row = m0 + wm * 64 + mi * 16 + quad * 4 + rg;
        int b = row >> 11, l = row & 2047;
        float vals[4];
#pragma unroll
        for (int ni = 0; ni < 4; ++ni) vals[ni] = acc[mi][ni][rg];
#pragma unroll
        for (int t = 0; t < 2; ++t) {
          int j = t * 16 + ln;
          float c = rcos[l * 32 + j], s = rsin[l * 32 + j];
          float x1 = vals[t], x2 = vals[t + 2];
          vals[t] = x1 * c + x2 * s;
          vals[t + 2] = -x1 * s + x2 * c;
        }
        if (nsec) {
#pragma unroll
          for (int ni = 0; ni < 4; ++ni) vals[ni] *= ratio;
        }
        float ms = vals[0] * vals[0] + vals[1] * vals[1] + vals[2] * vals[2] + vals[3] * vals[3];
        ms += __shfl_xor(ms, 1);
        ms += __shfl_xor(ms, 2);
        ms += __shfl_xor(ms, 4);
        ms += __shfl_xor(ms, 8);
        float rn = rsqrtf(ms * (1.0f / 64.0f) + EPSV) * post;
        size_t base = ((size_t)(b * NH + h) * Ls + l) * HD;
#pragma unroll
        for (int ni = 0; ni < 4; ++ni) dst[base + ni * 16 + ln] = (f16)(vals[ni] * rn);
      }
    }
  }
}

// ============ Flash attention: kt-split wave groups + all-MFMA32 + rsum-via-ones ============
// r8->r9: fexp2 + unroll-2 verified. Unchanged this round.
__global__ __launch_bounds__(512, 4) void flash_kernel(
    const f16* __restrict__ qg, const f16* __restrict__ kg, const f16* __restrict__ vtg,
    f16* __restrict__ ao) {
  __shared__ alignas(16) f16 sK[2][2][64 * 64];   // [group][buf]
  __shared__ alignas(16) f16 sVT[2][2][64 * 64];  // [group][buf] [d][key-permuted]
  const int tid = threadIdx.x;
  const int w = tid >> 6, lane = tid & 63, ln = lane & 15, quad = lane >> 4;
  const int grp = w >> 2, wl = w & 3;  // kt-group, wave-in-group
  const int gt = tid & 255;            // thread id within group (staging)
  const int bx = blockIdx.x;
  const int bh = bx & 31, qt = bx >> 5;  // XCD-major: (b,h) fixed per bx%8 class
  const int h = bh & 15, b = bh >> 4;
  const f16* Qh = qg + (size_t)(b * NH + h) * Ls * HD;
  const f16* Kh = kg + (size_t)(b * NH + h) * Ls * HD;
  const f16* VTh = vtg + (size_t)(b * NH + h) * HD * Ls;
  const int q0 = qt * 128;

  // Q as B-frags straight from global: lane n=ln (q-col), k = kk*32 + quad*8 + j
  f16x8 aq[2][2];
#pragma unroll
  for (int st = 0; st < 2; ++st)
#pragma unroll
    for (int kk = 0; kk < 2; ++kk)
      aq[st][kk] = *(const f16x8*)&Qh[(size_t)(q0 + wl * 32 + st * 16 + ln) * HD + kk * 32 + quad * 8];

  f16x8 kr[2], vr[2];
  auto loadKV = [&](int k0) {
#pragma unroll
    for (int s = 0; s < 2; ++s) {
      int ch = gt + s * 256, r = ch >> 3, cg = (ch & 7) * 8;
      kr[s] = *(const f16x8*)&Kh[(size_t)(k0 + r) * HD + cg];
      vr[s] = *(const f16x8*)&VTh[(size_t)r * Ls + k0 + cg];
    }
  };
  auto stageKV = [&](int buf) {
#pragma unroll
    for (int s = 0; s < 2; ++s) {
      int ch = gt + s * 256, r = ch >> 3;
      int po = r * 64 + (((ch & 7) ^ (r & 7)) * 8);
      *(f16x8*)&sK[grp][buf][po] = kr[s];
      *(f16x8*)&sVT[grp][buf][po] = vr[s];
    }
  };

  f32x4 O[2][4] = {};
  f32x4 racc[2] = {};
  const f16x8 onesv = {(f16)1.f, (f16)1.f, (f16)1.f, (f16)1.f,
                       (f16)1.f, (f16)1.f, (f16)1.f, (f16)1.f};
  const f32x4 zc = {};

  const int kbase = grp << 10;  // group key offset
  loadKV(kbase);
  stageKV(0);
  __syncthreads();

#pragma unroll 2
  for (int t = 0; t < 16; ++t) {
    const int cur = t & 1;  // compile-time under unroll-2
    if (t < 15) loadKV(kbase + (t + 1) * 64);  // global->reg prefetch across compute

    // S^T + exp in registers -> merged PV A-frags (f16x8 = two 16-key tiles)
    f16x8 pA[2][2];
#pragma unroll
    for (int nt = 0; nt < 4; ++nt) {
      const int r = nt * 16 + ln;  // key row
      const f16x8 kf0 = *(const f16x8*)&sK[grp][cur][r * 64 + ((quad ^ (r & 7)) * 8)];
      const f16x8 kf1 = *(const f16x8*)&sK[grp][cur][r * 64 + (((4 + quad) ^ (r & 7)) * 8)];
#pragma unroll
      for (int st = 0; st < 2; ++st) {
        f32x4 z = MFMA32(kf1, aq[st][1], MFMA32(kf0, aq[st][0], zc));
#pragma unroll
        for (int j = 0; j < 4; ++j)
          pA[st][nt >> 1][(nt & 1) * 4 + j] = (f16)fexp2(z[j]);
      }
    }

    __builtin_amdgcn_s_setprio(1);
#pragma unroll
    for (int st = 0; st < 2; ++st) {
      racc[st] = MFMA32(pA[st][0], onesv, racc[st]);
      racc[st] = MFMA32(pA[st][1], onesv, racc[st]);
    }
#pragma unroll
    for (int dt = 0; dt < 4; ++dt) {
      const int row = dt * 16 + ln;  // d row
#pragma unroll
      for (int nt2 = 0; nt2 < 2; ++nt2) {
        const f16x8 vf = *(const f16x8*)&sVT[grp][cur][row * 64 + (((quad * 2 + nt2) ^ (row & 7)) * 8)];
#pragma unroll
        for (int st = 0; st < 2; ++st)
          O[st][dt] = MFMA32(pA[st][nt2], vf, O[st][dt]);
      }
    }
    __builtin_amdgcn_s_setprio(0);

    if (t < 15) stageKV(cur ^ 1);  // vmcnt wait lands here, after compute
    __syncthreads();
  }

  // ---- combine the two kt-halves through the (now dead) staging LDS ----
  float* cO = (float*)&sK[0][0][0];   // 128 q x 64 d f32 = 32 KB (all of sK)
  float* cR = (float*)&sVT[0][0][0];  // 128 f32
  if (grp == 1) {
#pragma unroll
    for (int st = 0; st < 2; ++st) {
#pragma unroll
      for (int rg = 0; rg < 4; ++rg) {
        const int ql = wl * 32 + st * 16 + quad * 4 + rg;
#pragma unroll
        for (int dt = 0; dt < 4; ++dt) cO[ql * 64 + dt * 16 + ln] = O[st][dt][rg];
        if (ln == 0) cR[ql] = racc[st][rg];
      }
    }
  }
  __syncthreads();
  if (grp == 0) {
#pragma unroll
    for (int st = 0; st < 2; ++st) {
#pragma unroll
      for (int rg = 0; rg < 4; ++rg) {
        const int ql = wl * 32 + st * 16 + quad * 4 + rg;
        const float inv = 1.0f / (racc[st][rg] + cR[ql]);
        const int q = q0 + ql;
        const size_t orow = ((size_t)b * Ls + q) * DIM + h * HD;
#pragma unroll
        for (int dt = 0; dt < 4; ++dt)
          ao[orow + dt * 16 + ln] = (f16)((O[st][dt][rg] + cO[ql * 64 + dt * 16 + ln]) * inv);
      }
    }
  }
}

// ====== proj GEMM: 64x128 tile, BK=32, T14 reg-staged DEPTH-3 (ported from qkv) ======
// Same per-iter vmcnt(0)-drain disease r9 diagnosed on qkv; same verified fix.
__global__ __launch_bounds__(256) void proj_gemm_kernel(
    const f16* __restrict__ A, const f16* __restrict__ W, float* __restrict__ out) {
  constexpr int K = DIM;
  __shared__ alignas(16) f16 sA[2][64 * 32];
  __shared__ alignas(16) f16 sB[2][128 * 32];
  const int tid = threadIdx.x;
  const int w = tid >> 6, lane = tid & 63, ln = lane & 15, quad = lane >> 4;
  const int wm = w >> 1, wn = w & 1;  // wave: 32 rows x 64 cols
  const int m0 = blockIdx.y * 64, n0 = blockIdx.x * 128;

  const f16* gA;  // 256 chunks: 1 per thread
  {
    int p = tid >> 3, g = (tid & 7) ^ (p & 7);
    gA = A + (size_t)(m0 + 2 * p + (g >> 2)) * K + (g & 3) * 8;
  }
  const f16* gB[2];
#pragma unroll
  for (int s = 0; s < 2; ++s) {
    int lc = tid + s * 256;
    int p = lc >> 3, g = (lc & 7) ^ (p & 7);
    gB[s] = W + (size_t)(n0 + 2 * p + (g >> 2)) * K + (g & 3) * 8;
  }

  f16x8 rA[3], rB[3][2];  // tile j in set j%3
  auto loadT = [&](int k0, int pr) {
    rA[pr] = *(const f16x8*)(gA + k0);
#pragma unroll
    for (int s = 0; s < 2; ++s) rB[pr][s] = *(const f16x8*)(gB[s] + k0);
  };
  auto writeT = [&](int buf, int pr) {
    *(f16x8*)&sA[buf][tid * 8] = rA[pr];
#pragma unroll
    for (int s = 0; s < 2; ++s) *(f16x8*)&sB[buf][(tid + s * 256) * 8] = rB[pr][s];
  };

  f32x4 acc[2][4] = {};

  loadT(0, 0);
  loadT(32, 1);
  loadT(64, 2);
  writeT(0, 0);
  __syncthreads();

#pragma unroll
  for (int it = 0; it < 32; ++it) {
    const int cur = it & 1, nxt = cur ^ 1;
    if (it < 29) loadT((it + 3) * 32, (it + 3) % 3);
    f16x8 a[2];
#pragma unroll
    for (int mi = 0; mi < 2; ++mi)
      a[mi] = *(const f16x8*)&sA[cur][sw32(wm * 32 + mi * 16 + ln, quad)];
#pragma unroll
    for (int ni = 0; ni < 4; ++ni) {
      f16x8 b = *(const f16x8*)&sB[cur][sw32(wn * 64 + ni * 16 + ln, quad)];
#pragma unroll
      for (int mi = 0; mi < 2; ++mi) acc[mi][ni] = MFMA32(a[mi], b, acc[mi][ni]);
    }
    if (it < 31) writeT(nxt, (it + 1) % 3);
    __syncthreads();
  }

#pragma unroll
  for (int mi = 0; mi < 2; ++mi) {
#pragma unroll
    for (int rg = 0; rg < 4; ++rg) {
      int row = m0 + wm * 32 + mi * 16 + quad * 4 + rg;
      size_t o = (size_t)row * DIM + n0 + wn * 64;
#pragma unroll
      for (int ni = 0; ni < 4; ++ni) out[o + ni * 16 + ln] = acc[mi][ni][rg];
    }
  }
}

extern "C" void kernel_launch(void* const* d_in, const int* in_sizes, int n_in,
                              void* d_out, int out_size, void* d_ws, size_t ws_size,
                              hipStream_t stream) {
  (void)in_sizes; (void)n_in; (void)out_size; (void)ws_size;
  const float* x = (const float*)d_in[0];
  const float* v0 = (const float*)d_in[1];
  const float* rcos = (const float*)d_in[2];
  const float* rsin = (const float*)d_in[3];
  const float* wqkv = (const float*)d_in[4];
  const float* wproj = (const float*)d_in[5];
  const float* lamp = (const float*)d_in[6];
  float* out = (float*)d_out;
  float* vout = out + (size_t)BL * DIM;  // output #1: blended v, (B,H,L,HD)

  char* p = (char*)d_ws;
  auto take = [&](size_t n) { char* q = p; p += ((n + 255) / 256) * 256; return q; };
  f16* xf = (f16*)take((size_t)BL * DIM * 2);
  f16* wqf = (f16*)take((size_t)3 * DIM * DIM * 2);
  f16* wpf = (f16*)take((size_t)DIM * DIM * 2);
  f16* qb = (f16*)take((size_t)BL * DIM * 2);
  f16* kb = (f16*)take((size_t)BL * DIM * 2);
  f16* vbT = (f16*)take((size_t)BL * DIM * 2);  // (b,h,d, key-permuted l)
  f16* ao = xf;  // x dead after qkv_gemm; reuse (stream-ordered)

  constexpr int NCVT4 = (BL * DIM + 3 * DIM * DIM + DIM * DIM) / 4;
  cvt_all_kernel<<<dim3(NCVT4 / 256), dim3(256), 0, stream>>>(x, wqkv, wproj, xf, wqf, wpf);

  qkv_gemm_kernel<<<dim3(3 * DIM / 128, BL / 128), dim3(256), 0, stream>>>(
      xf, wqf, v0, rcos, rsin, lamp, qb, kb, vbT, vout);

  flash_kernel<<<dim3(Bs * NH * (Ls / 128)), dim3(512), 0, stream>>>(qb, kb, vbT, ao);

  proj_gemm_kernel<<<dim3(DIM / 128, BL / 64), dim3(256), 0, stream>>>(ao, wpf, out);
}

// Round 12
// 200.523 us; speedup vs baseline: 1.2143x; 1.0044x over previous
//
#include <hip/hip_runtime.h>

typedef _Float16 f16;
typedef _Float16 f16x8 __attribute__((ext_vector_type(8)));
typedef _Float16 f16x4 __attribute__((ext_vector_type(4)));
typedef float f32x4 __attribute__((ext_vector_type(4)));

#define MFMA32(a, b, c) __builtin_amdgcn_mfma_f32_16x16x32_f16((a), (b), (c), 0, 0, 0)

constexpr int Bs = 2, Ls = 2048, DIM = 1024, NH = 16, HD = 64;
constexpr int BL = Bs * Ls;  // 4096
constexpr float EPSV = 1e-6f;
constexpr float SCL2 = 0.125f * 1.44269504f;  // (1/sqrt(64)) * log2(e); folded into q

// Raw v_exp_f32 (2^x). Scores are RMS-normed, |x| small -> ocml's denorm/clamp fixup
// path is pure VALU waste; the bare instruction suffices.
__device__ __forceinline__ float fexp2(float x) {
#if __has_builtin(__builtin_amdgcn_exp2f)
  return __builtin_amdgcn_exp2f(x);
#else
  return exp2f(x);
#endif
}

// BK=32 pair-XOR swizzle: rows are 64B (4 chunks); swizzle unit = row PAIR (8 chunks).
// LDS linear chunk lc <-> (pair p = lc>>3, phys ph = lc&7); global chunk g = ph ^ (p&7),
// global (row, colElems) = (2p + (g>>2), (g&3)*8). Frag read of (row r, kchunk q):
// addr elems = (r>>1)*64 + (((r&1)*4 + q) ^ ((r>>1)&7))*8.  Banks: 2-way (free).
__device__ __forceinline__ int sw32(int r, int q) {
  int p = r >> 1;
  return p * 64 + ((((r & 1) * 4 + q) ^ (p & 7)) * 8);
}

// ---------------- fp32 -> fp16 convert, all three tensors in one launch ----------------
// fp32 sources are never read again -> nontemporal loads keep them out of L2.
__global__ void cvt_all_kernel(const float* __restrict__ x, const float* __restrict__ wq,
                               const float* __restrict__ wp, f16* __restrict__ xf,
                               f16* __restrict__ wqf, f16* __restrict__ wpf) {
  constexpr int NX4 = BL * DIM / 4;
  constexpr int NW4 = 3 * DIM * DIM / 4;
  int i = blockIdx.x * blockDim.x + threadIdx.x;
  const f32x4* src;
  f16x4* dst;
  int j;
  if (i < NX4) {
    src = (const f32x4*)x; dst = (f16x4*)xf; j = i;
  } else if (i < NX4 + NW4) {
    src = (const f32x4*)wq; dst = (f16x4*)wqf; j = i - NX4;
  } else {
    src = (const f32x4*)wp; dst = (f16x4*)wpf; j = i - NX4 - NW4;
  }
  f32x4 a = __builtin_nontemporal_load(&src[j]);
  f16x4 o = {(f16)a[0], (f16)a[1], (f16)a[2], (f16)a[3]};
  dst[j] = o;
}

// ====== QKV GEMM: 128x64 tile (occupancy rewrite), BK=32, T14 reg-staged depth-2 ======
// r11: depth-3 null -> prefetch depth not the limiter; grid 768=3 blocks/CU was (LDS/VGPR
// allow 5-6). This round: BN 128->64 -> 1536 blocks, 24KB LDS, ~90 VGPR, launch_bounds
// (256,5) -> 5-6 blocks/CU. Wave = 32 rows x 64 cols (full head) -> epilogue wave-local;
// nsec/h now BLOCK-uniform, so the v-transpose barrier is legal. Depth-2 staging (depth-3
// reverted: null on qkv, costs VGPR). Sync structure = r10-verified.
__global__ __launch_bounds__(256, 5) void qkv_gemm_kernel(
    const f16* __restrict__ A, const f16* __restrict__ W,
    const float* __restrict__ v0,
    const float* __restrict__ rcos, const float* __restrict__ rsin,
    const float* __restrict__ lamp,
    f16* __restrict__ qb, f16* __restrict__ kb, f16* __restrict__ vbT,
    float* __restrict__ vout) {
  constexpr int K = DIM;
  __shared__ alignas(16) f16 sA[2][128 * 32];  // 16KB
  __shared__ alignas(16) f16 sB[2][64 * 32];   // 8KB
  const int tid = threadIdx.x;
  const int w = tid >> 6, lane = tid & 63, ln = lane & 15, quad = lane >> 4;
  const int m0 = blockIdx.y * 128, n0 = blockIdx.x * 64;

  const f16* gA[2];  // A: 512 chunks/tile -> 2/thread
  const f16* gB;     // B: 256 chunks/tile -> 1/thread
#pragma unroll
  for (int s = 0; s < 2; ++s) {
    int lc = tid + s * 256;
    int p = lc >> 3, g = (lc & 7) ^ (p & 7);
    gA[s] = A + (size_t)(m0 + 2 * p + (g >> 2)) * K + (g & 3) * 8;
  }
  {
    int p = tid >> 3, g = (tid & 7) ^ (p & 7);
    gB = W + (size_t)(n0 + 2 * p + (g >> 2)) * K + (g & 3) * 8;
  }

  f16x8 rA[2][2], rB[2];  // [parity][s]; tile j lives in set j&1
  auto loadT = [&](int k0, int pr) {
#pragma unroll
    for (int s = 0; s < 2; ++s) rA[pr][s] = *(const f16x8*)(gA[s] + k0);
    rB[pr] = *(const f16x8*)(gB + k0);
  };
  auto writeT = [&](int buf, int pr) {
#pragma unroll
    for (int s = 0; s < 2; ++s) *(f16x8*)&sA[buf][(tid + s * 256) * 8] = rA[pr][s];
    *(f16x8*)&sB[buf][tid * 8] = rB[pr];
  };

  f32x4 acc[2][4] = {};

  loadT(0, 0);
  loadT(32, 1);
  writeT(0, 0);     // waits tile0's loads only; tile1's stay in flight
  __syncthreads();

#pragma unroll
  for (int it = 0; it < 32; ++it) {
    const int cur = it & 1, nxt = cur ^ 1;
    if (it < 30) loadT((it + 2) * 32, cur);  // reg set freed by writeT at iter it-1
    f16x8 a[2];
#pragma unroll
    for (int mi = 0; mi < 2; ++mi)
      a[mi] = *(const f16x8*)&sA[cur][sw32(w * 32 + mi * 16 + ln, quad)];
#pragma unroll
    for (int ni = 0; ni < 4; ++ni) {
      f16x8 b = *(const f16x8*)&sB[cur][sw32(ni * 16 + ln, quad)];
#pragma unroll
      for (int mi = 0; mi < 2; ++mi) acc[mi][ni] = MFMA32(a[mi], b, acc[mi][ni]);
    }
    if (it < 31) writeT(nxt, nxt);  // vmcnt wait for tile it+1 lands here, after compute
    __syncthreads();
  }

  // Epilogue. Block covers ONE head (64 cols) -> nsec/h uniform. Wave: rows w*32..+32,
  // all 4 ni col-tiles. C/D: col=ni*16+ln, row=w*32+mi*16+quad*4+rg.
  const int nsec = n0 >> 10;        // 0=q, 1=k, 2=v  (block-uniform)
  const int h = (n0 & 1023) >> 6;   // head

  if (nsec == 2) {
    const float lam = lamp[0];
    // wave PAIR (w>>1) covers a 64-key group; shared 8KB transpose tile [d][sidx]
    const int prow = m0 + (w >> 1) * 64;     // 64-aligned key-group base
    const int b = prow >> 11, l0 = prow & 2047;
    const size_t vb = (size_t)(b * NH + h) * Ls * HD;
    f16* wT = &sA[0][0] + (w >> 1) * 4096;   // 2 pair-tiles, fits sA (16KB)
    // final K-loop barrier already drained all sA/sB reads
#pragma unroll
    for (int mi = 0; mi < 2; ++mi) {
#pragma unroll
      for (int ni = 0; ni < 4; ++ni) {
        const int d = ni * 16 + ln;
        f16 pk[4];
#pragma unroll
        for (int rg = 0; rg < 4; ++rg) {
          const int kk = (w & 1) * 32 + mi * 16 + quad * 4 + rg;  // key within group
          const size_t base = vb + (size_t)(l0 + kk) * HD + d;
          float vnew = lam * acc[mi][ni][rg] + (1.0f - lam) * v0[base];
          vout[base] = vnew;  // fp32 output #1 (b,h,l,d), coalesced
          pk[rg] = (f16)vnew;
        }
        // sidx(key)=((key>>2)&3)*16+(key>>4)*4+(key&3) -> quad*16 + (mi+2*(w&1))*4 + rg
        f16x4 q4 = {pk[0], pk[1], pk[2], pk[3]};
        const int sidx0 = quad * 16 + (mi + 2 * (w & 1)) * 4;
        *(f16x4*)&wT[d * 64 + (sidx0 ^ ((d & 7) << 3))] = q4;
      }
    }
    __syncthreads();  // legal: nsec is block-uniform; pair halves now visible
    // coalesced read-out: each wave of the pair handles 32 d-rows
    const size_t tB = (size_t)(b * NH + h) * HD * Ls + l0;
#pragma unroll
    for (int dd = 0; dd < 8; ++dd) {
      const int d = (w & 1) * 32 + dd * 4 + quad;
      f16x4 vv = *(const f16x4*)&wT[d * 64 + ((ln * 4) ^ ((d & 7) << 3))];
      *(f16x4*)&vbT[tB + (size_t)d * Ls + ln * 4] = vv;
    }
  } else {
    f16* dst = nsec ? kb : qb;
    const float ratio = sqrtf(logf(2048.0f) / logf(1040.0f));
    const float post = nsec ? 1.0f : SCL2;  // fold softmax scale*log2e into q
#pragma unroll
    for (int mi = 0; mi < 2; ++mi) {
#pragma unroll
      for (int rg = 0; rg < 4; ++rg) {
        int row = m0 + w * 32 + mi * 16 + quad * 4 + rg;
        int b = row >> 11, l = row & 2047;
        float vals[4];
#pragma unroll
        for (int ni = 0; ni < 4; ++ni) vals[ni] = acc[mi][ni][rg];
#pragma unroll
        for (int t = 0; t < 2; ++t) {
          int j = t * 16 + ln;
          float c = rcos[l * 32 + j], s = rsin[l * 32 + j];
          float x1 = vals[t], x2 = vals[t + 2];
          vals[t] = x1 * c + x2 * s;
          vals[t + 2] = -x1 * s + x2 * c;
        }
        if (nsec) {
#pragma unroll
          for (int ni = 0; ni < 4; ++ni) vals[ni] *= ratio;
        }
        float ms = vals[0] * vals[0] + vals[1] * vals[1] + vals[2] * vals[2] + vals[3] * vals[3];
        ms += __shfl_xor(ms, 1);
        ms += __shfl_xor(ms, 2);
        ms += __shfl_xor(ms, 4);
        ms += __shfl_xor(ms, 8);
        float rn = rsqrtf(ms * (1.0f / 64.0f) + EPSV) * post;
        size_t base = ((size_t)(b * NH + h) * Ls + l) * HD;
#pragma unroll
        for (int ni = 0; ni < 4; ++ni) dst[base + ni * 16 + ln] = (f16)(vals[ni] * rn);
      }
    }
  }
}

// ============ Flash attention: kt-split wave groups + all-MFMA32 + rsum-via-ones ============
// r8->r9: fexp2 + unroll-2 verified. Unchanged this round.
__global__ __launch_bounds__(512, 4) void flash_kernel(
    const f16* __restrict__ qg, const f16* __restrict__ kg, const f16* __restrict__ vtg,
    f16* __restrict__ ao) {
  __shared__ alignas(16) f16 sK[2][2][64 * 64];   // [group][buf]
  __shared__ alignas(16) f16 sVT[2][2][64 * 64];  // [group][buf] [d][key-permuted]
  const int tid = threadIdx.x;
  const int w = tid >> 6, lane = tid & 63, ln = lane & 15, quad = lane >> 4;
  const int grp = w >> 2, wl = w & 3;  // kt-group, wave-in-group
  const int gt = tid & 255;            // thread id within group (staging)
  const int bx = blockIdx.x;
  const int bh = bx & 31, qt = bx >> 5;  // XCD-major: (b,h) fixed per bx%8 class
  const int h = bh & 15, b = bh >> 4;
  const f16* Qh = qg + (size_t)(b * NH + h) * Ls * HD;
  const f16* Kh = kg + (size_t)(b * NH + h) * Ls * HD;
  const f16* VTh = vtg + (size_t)(b * NH + h) * HD * Ls;
  const int q0 = qt * 128;

  // Q as B-frags straight from global: lane n=ln (q-col), k = kk*32 + quad*8 + j
  f16x8 aq[2][2];
#pragma unroll
  for (int st = 0; st < 2; ++st)
#pragma unroll
    for (int kk = 0; kk < 2; ++kk)
      aq[st][kk] = *(const f16x8*)&Qh[(size_t)(q0 + wl * 32 + st * 16 + ln) * HD + kk * 32 + quad * 8];

  f16x8 kr[2], vr[2];
  auto loadKV = [&](int k0) {
#pragma unroll
    for (int s = 0; s < 2; ++s) {
      int ch = gt + s * 256, r = ch >> 3, cg = (ch & 7) * 8;
      kr[s] = *(const f16x8*)&Kh[(size_t)(k0 + r) * HD + cg];
      vr[s] = *(const f16x8*)&VTh[(size_t)r * Ls + k0 + cg];
    }
  };
  auto stageKV = [&](int buf) {
#pragma unroll
    for (int s = 0; s < 2; ++s) {
      int ch = gt + s * 256, r = ch >> 3;
      int po = r * 64 + (((ch & 7) ^ (r & 7)) * 8);
      *(f16x8*)&sK[grp][buf][po] = kr[s];
      *(f16x8*)&sVT[grp][buf][po] = vr[s];
    }
  };

  f32x4 O[2][4] = {};
  f32x4 racc[2] = {};
  const f16x8 onesv = {(f16)1.f, (f16)1.f, (f16)1.f, (f16)1.f,
                       (f16)1.f, (f16)1.f, (f16)1.f, (f16)1.f};
  const f32x4 zc = {};

  const int kbase = grp << 10;  // group key offset
  loadKV(kbase);
  stageKV(0);
  __syncthreads();

#pragma unroll 2
  for (int t = 0; t < 16; ++t) {
    const int cur = t & 1;  // compile-time under unroll-2
    if (t < 15) loadKV(kbase + (t + 1) * 64);  // global->reg prefetch across compute

    // S^T + exp in registers -> merged PV A-frags (f16x8 = two 16-key tiles)
    f16x8 pA[2][2];
#pragma unroll
    for (int nt = 0; nt < 4; ++nt) {
      const int r = nt * 16 + ln;  // key row
      const f16x8 kf0 = *(const f16x8*)&sK[grp][cur][r * 64 + ((quad ^ (r & 7)) * 8)];
      const f16x8 kf1 = *(const f16x8*)&sK[grp][cur][r * 64 + (((4 + quad) ^ (r & 7)) * 8)];
#pragma unroll
      for (int st = 0; st < 2; ++st) {
        f32x4 z = MFMA32(kf1, aq[st][1], MFMA32(kf0, aq[st][0], zc));
#pragma unroll
        for (int j = 0; j < 4; ++j)
          pA[st][nt >> 1][(nt & 1) * 4 + j] = (f16)fexp2(z[j]);
      }
    }

    __builtin_amdgcn_s_setprio(1);
#pragma unroll
    for (int st = 0; st < 2; ++st) {
      racc[st] = MFMA32(pA[st][0], onesv, racc[st]);
      racc[st] = MFMA32(pA[st][1], onesv, racc[st]);
    }
#pragma unroll
    for (int dt = 0; dt < 4; ++dt) {
      const int row = dt * 16 + ln;  // d row
#pragma unroll
      for (int nt2 = 0; nt2 < 2; ++nt2) {
        const f16x8 vf = *(const f16x8*)&sVT[grp][cur][row * 64 + (((quad * 2 + nt2) ^ (row & 7)) * 8)];
#pragma unroll
        for (int st = 0; st < 2; ++st)
          O[st][dt] = MFMA32(pA[st][nt2], vf, O[st][dt]);
      }
    }
    __builtin_amdgcn_s_setprio(0);

    if (t < 15) stageKV(cur ^ 1);  // vmcnt wait lands here, after compute
    __syncthreads();
  }

  // ---- combine the two kt-halves through the (now dead) staging LDS ----
  float* cO = (float*)&sK[0][0][0];   // 128 q x 64 d f32 = 32 KB (all of sK)
  float* cR = (float*)&sVT[0][0][0];  // 128 f32
  if (grp == 1) {
#pragma unroll
    for (int st = 0; st < 2; ++st) {
#pragma unroll
      for (int rg = 0; rg < 4; ++rg) {
        const int ql = wl * 32 + st * 16 + quad * 4 + rg;
#pragma unroll
        for (int dt = 0; dt < 4; ++dt) cO[ql * 64 + dt * 16 + ln] = O[st][dt][rg];
        if (ln == 0) cR[ql] = racc[st][rg];
      }
    }
  }
  __syncthreads();
  if (grp == 0) {
#pragma unroll
    for (int st = 0; st < 2; ++st) {
#pragma unroll
      for (int rg = 0; rg < 4; ++rg) {
        const int ql = wl * 32 + st * 16 + quad * 4 + rg;
        const float inv = 1.0f / (racc[st][rg] + cR[ql]);
        const int q = q0 + ql;
        const size_t orow = ((size_t)b * Ls + q) * DIM + h * HD;
#pragma unroll
        for (int dt = 0; dt < 4; ++dt)
          ao[orow + dt * 16 + ln] = (f16)((O[st][dt][rg] + cO[ql * 64 + dt * 16 + ln]) * inv);
      }
    }
  }
}

// ====== proj GEMM: 64x128 tile, BK=32, T14 reg-staged DEPTH-3 (r11-verified) ======
__global__ __launch_bounds__(256) void proj_gemm_kernel(
    const f16* __restrict__ A, const f16* __restrict__ W, float* __restrict__ out) {
  constexpr int K = DIM;
  __shared__ alignas(16) f16 sA[2][64 * 32];
  __shared__ alignas(16) f16 sB[2][128 * 32];
  const int tid = threadIdx.x;
  const int w = tid >> 6, lane = tid & 63, ln = lane & 15, quad = lane >> 4;
  const int wm = w >> 1, wn = w & 1;  // wave: 32 rows x 64 cols
  const int m0 = blockIdx.y * 64, n0 = blockIdx.x * 128;

  const f16* gA;  // 256 chunks: 1 per thread
  {
    int p = tid >> 3, g = (tid & 7) ^ (p & 7);
    gA = A + (size_t)(m0 + 2 * p + (g >> 2)) * K + (g & 3) * 8;
  }
  const f16* gB[2];
#pragma unroll
  for (int s = 0; s < 2; ++s) {
    int lc = tid + s * 256;
    int p = lc >> 3, g = (lc & 7) ^ (p & 7);
    gB[s] = W + (size_t)(n0 + 2 * p + (g >> 2)) * K + (g & 3) * 8;
  }

  f16x8 rA[3], rB[3][2];  // tile j in set j%3
  auto loadT = [&](int k0, int pr) {
    rA[pr] = *(const f16x8*)(gA + k0);
#pragma unroll
    for (int s = 0; s < 2; ++s) rB[pr][s] = *(const f16x8*)(gB[s] + k0);
  };
  auto writeT = [&](int buf, int pr) {
    *(f16x8*)&sA[buf][tid * 8] = rA[pr];
#pragma unroll
    for (int s = 0; s < 2; ++s) *(f16x8*)&sB[buf][(tid + s * 256) * 8] = rB[pr][s];
  };

  f32x4 acc[2][4] = {};

  loadT(0, 0);
  loadT(32, 1);
  loadT(64, 2);
  writeT(0, 0);
  __syncthreads();

#pragma unroll
  for (int it = 0; it < 32; ++it) {
    const int cur = it & 1, nxt = cur ^ 1;
    if (it < 29) loadT((it + 3) * 32, (it + 3) % 3);
    f16x8 a[2];
#pragma unroll
    for (int mi = 0; mi < 2; ++mi)
      a[mi] = *(const f16x8*)&sA[cur][sw32(wm * 32 + mi * 16 + ln, quad)];
#pragma unroll
    for (int ni = 0; ni < 4; ++ni) {
      f16x8 b = *(const f16x8*)&sB[cur][sw32(wn * 64 + ni * 16 + ln, quad)];
#pragma unroll
      for (int mi = 0; mi < 2; ++mi) acc[mi][ni] = MFMA32(a[mi], b, acc[mi][ni]);
    }
    if (it < 31) writeT(nxt, (it + 1) % 3);
    __syncthreads();
  }

#pragma unroll
  for (int mi = 0; mi < 2; ++mi) {
#pragma unroll
    for (int rg = 0; rg < 4; ++rg) {
      int row = m0 + wm * 32 + mi * 16 + quad * 4 + rg;
      size_t o = (size_t)row * DIM + n0 + wn * 64;
#pragma unroll
      for (int ni = 0; ni < 4; ++ni) out[o + ni * 16 + ln] = acc[mi][ni][rg];
    }
  }
}

extern "C" void kernel_launch(void* const* d_in, const int* in_sizes, int n_in,
                              void* d_out, int out_size, void* d_ws, size_t ws_size,
                              hipStream_t stream) {
  (void)in_sizes; (void)n_in; (void)out_size; (void)ws_size;
  const float* x = (const float*)d_in[0];
  const float* v0 = (const float*)d_in[1];
  const float* rcos = (const float*)d_in[2];
  const float* rsin = (const float*)d_in[3];
  const float* wqkv = (const float*)d_in[4];
  const float* wproj = (const float*)d_in[5];
  const float* lamp = (const float*)d_in[6];
  float* out = (float*)d_out;
  float* vout = out + (size_t)BL * DIM;  // output #1: blended v, (B,H,L,HD)

  char* p = (char*)d_ws;
  auto take = [&](size_t n) { char* q = p; p += ((n + 255) / 256) * 256; return q; };
  f16* xf = (f16*)take((size_t)BL * DIM * 2);
  f16* wqf = (f16*)take((size_t)3 * DIM * DIM * 2);
  f16* wpf = (f16*)take((size_t)DIM * DIM * 2);
  f16* qb = (f16*)take((size_t)BL * DIM * 2);
  f16* kb = (f16*)take((size_t)BL * DIM * 2);
  f16* vbT = (f16*)take((size_t)BL * DIM * 2);  // (b,h,d, key-permuted l)
  f16* ao = xf;  // x dead after qkv_gemm; reuse (stream-ordered)

  constexpr int NCVT4 = (BL * DIM + 3 * DIM * DIM + DIM * DIM) / 4;
  cvt_all_kernel<<<dim3(NCVT4 / 256), dim3(256), 0, stream>>>(x, wqkv, wproj, xf, wqf, wpf);

  qkv_gemm_kernel<<<dim3(3 * DIM / 64, BL / 128), dim3(256), 0, stream>>>(
      xf, wqf, v0, rcos, rsin, lamp, qb, kb, vbT, vout);

  flash_kernel<<<dim3(Bs * NH * (Ls / 128)), dim3(512), 0, stream>>>(qb, kb, vbT, ao);

  proj_gemm_kernel<<<dim3(DIM / 128, BL / 64), dim3(256), 0, stream>>>(ao, wpf, out);
}

// Round 13
// 194.766 us; speedup vs baseline: 1.2502x; 1.0296x over previous
//
#include <hip/hip_runtime.h>

typedef _Float16 f16;
typedef _Float16 f16x8 __attribute__((ext_vector_type(8)));
typedef _Float16 f16x4 __attribute__((ext_vector_type(4)));
typedef float f32x4 __attribute__((ext_vector_type(4)));

#define MFMA32(a, b, c) __builtin_amdgcn_mfma_f32_16x16x32_f16((a), (b), (c), 0, 0, 0)

constexpr int Bs = 2, Ls = 2048, DIM = 1024, NH = 16, HD = 64;
constexpr int BL = Bs * Ls;  // 4096
constexpr float EPSV = 1e-6f;
constexpr float SCL2 = 0.125f * 1.44269504f;  // (1/sqrt(64)) * log2(e); folded into q

// Raw v_exp_f32 (2^x). Scores are RMS-normed, |x| small -> ocml's denorm/clamp fixup
// path is pure VALU waste; the bare instruction suffices.
__device__ __forceinline__ float fexp2(float x) {
#if __has_builtin(__builtin_amdgcn_exp2f)
  return __builtin_amdgcn_exp2f(x);
#else
  return exp2f(x);
#endif
}

// BK=32 pair-XOR swizzle: rows are 64B (4 chunks); swizzle unit = row PAIR (8 chunks).
// LDS linear chunk lc <-> (pair p = lc>>3, phys ph = lc&7); global chunk g = ph ^ (p&7),
// global (row, colElems) = (2p + (g>>2), (g&3)*8). Frag read of (row r, kchunk q):
// addr elems = (r>>1)*64 + (((r&1)*4 + q) ^ ((r>>1)&7))*8.  Banks: 2-way (free).
__device__ __forceinline__ int sw32(int r, int q) {
  int p = r >> 1;
  return p * 64 + ((((r & 1) * 4 + q) ^ (p & 7)) * 8);
}

// ---------------- fp32 -> fp16 convert, all three tensors in one launch ----------------
// fp32 sources are never read again -> nontemporal loads keep them out of L2.
__global__ void cvt_all_kernel(const float* __restrict__ x, const float* __restrict__ wq,
                               const float* __restrict__ wp, f16* __restrict__ xf,
                               f16* __restrict__ wqf, f16* __restrict__ wpf) {
  constexpr int NX4 = BL * DIM / 4;
  constexpr int NW4 = 3 * DIM * DIM / 4;
  int i = blockIdx.x * blockDim.x + threadIdx.x;
  const f32x4* src;
  f16x4* dst;
  int j;
  if (i < NX4) {
    src = (const f32x4*)x; dst = (f16x4*)xf; j = i;
  } else if (i < NX4 + NW4) {
    src = (const f32x4*)wq; dst = (f16x4*)wqf; j = i - NX4;
  } else {
    src = (const f32x4*)wp; dst = (f16x4*)wpf; j = i - NX4 - NW4;
  }
  f32x4 a = __builtin_nontemporal_load(&src[j]);
  f16x4 o = {(f16)a[0], (f16)a[1], (f16)a[2], (f16)a[3]};
  dst[j] = o;
}

// ====== QKV GEMM: 128x64 tile, BK=64 (2x BK=32 sub-tiles/iter), T14 reg-staged depth-2 ======
// r12: occupancy 13.5->37.6% with dur NULL -> neither prefetch depth (r11) nor wave count
// (r12) limits; the floor is the PER-ITERATION fixed cost (barrier + writeT vmcnt + ds_read
// ->MFMA chain) x 32 iters. This round: 16 iters of 2x work — same BK=32 LDS layout/swizzle,
// each buffer holds two sub-K blocks; barrier count halves, fixed cost amortizes 2x.
// LDS 48KB -> 3 blocks/CU (r12 proved occupancy non-binding). VGPR was 48 -> room for 2x
// staging regs. Sync structure = r10/r12-verified.
// Pre-commit: qkv >= 50us -> structural limit for this decomposition; stop qkv, go flash.
__global__ __launch_bounds__(256, 3) void qkv_gemm_kernel(
    const f16* __restrict__ A, const f16* __restrict__ W,
    const float* __restrict__ v0,
    const float* __restrict__ rcos, const float* __restrict__ rsin,
    const float* __restrict__ lamp,
    f16* __restrict__ qb, f16* __restrict__ kb, f16* __restrict__ vbT,
    float* __restrict__ vout) {
  constexpr int K = DIM;
  __shared__ alignas(16) f16 sA[2][2][128 * 32];  // [buf][kk]; 32KB
  __shared__ alignas(16) f16 sB[2][2][64 * 32];   // [buf][kk]; 16KB
  const int tid = threadIdx.x;
  const int w = tid >> 6, lane = tid & 63, ln = lane & 15, quad = lane >> 4;
  const int m0 = blockIdx.y * 128, n0 = blockIdx.x * 64;

  const f16* gA[2];  // A: 512 chunks per BK=32 sub-tile -> 2/thread
  const f16* gB;     // B: 256 chunks per sub-tile -> 1/thread
#pragma unroll
  for (int s = 0; s < 2; ++s) {
    int lc = tid + s * 256;
    int p = lc >> 3, g = (lc & 7) ^ (p & 7);
    gA[s] = A + (size_t)(m0 + 2 * p + (g >> 2)) * K + (g & 3) * 8;
  }
  {
    int p = tid >> 3, g = (tid & 7) ^ (p & 7);
    gB = W + (size_t)(n0 + 2 * p + (g >> 2)) * K + (g & 3) * 8;
  }

  f16x8 rA[2][2][2], rB[2][2];  // [parity][kk][s] / [parity][kk]; tile j in parity j&1
  auto loadT = [&](int k0, int pr) {
#pragma unroll
    for (int kk = 0; kk < 2; ++kk) {
#pragma unroll
      for (int s = 0; s < 2; ++s) rA[pr][kk][s] = *(const f16x8*)(gA[s] + k0 + kk * 32);
      rB[pr][kk] = *(const f16x8*)(gB + k0 + kk * 32);
    }
  };
  auto writeT = [&](int buf, int pr) {
#pragma unroll
    for (int kk = 0; kk < 2; ++kk) {
#pragma unroll
      for (int s = 0; s < 2; ++s) *(f16x8*)&sA[buf][kk][(tid + s * 256) * 8] = rA[pr][kk][s];
      *(f16x8*)&sB[buf][kk][tid * 8] = rB[pr][kk];
    }
  };

  f32x4 acc[2][4] = {};

  loadT(0, 0);
  loadT(64, 1);
  writeT(0, 0);     // waits tile0's loads only; tile1's stay in flight
  __syncthreads();

#pragma unroll
  for (int it = 0; it < 16; ++it) {
    const int cur = it & 1, nxt = cur ^ 1;
    if (it < 14) loadT((it + 2) * 64, cur);  // reg set freed by writeT at iter it-1
#pragma unroll
    for (int kk = 0; kk < 2; ++kk) {
      f16x8 a[2];
#pragma unroll
      for (int mi = 0; mi < 2; ++mi)
        a[mi] = *(const f16x8*)&sA[cur][kk][sw32(w * 32 + mi * 16 + ln, quad)];
#pragma unroll
      for (int ni = 0; ni < 4; ++ni) {
        f16x8 b = *(const f16x8*)&sB[cur][kk][sw32(ni * 16 + ln, quad)];
#pragma unroll
        for (int mi = 0; mi < 2; ++mi) acc[mi][ni] = MFMA32(a[mi], b, acc[mi][ni]);
      }
    }
    if (it < 15) writeT(nxt, nxt);  // vmcnt wait for tile it+1 lands here, after compute
    __syncthreads();
  }

  // Epilogue. Block covers ONE head (64 cols) -> nsec/h uniform. Wave: rows w*32..+32,
  // all 4 ni col-tiles. C/D: col=ni*16+ln, row=w*32+mi*16+quad*4+rg.
  const int nsec = n0 >> 10;        // 0=q, 1=k, 2=v  (block-uniform)
  const int h = (n0 & 1023) >> 6;   // head

  if (nsec == 2) {
    const float lam = lamp[0];
    // wave PAIR (w>>1) covers a 64-key group; shared 8KB transpose tile [d][sidx]
    const int prow = m0 + (w >> 1) * 64;     // 64-aligned key-group base
    const int b = prow >> 11, l0 = prow & 2047;
    const size_t vb = (size_t)(b * NH + h) * Ls * HD;
    f16* wT = &sA[0][0][0] + (w >> 1) * 4096;  // 2 pair-tiles, fits sA
    // final K-loop barrier already drained all sA/sB reads
#pragma unroll
    for (int mi = 0; mi < 2; ++mi) {
#pragma unroll
      for (int ni = 0; ni < 4; ++ni) {
        const int d = ni * 16 + ln;
        f16 pk[4];
#pragma unroll
        for (int rg = 0; rg < 4; ++rg) {
          const int kk = (w & 1) * 32 + mi * 16 + quad * 4 + rg;  // key within group
          const size_t base = vb + (size_t)(l0 + kk) * HD + d;
          float vnew = lam * acc[mi][ni][rg] + (1.0f - lam) * v0[base];
          vout[base] = vnew;  // fp32 output #1 (b,h,l,d), coalesced
          pk[rg] = (f16)vnew;
        }
        // sidx(key)=((key>>2)&3)*16+(key>>4)*4+(key&3) -> quad*16 + (mi+2*(w&1))*4 + rg
        f16x4 q4 = {pk[0], pk[1], pk[2], pk[3]};
        const int sidx0 = quad * 16 + (mi + 2 * (w & 1)) * 4;
        *(f16x4*)&wT[d * 64 + (sidx0 ^ ((d & 7) << 3))] = q4;
      }
    }
    __syncthreads();  // legal: nsec is block-uniform; pair halves now visible
    // coalesced read-out: each wave of the pair handles 32 d-rows
    const size_t tB = (size_t)(b * NH + h) * HD * Ls + l0;
#pragma unroll
    for (int dd = 0; dd < 8; ++dd) {
      const int d = (w & 1) * 32 + dd * 4 + quad;
      f16x4 vv = *(const f16x4*)&wT[d * 64 + ((ln * 4) ^ ((d & 7) << 3))];
      *(f16x4*)&vbT[tB + (size_t)d * Ls + ln * 4] = vv;
    }
  } else {
    f16* dst = nsec ? kb : qb;
    const float ratio = sqrtf(logf(2048.0f) / logf(1040.0f));
    const float post = nsec ? 1.0f : SCL2;  // fold softmax scale*log2e into q
#pragma unroll
    for (int mi = 0; mi < 2; ++mi) {
#pragma unroll
      for (int rg = 0; rg < 4; ++rg) {
        int row = m0 + w * 32 + mi * 16 + quad * 4 + rg;
        int b = row >> 11, l = row & 2047;
        float vals[4];
#pragma unroll
        for (int ni = 0; ni < 4; ++ni) vals[ni] = acc[mi][ni][rg];
#pragma unroll
        for (int t = 0; t < 2; ++t) {
          int j = t * 16 + ln;
          float c = rcos[l * 32 + j], s = rsin[l * 32 + j];
          float x1 = vals[t], x2 = vals[t + 2];
          vals[t] = x1 * c + x2 * s;
          vals[t + 2] = -x1 * s + x2 * c;
        }
        if (nsec) {
#pragma unroll
          for (int ni = 0; ni < 4; ++ni) vals[ni] *= ratio;
        }
        float ms = vals[0] * vals[0] + vals[1] * vals[1] + vals[2] * vals[2] + vals[3] * vals[3];
        ms += __shfl_xor(ms, 1);
        ms += __shfl_xor(ms, 2);
        ms += __shfl_xor(ms, 4);
        ms += __shfl_xor(ms, 8);
        float rn = rsqrtf(ms * (1.0f / 64.0f) + EPSV) * post;
        size_t base = ((size_t)(b * NH + h) * Ls + l) * HD;
#pragma unroll
        for (int ni = 0; ni < 4; ++ni) dst[base + ni * 16 + ln] = (f16)(vals[ni] * rn);
      }
    }
  }
}

// ============ Flash attention: kt-split wave groups + all-MFMA32 + rsum-via-ones ============
// r8->r9: fexp2 + unroll-2 verified. Unchanged this round.
__global__ __launch_bounds__(512, 4) void flash_kernel(
    const f16* __restrict__ qg, const f16* __restrict__ kg, const f16* __restrict__ vtg,
    f16* __restrict__ ao) {
  __shared__ alignas(16) f16 sK[2][2][64 * 64];   // [group][buf]
  __shared__ alignas(16) f16 sVT[2][2][64 * 64];  // [group][buf] [d][key-permuted]
  const int tid = threadIdx.x;
  const int w = tid >> 6, lane = tid & 63, ln = lane & 15, quad = lane >> 4;
  const int grp = w >> 2, wl = w & 3;  // kt-group, wave-in-group
  const int gt = tid & 255;            // thread id within group (staging)
  const int bx = blockIdx.x;
  const int bh = bx & 31, qt = bx >> 5;  // XCD-major: (b,h) fixed per bx%8 class
  const int h = bh & 15, b = bh >> 4;
  const f16* Qh = qg + (size_t)(b * NH + h) * Ls * HD;
  const f16* Kh = kg + (size_t)(b * NH + h) * Ls * HD;
  const f16* VTh = vtg + (size_t)(b * NH + h) * HD * Ls;
  const int q0 = qt * 128;

  // Q as B-frags straight from global: lane n=ln (q-col), k = kk*32 + quad*8 + j
  f16x8 aq[2][2];
#pragma unroll
  for (int st = 0; st < 2; ++st)
#pragma unroll
    for (int kk = 0; kk < 2; ++kk)
      aq[st][kk] = *(const f16x8*)&Qh[(size_t)(q0 + wl * 32 + st * 16 + ln) * HD + kk * 32 + quad * 8];

  f16x8 kr[2], vr[2];
  auto loadKV = [&](int k0) {
#pragma unroll
    for (int s = 0; s < 2; ++s) {
      int ch = gt + s * 256, r = ch >> 3, cg = (ch & 7) * 8;
      kr[s] = *(const f16x8*)&Kh[(size_t)(k0 + r) * HD + cg];
      vr[s] = *(const f16x8*)&VTh[(size_t)r * Ls + k0 + cg];
    }
  };
  auto stageKV = [&](int buf) {
#pragma unroll
    for (int s = 0; s < 2; ++s) {
      int ch = gt + s * 256, r = ch >> 3;
      int po = r * 64 + (((ch & 7) ^ (r & 7)) * 8);
      *(f16x8*)&sK[grp][buf][po] = kr[s];
      *(f16x8*)&sVT[grp][buf][po] = vr[s];
    }
  };

  f32x4 O[2][4] = {};
  f32x4 racc[2] = {};
  const f16x8 onesv = {(f16)1.f, (f16)1.f, (f16)1.f, (f16)1.f,
                       (f16)1.f, (f16)1.f, (f16)1.f, (f16)1.f};
  const f32x4 zc = {};

  const int kbase = grp << 10;  // group key offset
  loadKV(kbase);
  stageKV(0);
  __syncthreads();

#pragma unroll 2
  for (int t = 0; t < 16; ++t) {
    const int cur = t & 1;  // compile-time under unroll-2
    if (t < 15) loadKV(kbase + (t + 1) * 64);  // global->reg prefetch across compute

    // S^T + exp in registers -> merged PV A-frags (f16x8 = two 16-key tiles)
    f16x8 pA[2][2];
#pragma unroll
    for (int nt = 0; nt < 4; ++nt) {
      const int r = nt * 16 + ln;  // key row
      const f16x8 kf0 = *(const f16x8*)&sK[grp][cur][r * 64 + ((quad ^ (r & 7)) * 8)];
      const f16x8 kf1 = *(const f16x8*)&sK[grp][cur][r * 64 + (((4 + quad) ^ (r & 7)) * 8)];
#pragma unroll
      for (int st = 0; st < 2; ++st) {
        f32x4 z = MFMA32(kf1, aq[st][1], MFMA32(kf0, aq[st][0], zc));
#pragma unroll
        for (int j = 0; j < 4; ++j)
          pA[st][nt >> 1][(nt & 1) * 4 + j] = (f16)fexp2(z[j]);
      }
    }

    __builtin_amdgcn_s_setprio(1);
#pragma unroll
    for (int st = 0; st < 2; ++st) {
      racc[st] = MFMA32(pA[st][0], onesv, racc[st]);
      racc[st] = MFMA32(pA[st][1], onesv, racc[st]);
    }
#pragma unroll
    for (int dt = 0; dt < 4; ++dt) {
      const int row = dt * 16 + ln;  // d row
#pragma unroll
      for (int nt2 = 0; nt2 < 2; ++nt2) {
        const f16x8 vf = *(const f16x8*)&sVT[grp][cur][row * 64 + (((quad * 2 + nt2) ^ (row & 7)) * 8)];
#pragma unroll
        for (int st = 0; st < 2; ++st)
          O[st][dt] = MFMA32(pA[st][nt2], vf, O[st][dt]);
      }
    }
    __builtin_amdgcn_s_setprio(0);

    if (t < 15) stageKV(cur ^ 1);  // vmcnt wait lands here, after compute
    __syncthreads();
  }

  // ---- combine the two kt-halves through the (now dead) staging LDS ----
  float* cO = (float*)&sK[0][0][0];   // 128 q x 64 d f32 = 32 KB (all of sK)
  float* cR = (float*)&sVT[0][0][0];  // 128 f32
  if (grp == 1) {
#pragma unroll
    for (int st = 0; st < 2; ++st) {
#pragma unroll
      for (int rg = 0; rg < 4; ++rg) {
        const int ql = wl * 32 + st * 16 + quad * 4 + rg;
#pragma unroll
        for (int dt = 0; dt < 4; ++dt) cO[ql * 64 + dt * 16 + ln] = O[st][dt][rg];
        if (ln == 0) cR[ql] = racc[st][rg];
      }
    }
  }
  __syncthreads();
  if (grp == 0) {
#pragma unroll
    for (int st = 0; st < 2; ++st) {
#pragma unroll
      for (int rg = 0; rg < 4; ++rg) {
        const int ql = wl * 32 + st * 16 + quad * 4 + rg;
        const float inv = 1.0f / (racc[st][rg] + cR[ql]);
        const int q = q0 + ql;
        const size_t orow = ((size_t)b * Ls + q) * DIM + h * HD;
#pragma unroll
        for (int dt = 0; dt < 4; ++dt)
          ao[orow + dt * 16 + ln] = (f16)((O[st][dt][rg] + cO[ql * 64 + dt * 16 + ln]) * inv);
      }
    }
  }
}

// ====== proj GEMM: 64x128 tile, BK=32, T14 reg-staged DEPTH-3 (r11-verified) ======
__global__ __launch_bounds__(256) void proj_gemm_kernel(
    const f16* __restrict__ A, const f16* __restrict__ W, float* __restrict__ out) {
  constexpr int K = DIM;
  __shared__ alignas(16) f16 sA[2][64 * 32];
  __shared__ alignas(16) f16 sB[2][128 * 32];
  const int tid = threadIdx.x;
  const int w = tid >> 6, lane = tid & 63, ln = lane & 15, quad = lane >> 4;
  const int wm = w >> 1, wn = w & 1;  // wave: 32 rows x 64 cols
  const int m0 = blockIdx.y * 64, n0 = blockIdx.x * 128;

  const f16* gA;  // 256 chunks: 1 per thread
  {
    int p = tid >> 3, g = (tid & 7) ^ (p & 7);
    gA = A + (size_t)(m0 + 2 * p + (g >> 2)) * K + (g & 3) * 8;
  }
  const f16* gB[2];
#pragma unroll
  for (int s = 0; s < 2; ++s) {
    int lc = tid + s * 256;
    int p = lc >> 3, g = (lc & 7) ^ (p & 7);
    gB[s] = W + (size_t)(n0 + 2 * p + (g >> 2)) * K + (g & 3) * 8;
  }

  f16x8 rA[3], rB[3][2];  // tile j in set j%3
  auto loadT = [&](int k0, int pr) {
    rA[pr] = *(const f16x8*)(gA + k0);
#pragma unroll
    for (int s = 0; s < 2; ++s) rB[pr][s] = *(const f16x8*)(gB[s] + k0);
  };
  auto writeT = [&](int buf, int pr) {
    *(f16x8*)&sA[buf][tid * 8] = rA[pr];
#pragma unroll
    for (int s = 0; s < 2; ++s) *(f16x8*)&sB[buf][(tid + s * 256) * 8] = rB[pr][s];
  };

  f32x4 acc[2][4] = {};

  loadT(0, 0);
  loadT(32, 1);
  loadT(64, 2);
  writeT(0, 0);
  __syncthreads();

#pragma unroll
  for (int it = 0; it < 32; ++it) {
    const int cur = it & 1, nxt = cur ^ 1;
    if (it < 29) loadT((it + 3) * 32, (it + 3) % 3);
    f16x8 a[2];
#pragma unroll
    for (int mi = 0; mi < 2; ++mi)
      a[mi] = *(const f16x8*)&sA[cur][sw32(wm * 32 + mi * 16 + ln, quad)];
#pragma unroll
    for (int ni = 0; ni < 4; ++ni) {
      f16x8 b = *(const f16x8*)&sB[cur][sw32(wn * 64 + ni * 16 + ln, quad)];
#pragma unroll
      for (int mi = 0; mi < 2; ++mi) acc[mi][ni] = MFMA32(a[mi], b, acc[mi][ni]);
    }
    if (it < 31) writeT(nxt, (it + 1) % 3);
    __syncthreads();
  }

#pragma unroll
  for (int mi = 0; mi < 2; ++mi) {
#pragma unroll
    for (int rg = 0; rg < 4; ++rg) {
      int row = m0 + wm * 32 + mi * 16 + quad * 4 + rg;
      size_t o = (size_t)row * DIM + n0 + wn * 64;
#pragma unroll
      for (int ni = 0; ni < 4; ++ni) out[o + ni * 16 + ln] = acc[mi][ni][rg];
    }
  }
}

extern "C" void kernel_launch(void* const* d_in, const int* in_sizes, int n_in,
                              void* d_out, int out_size, void* d_ws, size_t ws_size,
                              hipStream_t stream) {
  (void)in_sizes; (void)n_in; (void)out_size; (void)ws_size;
  const float* x = (const float*)d_in[0];
  const float* v0 = (const float*)d_in[1];
  const float* rcos = (const float*)d_in[2];
  const float* rsin = (const float*)d_in[3];
  const float* wqkv = (const float*)d_in[4];
  const float* wproj = (const float*)d_in[5];
  const float* lamp = (const float*)d_in[6];
  float* out = (float*)d_out;
  float* vout = out + (size_t)BL * DIM;  // output #1: blended v, (B,H,L,HD)

  char* p = (char*)d_ws;
  auto take = [&](size_t n) { char* q = p; p += ((n + 255) / 256) * 256; return q; };
  f16* xf = (f16*)take((size_t)BL * DIM * 2);
  f16* wqf = (f16*)take((size_t)3 * DIM * DIM * 2);
  f16* wpf = (f16*)take((size_t)DIM * DIM * 2);
  f16* qb = (f16*)take((size_t)BL * DIM * 2);
  f16* kb = (f16*)take((size_t)BL * DIM * 2);
  f16* vbT = (f16*)take((size_t)BL * DIM * 2);  // (b,h,d, key-permuted l)
  f16* ao = xf;  // x dead after qkv_gemm; reuse (stream-ordered)

  constexpr int NCVT4 = (BL * DIM + 3 * DIM * DIM + DIM * DIM) / 4;
  cvt_all_kernel<<<dim3(NCVT4 / 256), dim3(256), 0, stream>>>(x, wqkv, wproj, xf, wqf, wpf);

  qkv_gemm_kernel<<<dim3(3 * DIM / 64, BL / 128), dim3(256), 0, stream>>>(
      xf, wqf, v0, rcos, rsin, lamp, qb, kb, vbT, vout);

  flash_kernel<<<dim3(Bs * NH * (Ls / 128)), dim3(512), 0, stream>>>(qb, kb, vbT, ao);

  proj_gemm_kernel<<<dim3(DIM / 128, BL / 64), dim3(256), 0, stream>>>(ao, wpf, out);
}